// Round 4
// baseline (1728.121 us; speedup 1.0000x reference)
//
#include <hip/hip_runtime.h>
#include <stdint.h>

#define NN 20000
#define NE 160000
#define L_IN 15
#define D_H 128
#define N_HEADS 8
#define D_HC 1024
#define N_LAYERS 6
#define M_PAD 20096   // 157*128, row padding so GEMM tiles can over-read safely
#define QSTRIDE 4096  // q|k|v|x_r interleaved row stride

typedef unsigned short u16;
typedef __attribute__((ext_vector_type(8))) short short8;
typedef __attribute__((ext_vector_type(4))) float f32x4;

__device__ __forceinline__ float bu2f(u16 u) { return __uint_as_float(((unsigned)u) << 16); }
__device__ __forceinline__ u16 f2bu(float f) {
    unsigned x = __float_as_uint(f);
    return (u16)((x + 0x7fffu + ((x >> 16) & 1u)) >> 16);  // RNE
}
__device__ __forceinline__ float wred64(float v) {
#pragma unroll
    for (int m = 32; m >= 1; m >>= 1) v += __shfl_xor(v, m, 64);
    return v;
}

// ---------------- dtype detection ----------------
// If the float inputs are fp32, even-indexed u16s are fp32 mantissa low-halves:
// as bf16 their exponent field is ~uniform(0..255) -> ~80% look "weird".
// If inputs are bf16, all u16s are N(0,~1)-ish bf16 -> exponent in ~[100,150].
__global__ void k_detect(const u16* __restrict__ xb, int* __restrict__ flag) {
    int t = threadIdx.x;  // 256
    u16 u = xb[2 * t];
    int e = (u >> 7) & 0xFF;
    int weird = (e > 150 || (e != 0 && e < 100)) ? 1 : 0;
    __shared__ int cnt;
    if (t == 0) cnt = 0;
    __syncthreads();
    atomicAdd(&cnt, weird);
    __syncthreads();
    if (t == 0) *flag = (cnt > 64) ? 1 : 0;  // 1 = inputs are fp32
}

// convert one float input to bf16 (or copy if already bf16)
__global__ void k_convert(const void* __restrict__ in, u16* __restrict__ out, int n,
                          const int* __restrict__ flag) {
    int i = blockIdx.x * 256 + threadIdx.x;
    if (i >= n) return;
    if (*flag) out[i] = f2bu(((const float*)in)[i]);
    else       out[i] = ((const u16*)in)[i];
}

// ---------------- utility: zero an int buffer ----------------
__global__ void k_zero(int* __restrict__ p, int n) {
    int i = blockIdx.x * 256 + threadIdx.x;
    if (i < n) p[i] = 0;
}

// ---------------- weight transposes (once per call) ----------------
__global__ void k_transpose_qkvs(const u16* __restrict__ Wq, const u16* __restrict__ Wk,
                                 const u16* __restrict__ Wv, const u16* __restrict__ Ws,
                                 u16* __restrict__ WT) {
    int gid = blockIdx.x * 256 + threadIdx.x;  // total L*4096*128
    int l = gid / (4096 * 128);
    int r = gid - l * 4096 * 128;
    int n = r >> 7;       // 0..4095 (q|k|v|skip output col)
    int kk = r & 127;     // 0..127
    int s = n >> 10, nn = n & 1023;
    const u16* W = (s == 0) ? Wq : (s == 1) ? Wk : (s == 2) ? Wv : Ws;
    WT[gid] = W[(size_t)l * D_H * D_HC + kk * D_HC + nn];
}

__global__ void k_transpose_proj(const u16* __restrict__ Wp, u16* __restrict__ WT) {
    int gid = blockIdx.x * 256 + threadIdx.x;  // total L*128*1024
    int l = gid / (128 * 1024);
    int r = gid - l * 128 * 1024;
    int n = r >> 10;      // 0..127
    int kk = r & 1023;    // 0..1023
    WT[gid] = Wp[(size_t)l * D_HC * D_H + kk * D_H + n];
}

// ---------------- input projection: h = x @ Win + b_in ----------------
__global__ void k_input_proj(const u16* __restrict__ x, const u16* __restrict__ Win,
                             const u16* __restrict__ b_in, u16* __restrict__ h) {
    int gid = blockIdx.x * 256 + threadIdx.x;  // NN*128
    int n = gid >> 7, j = gid & 127;
    float acc = bu2f(b_in[j]);
#pragma unroll
    for (int i = 0; i < L_IN; i++) acc += bu2f(x[n * L_IN + i]) * bu2f(Win[i * D_H + j]);
    h[gid] = f2bu(acc);
}

// ---------------- CSR build (counting sort by dst) ----------------
__global__ void k_hist(const int* __restrict__ dst, int* __restrict__ cnt) {
    int e = blockIdx.x * 256 + threadIdx.x;
    if (e < NE) atomicAdd(&cnt[dst[e]], 1);
}
__global__ void k_scanA(const int* __restrict__ cnt, int* __restrict__ incl, int* __restrict__ bsum) {
    __shared__ int s[256];
    int b = blockIdx.x, t = threadIdx.x, i = b * 256 + t;
    int v = (i < NN) ? cnt[i] : 0;
    s[t] = v;
    __syncthreads();
    for (int off = 1; off < 256; off <<= 1) {
        int u = (t >= off) ? s[t - off] : 0;
        __syncthreads();
        s[t] += u;
        __syncthreads();
    }
    if (i < NN) incl[i] = s[t];
    if (t == 255) bsum[b] = s[255];
}
__global__ void k_scanB(const int* __restrict__ bsum, int* __restrict__ bpre, int nb) {
    if (threadIdx.x == 0 && blockIdx.x == 0) {
        int run = 0;
        for (int b = 0; b < nb; b++) { bpre[b] = run; run += bsum[b]; }
    }
}
__global__ void k_scanC(const int* __restrict__ incl, const int* __restrict__ bpre, int* __restrict__ offs) {
    int b = blockIdx.x, t = threadIdx.x, i = b * 256 + t;
    if (i < NN) offs[i + 1] = incl[i] + bpre[b];
    if (i == 0) offs[0] = 0;
}
__global__ void k_scatter(const int* __restrict__ dst, const int* __restrict__ offs,
                          int* __restrict__ cursor, int* __restrict__ perm) {
    int e = blockIdx.x * 256 + threadIdx.x;
    if (e < NE) {
        int d = dst[e];
        int p = offs[d] + atomicAdd(&cursor[d], 1);
        perm[p] = e;
    }
}

// ---------------- MFMA GEMM: C[M,N] = A[M,K] @ Bt[N,K]^T (+epilogue) ----------------
// m97-proven shape: 128x128 tile, BK=32, LDS = 2 x 128x32 u16 = 16384 B.
// mode 0: C(u16) = bf16(acc + bias_{q|k|v|skip}(col)), ldc=4096 (QKVS interleave)
// mode 1: C(u16) = bf16(nan-relu(acc + bias[col] + resid[row,col])), ldc=128
// mode 2: like mode 1 but C is d_out: writes float if *flag (fp32 world) else u16
__global__ void k_gemm(const u16* __restrict__ A, int lda, int K,
                       const u16* __restrict__ Bt,
                       void* __restrict__ C, int ldc, int mode,
                       const u16* __restrict__ bia0, const u16* __restrict__ bia1,
                       const u16* __restrict__ bia2, const u16* __restrict__ bia3,
                       const u16* __restrict__ resid, const int* __restrict__ flag) {
    __shared__ __align__(16) u16 Als[128 * 32];
    __shared__ __align__(16) u16 Bls[128 * 32];
    const int m0 = blockIdx.x * 128, n0 = blockIdx.y * 128;
    const int t = threadIdx.x;
    const int wave = t >> 6, lane = t & 63, quad = lane >> 4, l16 = lane & 15;
    const int wm = (wave >> 1) * 64, wn = (wave & 1) * 64;
    const int fp32out = (mode == 2 && flag && *flag) ? 1 : 0;
    f32x4 acc[4][4];
#pragma unroll
    for (int i = 0; i < 4; i++)
#pragma unroll
        for (int j = 0; j < 4; j++) acc[i][j] = (f32x4){0.f, 0.f, 0.f, 0.f};

    for (int ko = 0; ko < K; ko += 32) {
#pragma unroll
        for (int c = t; c < 512; c += 256) {  // 128 rows x 4 chunks of 16B
            int row = c >> 2, kc = c & 3;
            uint4 va = *reinterpret_cast<const uint4*>(A + (size_t)(m0 + row) * lda + ko + kc * 8);
            *reinterpret_cast<uint4*>(&Als[row * 32 + kc * 8]) = va;
            uint4 vb = *reinterpret_cast<const uint4*>(Bt + (size_t)(n0 + row) * K + ko + kc * 8);
            *reinterpret_cast<uint4*>(&Bls[row * 32 + kc * 8]) = vb;
        }
        __syncthreads();
        short8 af[4], bf[4];
#pragma unroll
        for (int mt = 0; mt < 4; mt++)
            af[mt] = *reinterpret_cast<const short8*>(&Als[(wm + mt * 16 + l16) * 32 + quad * 8]);
#pragma unroll
        for (int nt = 0; nt < 4; nt++)
            bf[nt] = *reinterpret_cast<const short8*>(&Bls[(wn + nt * 16 + l16) * 32 + quad * 8]);
#pragma unroll
        for (int mt = 0; mt < 4; mt++)
#pragma unroll
            for (int nt = 0; nt < 4; nt++)
                acc[mt][nt] = __builtin_amdgcn_mfma_f32_16x16x32_bf16(af[mt], bf[nt], acc[mt][nt], 0, 0, 0);
        __syncthreads();
    }
    // epilogue: D row = quad*4 + r, col = l16 within each 16x16 tile
#pragma unroll
    for (int mt = 0; mt < 4; mt++) {
#pragma unroll
        for (int r = 0; r < 4; r++) {
            int row = m0 + wm + mt * 16 + quad * 4 + r;
            if (row >= NN) continue;
#pragma unroll
            for (int nt = 0; nt < 4; nt++) {
                int col = n0 + wn + nt * 16 + l16;
                float v = acc[mt][nt][r];
                if (mode == 0) {
                    int s = col >> 10, cc = col & 1023;
                    const u16* bp = (s == 0) ? bia0 : (s == 1) ? bia1 : (s == 2) ? bia2 : bia3;
                    v += bu2f(bp[cc]);
                    ((u16*)C)[(size_t)row * ldc + col] = f2bu(v);
                } else {
                    v += bu2f(bia0[col]) + bu2f(resid[(size_t)row * D_H + col]);
                    // NaN-preserving relu (matches np.maximum semantics; also keeps
                    // failures visible instead of laundering NaN -> 0)
                    float rr = (v == v) ? fmaxf(v, 0.f) : v;
                    if (fp32out) ((float*)C)[(size_t)row * ldc + col] = rr;
                    else         ((u16*)C)[(size_t)row * ldc + col] = f2bu(rr);
                }
            }
        }
    }
}

// ---------------- fused attention + beta gate + LayerNorm ----------------
// One block per dst node. Online softmax over CSR neighbors, then the block
// (which holds the full 1024-wide o row) applies the beta gate + LayerNorm and
// writes y into the q-slot of qkvs (only this block ever touches row d's q/x_r).
#define CHUNK 64
__global__ void k_attn(u16* __restrict__ qkvs, const int* __restrict__ offs,
                       const int* __restrict__ perm, const int* __restrict__ src,
                       const u16* __restrict__ Wb, const u16* __restrict__ lng,
                       const u16* __restrict__ lnb) {
    int d = blockIdx.x;
    int t = threadIdx.x;
    int hh = t >> 5;  // head of this thread's 4 channels
    int wave = t >> 6, lane = t & 63;
    __shared__ float salpha[CHUNK][N_HEADS];
    __shared__ int ssrc[CHUNK];
    __shared__ float red[8];
    const float scale = 0.0883883476483184f;  // 1/sqrt(128)
    float q0, q1, q2, q3;
    {
        ushort4 qv = *reinterpret_cast<const ushort4*>(qkvs + (size_t)d * QSTRIDE + 4 * t);
        q0 = bu2f(qv.x) * scale; q1 = bu2f(qv.y) * scale;
        q2 = bu2f(qv.z) * scale; q3 = bu2f(qv.w) * scale;
    }
    float a0 = 0.f, a1 = 0.f, a2 = 0.f, a3 = 0.f;
    float mrun = -3.0e38f, lrun = 0.f;
    int beg = offs[d], end = offs[d + 1];
    for (int c0 = beg; c0 < end; c0 += CHUNK) {
        int cn = min(CHUNK, end - c0);
        __syncthreads();
        if (t < cn) ssrc[t] = src[perm[c0 + t]];
        __syncthreads();
        for (int i = 0; i < cn; i++) {
            int s = ssrc[i];
            ushort4 kv = *reinterpret_cast<const ushort4*>(qkvs + (size_t)s * QSTRIDE + D_HC + 4 * t);
            float p = q0 * bu2f(kv.x) + q1 * bu2f(kv.y) + q2 * bu2f(kv.z) + q3 * bu2f(kv.w);
            p += __shfl_xor(p, 16, 64); p += __shfl_xor(p, 8, 64);
            p += __shfl_xor(p, 4, 64);  p += __shfl_xor(p, 2, 64);
            p += __shfl_xor(p, 1, 64);
            if ((t & 31) == 0) salpha[i][hh] = p;
        }
        __syncthreads();
        float cmax = -3.0e38f;
        for (int i = 0; i < cn; i++) cmax = fmaxf(cmax, salpha[i][hh]);
        float mnew = fmaxf(mrun, cmax);
        float resc = __expf(mrun - mnew);
        lrun *= resc; a0 *= resc; a1 *= resc; a2 *= resc; a3 *= resc;
        for (int i = 0; i < cn; i++) {
            float w = __expf(salpha[i][hh] - mnew);
            lrun += w;
            int s = ssrc[i];
            ushort4 vv = *reinterpret_cast<const ushort4*>(qkvs + (size_t)s * QSTRIDE + 2 * D_HC + 4 * t);
            a0 += w * bu2f(vv.x); a1 += w * bu2f(vv.y);
            a2 += w * bu2f(vv.z); a3 += w * bu2f(vv.w);
        }
        mrun = mnew;
    }
    float inv = 1.f / (lrun + 1e-16f);
    float o[4] = {a0 * inv, a1 * inv, a2 * inv, a3 * inv};

    // ---- beta gate + LayerNorm epilogue ----
    ushort4 xv = *reinterpret_cast<const ushort4*>(qkvs + (size_t)d * QSTRIDE + 3 * D_HC + 4 * t);
    float xr[4] = {bu2f(xv.x), bu2f(xv.y), bu2f(xv.z), bu2f(xv.w)};
    ushort4 w1 = *reinterpret_cast<const ushort4*>(Wb + 4 * t);
    ushort4 w2 = *reinterpret_cast<const ushort4*>(Wb + D_HC + 4 * t);
    ushort4 w3 = *reinterpret_cast<const ushort4*>(Wb + 2 * D_HC + 4 * t);
    float part = o[0] * bu2f(w1.x) + o[1] * bu2f(w1.y) + o[2] * bu2f(w1.z) + o[3] * bu2f(w1.w)
               + xr[0] * bu2f(w2.x) + xr[1] * bu2f(w2.y) + xr[2] * bu2f(w2.z) + xr[3] * bu2f(w2.w)
               + (o[0] - xr[0]) * bu2f(w3.x) + (o[1] - xr[1]) * bu2f(w3.y)
               + (o[2] - xr[2]) * bu2f(w3.z) + (o[3] - xr[3]) * bu2f(w3.w);
    part = wred64(part);
    __syncthreads();
    if (lane == 0) red[wave] = part;
    __syncthreads();
    float logit = red[0] + red[1] + red[2] + red[3];
    __syncthreads();
    float beta = 1.f / (1.f + __expf(-logit));
    float g[4], s1 = 0.f, s2 = 0.f;
#pragma unroll
    for (int j = 0; j < 4; j++) {
        g[j] = beta * xr[j] + (1.f - beta) * o[j];
        s1 += g[j]; s2 += g[j] * g[j];
    }
    s1 = wred64(s1); s2 = wred64(s2);
    if (lane == 0) { red[wave] = s1; red[4 + wave] = s2; }
    __syncthreads();
    float mu = (red[0] + red[1] + red[2] + red[3]) * (1.f / 1024.f);
    float var = (red[4] + red[5] + red[6] + red[7]) * (1.f / 1024.f) - mu * mu;
    float rs = rsqrtf(var + 1e-5f);
    ushort4 gv = *reinterpret_cast<const ushort4*>(lng + 4 * t);
    ushort4 bv = *reinterpret_cast<const ushort4*>(lnb + 4 * t);
    ushort4 yo;
    yo.x = f2bu((g[0] - mu) * rs * bu2f(gv.x) + bu2f(bv.x));
    yo.y = f2bu((g[1] - mu) * rs * bu2f(gv.y) + bu2f(bv.y));
    yo.z = f2bu((g[2] - mu) * rs * bu2f(gv.z) + bu2f(bv.z));
    yo.w = f2bu((g[3] - mu) * rs * bu2f(gv.w) + bu2f(bv.w));
    *reinterpret_cast<ushort4*>(qkvs + (size_t)d * QSTRIDE + 4 * t) = yo;
}

// ---------------- host launch ----------------
extern "C" void kernel_launch(void* const* d_in, const int* in_sizes, int n_in,
                              void* d_out, int out_size, void* d_ws, size_t ws_size,
                              hipStream_t stream) {
    const int* ei = (const int*)d_in[1];
    const int* srcI = ei;
    const int* dstI = ei + NE;

    char* w = (char*)d_ws;
    auto carve = [&](size_t bytes) -> char* {
        char* p = w;
        w += (bytes + 255) & ~(size_t)255;
        return p;
    };
    u16* WTq    = (u16*)carve((size_t)N_LAYERS * 4096 * 128 * 2);
    u16* WTp    = (u16*)carve((size_t)N_LAYERS * 128 * 1024 * 2);
    u16* hA     = (u16*)carve((size_t)M_PAD * D_H * 2);
    u16* hB     = (u16*)carve((size_t)M_PAD * D_H * 2);
    u16* qkvs   = (u16*)carve((size_t)M_PAD * QSTRIDE * 2);
    int* cnt    = (int*)carve(2 * NN * 4);
    int* cursor = cnt + NN;
    int* offs   = (int*)carve((NN + 1) * 4);
    int* incl   = (int*)carve(NN * 4);
    int* bsum   = (int*)carve(128 * 4);
    int* bpre   = (int*)carve(128 * 4);
    int* perm   = (int*)carve(NE * 4);
    int* flag   = (int*)carve(256);

    // converted bf16 copies of all float inputs
    const int conv_idx[16]  = {0, 2, 3, 4, 5, 6, 7, 8, 9, 10, 11, 12, 13, 14, 15, 16};
    const int conv_size[16] = {NN * L_IN, L_IN * D_H, D_H,
                               N_LAYERS * D_H * D_HC, N_LAYERS * D_HC,   // Wq bq
                               N_LAYERS * D_H * D_HC, N_LAYERS * D_HC,   // Wk bk
                               N_LAYERS * D_H * D_HC, N_LAYERS * D_HC,   // Wv bv
                               N_LAYERS * D_H * D_HC, N_LAYERS * D_HC,   // Wskip bskip
                               N_LAYERS * 3 * D_HC,                      // Wbeta
                               N_LAYERS * D_HC, N_LAYERS * D_HC,         // ln_g ln_b
                               N_LAYERS * D_HC * D_H, N_LAYERS * D_H};   // Wproj bproj
    u16* conv[16];
    for (int i = 0; i < 16; i++) conv[i] = (u16*)carve((size_t)conv_size[i] * 2);

    k_detect<<<1, 256, 0, stream>>>((const u16*)d_in[0], flag);
    for (int i = 0; i < 16; i++)
        k_convert<<<(conv_size[i] + 255) / 256, 256, 0, stream>>>(d_in[conv_idx[i]], conv[i],
                                                                  conv_size[i], flag);
    const u16* x    = conv[0];
    const u16* Win  = conv[1];
    const u16* b_in = conv[2];
    const u16* Wq   = conv[3];
    const u16* bq   = conv[4];
    const u16* Wk   = conv[5];
    const u16* bk   = conv[6];
    const u16* Wv   = conv[7];
    const u16* bv   = conv[8];
    const u16* Wsk  = conv[9];
    const u16* bsk  = conv[10];
    const u16* Wb   = conv[11];
    const u16* lng  = conv[12];
    const u16* lnb  = conv[13];
    const u16* Wp   = conv[14];
    const u16* bp   = conv[15];

    k_transpose_qkvs<<<(N_LAYERS * 4096 * 128) / 256, 256, 0, stream>>>(Wq, Wk, Wv, Wsk, WTq);
    k_transpose_proj<<<(N_LAYERS * 128 * 1024) / 256, 256, 0, stream>>>(Wp, WTp);
    k_input_proj<<<(NN * D_H) / 256, 256, 0, stream>>>(x, Win, b_in, hA);
    k_zero<<<(2 * NN + 255) / 256, 256, 0, stream>>>(cnt, 2 * NN);
    k_hist<<<(NE + 255) / 256, 256, 0, stream>>>(dstI, cnt);
    const int NB = (NN + 255) / 256;  // 79
    k_scanA<<<NB, 256, 0, stream>>>(cnt, incl, bsum);
    k_scanB<<<1, 64, 0, stream>>>(bsum, bpre, NB);
    k_scanC<<<NB, 256, 0, stream>>>(incl, bpre, offs);
    k_scatter<<<(NE + 255) / 256, 256, 0, stream>>>(dstI, offs, cursor, perm);

    u16* hc = hA;
    u16* hn = hB;
    for (int l = 0; l < N_LAYERS; l++) {
        k_gemm<<<dim3(157, 32), 256, 0, stream>>>(hc, D_H, D_H, WTq + (size_t)l * 4096 * 128,
                                                  qkvs, QSTRIDE, 0,
                                                  bq + l * D_HC, bk + l * D_HC, bv + l * D_HC,
                                                  bsk + l * D_HC, nullptr, flag);
        k_attn<<<NN, 256, 0, stream>>>(qkvs, offs, perm, srcI,
                                       Wb + (size_t)l * 3 * D_HC,
                                       lng + l * D_HC, lnb + l * D_HC);
        int last = (l == N_LAYERS - 1);
        void* outp = last ? d_out : (void*)hn;
        k_gemm<<<dim3(157, 1), 256, 0, stream>>>(qkvs, QSTRIDE, D_HC, WTp + (size_t)l * 128 * 1024,
                                                 outp, D_H, last ? 2 : 1,
                                                 bp + l * D_H, nullptr, nullptr, nullptr, hc, flag);
        u16* tmp = hc; hc = hn; hn = tmp;
    }
}

// Round 5
// 1380.318 us; speedup vs baseline: 1.2520x; 1.2520x over previous
//
#include <hip/hip_runtime.h>
#include <stdint.h>

#define NN 20000
#define NE 160000
#define L_IN 15
#define D_H 128
#define N_HEADS 8
#define D_HC 1024
#define N_LAYERS 6
#define M_PAD 20096   // 157*128 = 314*64
#define QSTRIDE 4096  // q|k|v|x_r interleaved row stride

typedef unsigned short u16;
typedef __attribute__((ext_vector_type(8))) short short8;
typedef __attribute__((ext_vector_type(4))) float f32x4;

__device__ __forceinline__ float bu2f(u16 u) { return __uint_as_float(((unsigned)u) << 16); }
__device__ __forceinline__ u16 f2bu(float f) {
    unsigned x = __float_as_uint(f);
    return (u16)((x + 0x7fffu + ((x >> 16) & 1u)) >> 16);  // RNE
}
__device__ __forceinline__ float wred64(float v) {
#pragma unroll
    for (int m = 32; m >= 1; m >>= 1) v += __shfl_xor(v, m, 64);
    return v;
}
// 16 bf16 (as 2x uint4) -> 16 f32, channel order preserved (little-endian lo first)
__device__ __forceinline__ void cvt16(const uint4& u0, const uint4& u1, float* f) {
    unsigned d[8] = {u0.x, u0.y, u0.z, u0.w, u1.x, u1.y, u1.z, u1.w};
#pragma unroll
    for (int i = 0; i < 8; i++) {
        f[2 * i]     = __uint_as_float(d[i] << 16);
        f[2 * i + 1] = __uint_as_float(d[i] & 0xffff0000u);
    }
}

// ---------------- dtype detection ----------------
__global__ void k_detect(const u16* __restrict__ xb, int* __restrict__ flag) {
    int t = threadIdx.x;  // 256
    u16 u = xb[2 * t];
    int e = (u >> 7) & 0xFF;
    int weird = (e > 150 || (e != 0 && e < 100)) ? 1 : 0;
    __shared__ int cnt;
    if (t == 0) cnt = 0;
    __syncthreads();
    atomicAdd(&cnt, weird);
    __syncthreads();
    if (t == 0) *flag = (cnt > 64) ? 1 : 0;  // 1 = inputs are fp32
}

__global__ void k_convert(const void* __restrict__ in, u16* __restrict__ out, int n,
                          const int* __restrict__ flag) {
    int i = blockIdx.x * 256 + threadIdx.x;
    if (i >= n) return;
    if (*flag) out[i] = f2bu(((const float*)in)[i]);
    else       out[i] = ((const u16*)in)[i];
}

__global__ void k_zero(int* __restrict__ p, int n) {
    int i = blockIdx.x * 256 + threadIdx.x;
    if (i < n) p[i] = 0;
}

// ---------------- weight transposes ----------------
__global__ void k_transpose_qkvs(const u16* __restrict__ Wq, const u16* __restrict__ Wk,
                                 const u16* __restrict__ Wv, const u16* __restrict__ Ws,
                                 u16* __restrict__ WT) {
    int gid = blockIdx.x * 256 + threadIdx.x;  // total L*4096*128
    int l = gid / (4096 * 128);
    int r = gid - l * 4096 * 128;
    int n = r >> 7;
    int kk = r & 127;
    int s = n >> 10, nn = n & 1023;
    const u16* W = (s == 0) ? Wq : (s == 1) ? Wk : (s == 2) ? Wv : Ws;
    WT[gid] = W[(size_t)l * D_H * D_HC + kk * D_HC + nn];
}

__global__ void k_transpose_proj(const u16* __restrict__ Wp, u16* __restrict__ WT) {
    int gid = blockIdx.x * 256 + threadIdx.x;  // total L*128*1024
    int l = gid / (128 * 1024);
    int r = gid - l * 128 * 1024;
    int n = r >> 10;
    int kk = r & 1023;
    WT[gid] = Wp[(size_t)l * D_HC * D_H + kk * D_H + n];
}

// ---------------- input projection ----------------
__global__ void k_input_proj(const u16* __restrict__ x, const u16* __restrict__ Win,
                             const u16* __restrict__ b_in, u16* __restrict__ h) {
    int gid = blockIdx.x * 256 + threadIdx.x;  // NN*128
    int n = gid >> 7, j = gid & 127;
    float acc = bu2f(b_in[j]);
#pragma unroll
    for (int i = 0; i < L_IN; i++) acc += bu2f(x[n * L_IN + i]) * bu2f(Win[i * D_H + j]);
    h[gid] = f2bu(acc);
}

// ---------------- CSR build ----------------
__global__ void k_hist(const int* __restrict__ dst, int* __restrict__ cnt) {
    int e = blockIdx.x * 256 + threadIdx.x;
    if (e < NE) atomicAdd(&cnt[dst[e]], 1);
}
__global__ void k_scanA(const int* __restrict__ cnt, int* __restrict__ incl, int* __restrict__ bsum) {
    __shared__ int s[256];
    int b = blockIdx.x, t = threadIdx.x, i = b * 256 + t;
    int v = (i < NN) ? cnt[i] : 0;
    s[t] = v;
    __syncthreads();
    for (int off = 1; off < 256; off <<= 1) {
        int u = (t >= off) ? s[t - off] : 0;
        __syncthreads();
        s[t] += u;
        __syncthreads();
    }
    if (i < NN) incl[i] = s[t];
    if (t == 255) bsum[b] = s[255];
}
__global__ void k_scanB(const int* __restrict__ bsum, int* __restrict__ bpre, int nb) {
    __shared__ int s[128];
    int t = threadIdx.x;  // 128
    int v = (t < nb) ? bsum[t] : 0;
    s[t] = v;
    __syncthreads();
    for (int off = 1; off < 128; off <<= 1) {
        int u = (t >= off) ? s[t - off] : 0;
        __syncthreads();
        s[t] += u;
        __syncthreads();
    }
    if (t < nb) bpre[t] = s[t] - v;  // exclusive
}
__global__ void k_scanC(const int* __restrict__ incl, const int* __restrict__ bpre, int* __restrict__ offs) {
    int b = blockIdx.x, t = threadIdx.x, i = b * 256 + t;
    if (i < NN) offs[i + 1] = incl[i] + bpre[b];
    if (i == 0) offs[0] = 0;
}
__global__ void k_scatter(const int* __restrict__ dst, const int* __restrict__ offs,
                          int* __restrict__ cursor, int* __restrict__ perm) {
    int e = blockIdx.x * 256 + threadIdx.x;
    if (e < NE) {
        int d = dst[e];
        int p = offs[d] + atomicAdd(&cursor[d], 1);
        perm[p] = e;
    }
}
__global__ void k_gather_src(const int* __restrict__ src, const int* __restrict__ perm,
                             int* __restrict__ srcp) {
    int p = blockIdx.x * 256 + threadIdx.x;
    if (p < NE) srcp[p] = src[perm[p]];
}

// ---------------- MFMA GEMM (QKVS): C[M,4096] = A[M,128] @ Bt^T, bias epilogue ----
// 128x128 tile, BK=32. Epilogue staged through LDS for dwordx4 stores (164 MB/layer).
__global__ void k_gemm(const u16* __restrict__ A, int lda, int K,
                       const u16* __restrict__ Bt,
                       u16* __restrict__ C, int ldc,
                       const u16* __restrict__ bia0, const u16* __restrict__ bia1,
                       const u16* __restrict__ bia2, const u16* __restrict__ bia3) {
    __shared__ __align__(16) u16 smem[128 * 136];  // 34816 B; loop uses first 16 KB
    u16* Als = smem;
    u16* Bls = smem + 4096;
    const int m0 = blockIdx.x * 128, n0 = blockIdx.y * 128;
    const int t = threadIdx.x;
    const int wave = t >> 6, lane = t & 63, quad = lane >> 4, l16 = lane & 15;
    const int wm = (wave >> 1) * 64, wn = (wave & 1) * 64;
    f32x4 acc[4][4];
#pragma unroll
    for (int i = 0; i < 4; i++)
#pragma unroll
        for (int j = 0; j < 4; j++) acc[i][j] = (f32x4){0.f, 0.f, 0.f, 0.f};

    for (int ko = 0; ko < K; ko += 32) {
#pragma unroll
        for (int c = t; c < 512; c += 256) {
            int row = c >> 2, kc = c & 3;
            uint4 va = *reinterpret_cast<const uint4*>(A + (size_t)(m0 + row) * lda + ko + kc * 8);
            *reinterpret_cast<uint4*>(&Als[row * 32 + kc * 8]) = va;
            uint4 vb = *reinterpret_cast<const uint4*>(Bt + (size_t)(n0 + row) * K + ko + kc * 8);
            *reinterpret_cast<uint4*>(&Bls[row * 32 + kc * 8]) = vb;
        }
        __syncthreads();
        short8 af[4], bf[4];
#pragma unroll
        for (int mt = 0; mt < 4; mt++)
            af[mt] = *reinterpret_cast<const short8*>(&Als[(wm + mt * 16 + l16) * 32 + quad * 8]);
#pragma unroll
        for (int nt = 0; nt < 4; nt++)
            bf[nt] = *reinterpret_cast<const short8*>(&Bls[(wn + nt * 16 + l16) * 32 + quad * 8]);
#pragma unroll
        for (int mt = 0; mt < 4; mt++)
#pragma unroll
            for (int nt = 0; nt < 4; nt++)
                acc[mt][nt] = __builtin_amdgcn_mfma_f32_16x16x32_bf16(af[mt], bf[nt], acc[mt][nt], 0, 0, 0);
        __syncthreads();
    }
    // epilogue: bias add, stage bf16 tile in LDS (stride 136 keeps 16B align, 4-way max)
#pragma unroll
    for (int mt = 0; mt < 4; mt++) {
#pragma unroll
        for (int r = 0; r < 4; r++) {
            int rl = wm + mt * 16 + quad * 4 + r;
#pragma unroll
            for (int nt = 0; nt < 4; nt++) {
                int cl = wn + nt * 16 + l16;
                int col = n0 + cl;
                int s = col >> 10, cc = col & 1023;
                const u16* bp = (s == 0) ? bia0 : (s == 1) ? bia1 : (s == 2) ? bia2 : bia3;
                smem[rl * 136 + cl] = f2bu(acc[mt][nt][r] + bu2f(bp[cc]));
            }
        }
    }
    __syncthreads();
#pragma unroll
    for (int c = t; c < 2048; c += 256) {
        int row = c >> 4, kc = c & 15;
        int grow = m0 + row;
        if (grow < NN)
            *reinterpret_cast<uint4*>(C + (size_t)grow * ldc + n0 + kc * 8) =
                *reinterpret_cast<const uint4*>(&smem[row * 136 + kc * 8]);
    }
}

// ---------------- proj GEMM: C[M,128] = A[M,1024] @ Bt^T + bias + resid, relu ----
// 64x128 tiles -> 314 blocks. mode 1: bf16 out; mode 2: out dtype per *flag.
__global__ void k_proj(const u16* __restrict__ A, int lda,
                       const u16* __restrict__ Bt,
                       void* __restrict__ C, int mode,
                       const u16* __restrict__ bias, const u16* __restrict__ resid,
                       const int* __restrict__ flag) {
    __shared__ __align__(16) u16 Als[64 * 32];
    __shared__ __align__(16) u16 Bls[128 * 32];
    const int m0 = blockIdx.x * 64;
    const int t = threadIdx.x;
    const int wave = t >> 6, lane = t & 63, quad = lane >> 4, l16 = lane & 15;
    const int fp32out = (mode == 2 && *flag) ? 1 : 0;
    f32x4 acc[8];
#pragma unroll
    for (int j = 0; j < 8; j++) acc[j] = (f32x4){0.f, 0.f, 0.f, 0.f};

    for (int ko = 0; ko < 1024; ko += 32) {
        {   // A: 64 rows x 4 chunks = 256
            int row = t >> 2, kc = t & 3;
            uint4 va = *reinterpret_cast<const uint4*>(A + (size_t)(m0 + row) * lda + ko + kc * 8);
            *reinterpret_cast<uint4*>(&Als[row * 32 + kc * 8]) = va;
        }
#pragma unroll
        for (int c = t; c < 512; c += 256) {  // B: 128 rows x 4 chunks
            int row = c >> 2, kc = c & 3;
            uint4 vb = *reinterpret_cast<const uint4*>(Bt + (size_t)row * 1024 + ko + kc * 8);
            *reinterpret_cast<uint4*>(&Bls[row * 32 + kc * 8]) = vb;
        }
        __syncthreads();
        short8 af = *reinterpret_cast<const short8*>(&Als[(wave * 16 + l16) * 32 + quad * 8]);
#pragma unroll
        for (int nt = 0; nt < 8; nt++) {
            short8 bf = *reinterpret_cast<const short8*>(&Bls[(nt * 16 + l16) * 32 + quad * 8]);
            acc[nt] = __builtin_amdgcn_mfma_f32_16x16x32_bf16(af, bf, acc[nt], 0, 0, 0);
        }
        __syncthreads();
    }
#pragma unroll
    for (int r = 0; r < 4; r++) {
        int row = m0 + wave * 16 + quad * 4 + r;
        if (row >= NN) continue;
#pragma unroll
        for (int nt = 0; nt < 8; nt++) {
            int col = nt * 16 + l16;
            float v = acc[nt][r] + bu2f(bias[col]) + bu2f(resid[(size_t)row * D_H + col]);
            float rr = (v == v) ? fmaxf(v, 0.f) : v;  // NaN-preserving relu
            if (fp32out) ((float*)C)[(size_t)row * D_H + col] = rr;
            else         ((u16*)C)[(size_t)row * D_H + col] = f2bu(rr);
        }
    }
}

// ---------------- fused attention + beta gate + LayerNorm ----------------
// One block per dst node. Single-pass softmax (no max subtraction: |alpha| is
// O(1) here, exp cannot overflow; partials combine additively across waves).
// Wave w owns edges {w, w+4, ...}; lane covers 16 channels (head = 8 lanes,
// 3-shuffle reduce). No barriers in the edge loop.
__global__ void k_attn(u16* __restrict__ qkvs, const int* __restrict__ offs,
                       const int* __restrict__ srcp,
                       const u16* __restrict__ Wb, const u16* __restrict__ lng,
                       const u16* __restrict__ lnb) {
    int d = blockIdx.x;
    int t = threadIdx.x;
    int wave = t >> 6, lane = t & 63;
    __shared__ int ssrc[256];
    __shared__ float sacc[4 * 1024];
    __shared__ float lsumh[32];  // [wave][head]
    __shared__ float red[8];
    const float scale = 0.0883883476483184f;  // 1/sqrt(128)

    float qf[16];
    {
        const u16* qp = qkvs + (size_t)d * QSTRIDE + 16 * lane;
        uint4 q0 = *reinterpret_cast<const uint4*>(qp);
        uint4 q1 = *reinterpret_cast<const uint4*>(qp + 8);
        cvt16(q0, q1, qf);
#pragma unroll
        for (int j = 0; j < 16; j++) qf[j] *= scale;
    }
    float a[16];
#pragma unroll
    for (int j = 0; j < 16; j++) a[j] = 0.f;
    float lrun = 0.f;

    int beg = offs[d], end = offs[d + 1];
    for (int c0 = beg; c0 < end; c0 += 256) {
        int cn = min(256, end - c0);
        __syncthreads();
        if (t < cn) ssrc[t] = srcp[c0 + t];
        __syncthreads();
        for (int i = wave; i < cn; i += 4) {
            int s = ssrc[i];
            const u16* kp = qkvs + (size_t)s * QSTRIDE + D_HC + 16 * lane;
            uint4 k0 = *reinterpret_cast<const uint4*>(kp);
            uint4 k1 = *reinterpret_cast<const uint4*>(kp + 8);
            uint4 v0 = *reinterpret_cast<const uint4*>(kp + D_HC);
            uint4 v1 = *reinterpret_cast<const uint4*>(kp + D_HC + 8);
            float kf[16];
            cvt16(k0, k1, kf);
            float p = 0.f;
#pragma unroll
            for (int j = 0; j < 16; j++) p += qf[j] * kf[j];
            p += __shfl_xor(p, 1, 64);
            p += __shfl_xor(p, 2, 64);
            p += __shfl_xor(p, 4, 64);
            float w = __expf(p);
            lrun += w;
            float vf[16];
            cvt16(v0, v1, vf);
#pragma unroll
            for (int j = 0; j < 16; j++) a[j] += w * vf[j];
        }
    }
    // combine the 4 waves' partials
    {
        float4* dp = reinterpret_cast<float4*>(&sacc[wave * 1024 + 16 * lane]);
        dp[0] = make_float4(a[0], a[1], a[2], a[3]);
        dp[1] = make_float4(a[4], a[5], a[6], a[7]);
        dp[2] = make_float4(a[8], a[9], a[10], a[11]);
        dp[3] = make_float4(a[12], a[13], a[14], a[15]);
        if ((lane & 7) == 0) lsumh[wave * 8 + (lane >> 3)] = lrun;
    }
    __syncthreads();
    int hh = t >> 5;  // head of channels 4t..4t+3
    float L = lsumh[hh] + lsumh[8 + hh] + lsumh[16 + hh] + lsumh[24 + hh];
    float inv = 1.f / (L + 1e-16f);
    float o[4];
#pragma unroll
    for (int j = 0; j < 4; j++)
        o[j] = (sacc[4 * t + j] + sacc[1024 + 4 * t + j] + sacc[2048 + 4 * t + j] +
                sacc[3072 + 4 * t + j]) * inv;

    // ---- beta gate + LayerNorm ----
    ushort4 xv = *reinterpret_cast<const ushort4*>(qkvs + (size_t)d * QSTRIDE + 3 * D_HC + 4 * t);
    float xr[4] = {bu2f(xv.x), bu2f(xv.y), bu2f(xv.z), bu2f(xv.w)};
    ushort4 w1 = *reinterpret_cast<const ushort4*>(Wb + 4 * t);
    ushort4 w2 = *reinterpret_cast<const ushort4*>(Wb + D_HC + 4 * t);
    ushort4 w3 = *reinterpret_cast<const ushort4*>(Wb + 2 * D_HC + 4 * t);
    float part = o[0] * bu2f(w1.x) + o[1] * bu2f(w1.y) + o[2] * bu2f(w1.z) + o[3] * bu2f(w1.w)
               + xr[0] * bu2f(w2.x) + xr[1] * bu2f(w2.y) + xr[2] * bu2f(w2.z) + xr[3] * bu2f(w2.w)
               + (o[0] - xr[0]) * bu2f(w3.x) + (o[1] - xr[1]) * bu2f(w3.y)
               + (o[2] - xr[2]) * bu2f(w3.z) + (o[3] - xr[3]) * bu2f(w3.w);
    part = wred64(part);
    if (lane == 0) red[wave] = part;
    __syncthreads();
    float logit = red[0] + red[1] + red[2] + red[3];
    __syncthreads();
    float beta = 1.f / (1.f + __expf(-logit));
    float g[4], s1 = 0.f, s2 = 0.f;
#pragma unroll
    for (int j = 0; j < 4; j++) {
        g[j] = beta * xr[j] + (1.f - beta) * o[j];
        s1 += g[j]; s2 += g[j] * g[j];
    }
    s1 = wred64(s1); s2 = wred64(s2);
    if (lane == 0) { red[wave] = s1; red[4 + wave] = s2; }
    __syncthreads();
    float mu = (red[0] + red[1] + red[2] + red[3]) * (1.f / 1024.f);
    float var = (red[4] + red[5] + red[6] + red[7]) * (1.f / 1024.f) - mu * mu;
    float rs = rsqrtf(var + 1e-5f);
    ushort4 gv = *reinterpret_cast<const ushort4*>(lng + 4 * t);
    ushort4 bv = *reinterpret_cast<const ushort4*>(lnb + 4 * t);
    ushort4 yo;
    yo.x = f2bu((g[0] - mu) * rs * bu2f(gv.x) + bu2f(bv.x));
    yo.y = f2bu((g[1] - mu) * rs * bu2f(gv.y) + bu2f(bv.y));
    yo.z = f2bu((g[2] - mu) * rs * bu2f(gv.z) + bu2f(bv.z));
    yo.w = f2bu((g[3] - mu) * rs * bu2f(gv.w) + bu2f(bv.w));
    *reinterpret_cast<ushort4*>(qkvs + (size_t)d * QSTRIDE + 4 * t) = yo;
}

// ---------------- host launch ----------------
extern "C" void kernel_launch(void* const* d_in, const int* in_sizes, int n_in,
                              void* d_out, int out_size, void* d_ws, size_t ws_size,
                              hipStream_t stream) {
    const int* ei = (const int*)d_in[1];
    const int* srcI = ei;
    const int* dstI = ei + NE;

    char* w = (char*)d_ws;
    auto carve = [&](size_t bytes) -> char* {
        char* p = w;
        w += (bytes + 255) & ~(size_t)255;
        return p;
    };
    u16* WTq    = (u16*)carve((size_t)N_LAYERS * 4096 * 128 * 2);
    u16* WTp    = (u16*)carve((size_t)N_LAYERS * 128 * 1024 * 2);
    u16* hA     = (u16*)carve((size_t)M_PAD * D_H * 2);
    u16* hB     = (u16*)carve((size_t)M_PAD * D_H * 2);
    u16* qkvs   = (u16*)carve((size_t)M_PAD * QSTRIDE * 2);
    int* cnt    = (int*)carve(2 * NN * 4);
    int* cursor = cnt + NN;
    int* offs   = (int*)carve((NN + 1) * 4);
    int* incl   = (int*)carve(NN * 4);
    int* bsum   = (int*)carve(128 * 4);
    int* bpre   = (int*)carve(128 * 4);
    int* perm   = (int*)carve(NE * 4);
    int* srcp   = (int*)carve(NE * 4);
    int* flag   = (int*)carve(256);

    const int conv_idx[16]  = {0, 2, 3, 4, 5, 6, 7, 8, 9, 10, 11, 12, 13, 14, 15, 16};
    const int conv_size[16] = {NN * L_IN, L_IN * D_H, D_H,
                               N_LAYERS * D_H * D_HC, N_LAYERS * D_HC,
                               N_LAYERS * D_H * D_HC, N_LAYERS * D_HC,
                               N_LAYERS * D_H * D_HC, N_LAYERS * D_HC,
                               N_LAYERS * D_H * D_HC, N_LAYERS * D_HC,
                               N_LAYERS * 3 * D_HC,
                               N_LAYERS * D_HC, N_LAYERS * D_HC,
                               N_LAYERS * D_HC * D_H, N_LAYERS * D_H};
    u16* conv[16];
    for (int i = 0; i < 16; i++) conv[i] = (u16*)carve((size_t)conv_size[i] * 2);

    k_detect<<<1, 256, 0, stream>>>((const u16*)d_in[0], flag);
    for (int i = 0; i < 16; i++)
        k_convert<<<(conv_size[i] + 255) / 256, 256, 0, stream>>>(d_in[conv_idx[i]], conv[i],
                                                                  conv_size[i], flag);
    const u16* x    = conv[0];
    const u16* Win  = conv[1];
    const u16* b_in = conv[2];
    const u16* Wq   = conv[3];
    const u16* bq   = conv[4];
    const u16* Wk   = conv[5];
    const u16* bk   = conv[6];
    const u16* Wv   = conv[7];
    const u16* bv   = conv[8];
    const u16* Wsk  = conv[9];
    const u16* bsk  = conv[10];
    const u16* Wb   = conv[11];
    const u16* lng  = conv[12];
    const u16* lnb  = conv[13];
    const u16* Wp   = conv[14];
    const u16* bp   = conv[15];

    k_transpose_qkvs<<<(N_LAYERS * 4096 * 128) / 256, 256, 0, stream>>>(Wq, Wk, Wv, Wsk, WTq);
    k_transpose_proj<<<(N_LAYERS * 128 * 1024) / 256, 256, 0, stream>>>(Wp, WTp);
    k_input_proj<<<(NN * D_H) / 256, 256, 0, stream>>>(x, Win, b_in, hA);
    k_zero<<<(2 * NN + 255) / 256, 256, 0, stream>>>(cnt, 2 * NN);
    k_hist<<<(NE + 255) / 256, 256, 0, stream>>>(dstI, cnt);
    const int NB = (NN + 255) / 256;  // 79
    k_scanA<<<NB, 256, 0, stream>>>(cnt, incl, bsum);
    k_scanB<<<1, 128, 0, stream>>>(bsum, bpre, NB);
    k_scanC<<<NB, 256, 0, stream>>>(incl, bpre, offs);
    k_scatter<<<(NE + 255) / 256, 256, 0, stream>>>(dstI, offs, cursor, perm);
    k_gather_src<<<(NE + 255) / 256, 256, 0, stream>>>(srcI, perm, srcp);

    u16* hc = hA;
    u16* hn = hB;
    for (int l = 0; l < N_LAYERS; l++) {
        k_gemm<<<dim3(157, 32), 256, 0, stream>>>(hc, D_H, D_H, WTq + (size_t)l * 4096 * 128,
                                                  qkvs, QSTRIDE,
                                                  bq + l * D_HC, bk + l * D_HC, bv + l * D_HC,
                                                  bsk + l * D_HC);
        k_attn<<<NN, 256, 0, stream>>>(qkvs, offs, srcp,
                                       Wb + (size_t)l * 3 * D_HC,
                                       lng + l * D_HC, lnb + l * D_HC);
        int last = (l == N_LAYERS - 1);
        void* outp = last ? d_out : (void*)hn;
        k_proj<<<314, 256, 0, stream>>>(qkvs, QSTRIDE, WTp + (size_t)l * 128 * 1024,
                                        outp, last ? 2 : 1,
                                        bp + l * D_H, hc, flag);
        u16* tmp = hc; hc = hn; hn = tmp;
    }
}

// Round 6
// 1376.456 us; speedup vs baseline: 1.2555x; 1.0028x over previous
//
#include <hip/hip_runtime.h>
#include <stdint.h>

#define NN 20000
#define NE 160000
#define L_IN 15
#define D_H 128
#define N_HEADS 8
#define D_HC 1024
#define N_LAYERS 6
#define M_PAD 20096   // 157*128 = 314*64
#define QSTRIDE 4096  // q|k|v|x_r interleaved row stride

typedef unsigned short u16;
typedef __attribute__((ext_vector_type(8))) short short8;
typedef __attribute__((ext_vector_type(4))) float f32x4;

__device__ __forceinline__ float bu2f(u16 u) { return __uint_as_float(((unsigned)u) << 16); }
__device__ __forceinline__ u16 f2bu(float f) {
    unsigned x = __float_as_uint(f);
    return (u16)((x + 0x7fffu + ((x >> 16) & 1u)) >> 16);  // RNE
}
__device__ __forceinline__ float wred64(float v) {
#pragma unroll
    for (int m = 32; m >= 1; m >>= 1) v += __shfl_xor(v, m, 64);
    return v;
}
// 16 bf16 (as 2x uint4) -> 16 f32, channel order preserved
__device__ __forceinline__ void cvt16(const uint4& u0, const uint4& u1, float* f) {
    unsigned d[8] = {u0.x, u0.y, u0.z, u0.w, u1.x, u1.y, u1.z, u1.w};
#pragma unroll
    for (int i = 0; i < 8; i++) {
        f[2 * i]     = __uint_as_float(d[i] << 16);
        f[2 * i + 1] = __uint_as_float(d[i] & 0xffff0000u);
    }
}

// ---------------- dtype detection ----------------
__global__ void k_detect(const u16* __restrict__ xb, int* __restrict__ flag) {
    int t = threadIdx.x;  // 256
    u16 u = xb[2 * t];
    int e = (u >> 7) & 0xFF;
    int weird = (e > 150 || (e != 0 && e < 100)) ? 1 : 0;
    __shared__ int cnt;
    if (t == 0) cnt = 0;
    __syncthreads();
    atomicAdd(&cnt, weird);
    __syncthreads();
    if (t == 0) *flag = (cnt > 64) ? 1 : 0;  // 1 = inputs are fp32
}

__global__ void k_convert(const void* __restrict__ in, u16* __restrict__ out, int n,
                          const int* __restrict__ flag) {
    int i = blockIdx.x * 256 + threadIdx.x;
    if (i >= n) return;
    if (*flag) out[i] = f2bu(((const float*)in)[i]);
    else       out[i] = ((const u16*)in)[i];
}

__global__ void k_zero(int* __restrict__ p, int n) {
    int i = blockIdx.x * 256 + threadIdx.x;
    if (i < n) p[i] = 0;
}

// ------------- fused convert + transpose (coalesced read AND write) -------------
// Wq/Wk/Wv/Ws: [l][128 k][1024 n] (fp32 or bf16 per flag) -> WT [l][4096 n][128 k] bf16
// grid (2, 64, 6) = (tk, tn, l), 256 threads, 64x64 tile via padded LDS.
__global__ void k_convT_qkvs(const void* __restrict__ Wq, const void* __restrict__ Wk,
                             const void* __restrict__ Wv, const void* __restrict__ Ws,
                             u16* __restrict__ WT, const int* __restrict__ flag) {
    __shared__ u16 tile[64][66];
    int tk = blockIdx.x, tn = blockIdx.y, l = blockIdx.z;
    int t = threadIdx.x;
    int s = (tn * 64) >> 10, nn0 = (tn * 64) & 1023;
    const void* W = (s == 0) ? Wq : (s == 1) ? Wk : (s == 2) ? Wv : Ws;
    int r = t >> 2, c0 = (t & 3) * 16;
    size_t base = (size_t)l * 128 * 1024 + (size_t)(tk * 64 + r) * 1024 + nn0 + c0;
    if (*flag) {
        const float* Wf = (const float*)W;
#pragma unroll
        for (int cc = 0; cc < 16; cc++) tile[c0 + cc][r] = f2bu(Wf[base + cc]);
    } else {
        const u16* Wh = (const u16*)W;
#pragma unroll
        for (int cc = 0; cc < 16; cc++) tile[c0 + cc][r] = Wh[base + cc];
    }
    __syncthreads();
    int i = t >> 2, j0 = (t & 3) * 16;
    u16* dst = WT + ((size_t)l * 4096 + tn * 64 + i) * 128 + tk * 64 + j0;
#pragma unroll
    for (int jj = 0; jj < 16; jj++) dst[jj] = tile[i][j0 + jj];
}

// Wp: [l][1024 k][128 n] -> WT [l][128 n][1024 k] bf16. grid (16, 2, 6).
__global__ void k_convT_proj(const void* __restrict__ Wp, u16* __restrict__ WT,
                             const int* __restrict__ flag) {
    __shared__ u16 tile[64][66];
    int tk = blockIdx.x, tn = blockIdx.y, l = blockIdx.z;
    int t = threadIdx.x;
    int r = t >> 2, c0 = (t & 3) * 16;
    size_t base = (size_t)l * 1024 * 128 + (size_t)(tk * 64 + r) * 128 + tn * 64 + c0;
    if (*flag) {
        const float* Wf = (const float*)Wp;
#pragma unroll
        for (int cc = 0; cc < 16; cc++) tile[c0 + cc][r] = f2bu(Wf[base + cc]);
    } else {
        const u16* Wh = (const u16*)Wp;
#pragma unroll
        for (int cc = 0; cc < 16; cc++) tile[c0 + cc][r] = Wh[base + cc];
    }
    __syncthreads();
    int i = t >> 2, j0 = (t & 3) * 16;
    u16* dst = WT + ((size_t)l * 128 + tn * 64 + i) * 1024 + tk * 64 + j0;
#pragma unroll
    for (int jj = 0; jj < 16; jj++) dst[jj] = tile[i][j0 + jj];
}

// ---------------- input projection ----------------
__global__ void k_input_proj(const u16* __restrict__ x, const u16* __restrict__ Win,
                             const u16* __restrict__ b_in, u16* __restrict__ h) {
    int gid = blockIdx.x * 256 + threadIdx.x;  // NN*128
    int n = gid >> 7, j = gid & 127;
    float acc = bu2f(b_in[j]);
#pragma unroll
    for (int i = 0; i < L_IN; i++) acc += bu2f(x[n * L_IN + i]) * bu2f(Win[i * D_H + j]);
    h[gid] = f2bu(acc);
}

// ---------------- CSR build ----------------
__global__ void k_hist(const int* __restrict__ dst, int* __restrict__ cnt) {
    int e = blockIdx.x * 256 + threadIdx.x;
    if (e < NE) atomicAdd(&cnt[dst[e]], 1);
}
__global__ void k_scanA(const int* __restrict__ cnt, int* __restrict__ incl, int* __restrict__ bsum) {
    __shared__ int s[256];
    int b = blockIdx.x, t = threadIdx.x, i = b * 256 + t;
    int v = (i < NN) ? cnt[i] : 0;
    s[t] = v;
    __syncthreads();
    for (int off = 1; off < 256; off <<= 1) {
        int u = (t >= off) ? s[t - off] : 0;
        __syncthreads();
        s[t] += u;
        __syncthreads();
    }
    if (i < NN) incl[i] = s[t];
    if (t == 255) bsum[b] = s[255];
}
__global__ void k_scanB(const int* __restrict__ bsum, int* __restrict__ bpre, int nb) {
    __shared__ int s[128];
    int t = threadIdx.x;  // 128
    int v = (t < nb) ? bsum[t] : 0;
    s[t] = v;
    __syncthreads();
    for (int off = 1; off < 128; off <<= 1) {
        int u = (t >= off) ? s[t - off] : 0;
        __syncthreads();
        s[t] += u;
        __syncthreads();
    }
    if (t < nb) bpre[t] = s[t] - v;  // exclusive
}
__global__ void k_scanC(const int* __restrict__ incl, const int* __restrict__ bpre, int* __restrict__ offs) {
    int b = blockIdx.x, t = threadIdx.x, i = b * 256 + t;
    if (i < NN) offs[i + 1] = incl[i] + bpre[b];
    if (i == 0) offs[0] = 0;
}
__global__ void k_scatter(const int* __restrict__ dst, const int* __restrict__ offs,
                          int* __restrict__ cursor, int* __restrict__ perm) {
    int e = blockIdx.x * 256 + threadIdx.x;
    if (e < NE) {
        int d = dst[e];
        int p = offs[d] + atomicAdd(&cursor[d], 1);
        perm[p] = e;
    }
}
__global__ void k_gather_src(const int* __restrict__ src, const int* __restrict__ perm,
                             int* __restrict__ srcp) {
    int p = blockIdx.x * 256 + threadIdx.x;
    if (p < NE) srcp[p] = src[perm[p]];
}

// ---------------- MFMA GEMM (QKVS) ----------------
__global__ void k_gemm(const u16* __restrict__ A, int lda, int K,
                       const u16* __restrict__ Bt,
                       u16* __restrict__ C, int ldc,
                       const u16* __restrict__ bia0, const u16* __restrict__ bia1,
                       const u16* __restrict__ bia2, const u16* __restrict__ bia3) {
    __shared__ __align__(16) u16 smem[128 * 136];
    u16* Als = smem;
    u16* Bls = smem + 4096;
    const int m0 = blockIdx.x * 128, n0 = blockIdx.y * 128;
    const int t = threadIdx.x;
    const int wave = t >> 6, lane = t & 63, quad = lane >> 4, l16 = lane & 15;
    const int wm = (wave >> 1) * 64, wn = (wave & 1) * 64;
    f32x4 acc[4][4];
#pragma unroll
    for (int i = 0; i < 4; i++)
#pragma unroll
        for (int j = 0; j < 4; j++) acc[i][j] = (f32x4){0.f, 0.f, 0.f, 0.f};

    for (int ko = 0; ko < K; ko += 32) {
#pragma unroll
        for (int c = t; c < 512; c += 256) {
            int row = c >> 2, kc = c & 3;
            uint4 va = *reinterpret_cast<const uint4*>(A + (size_t)(m0 + row) * lda + ko + kc * 8);
            *reinterpret_cast<uint4*>(&Als[row * 32 + kc * 8]) = va;
            uint4 vb = *reinterpret_cast<const uint4*>(Bt + (size_t)(n0 + row) * K + ko + kc * 8);
            *reinterpret_cast<uint4*>(&Bls[row * 32 + kc * 8]) = vb;
        }
        __syncthreads();
        short8 af[4], bf[4];
#pragma unroll
        for (int mt = 0; mt < 4; mt++)
            af[mt] = *reinterpret_cast<const short8*>(&Als[(wm + mt * 16 + l16) * 32 + quad * 8]);
#pragma unroll
        for (int nt = 0; nt < 4; nt++)
            bf[nt] = *reinterpret_cast<const short8*>(&Bls[(wn + nt * 16 + l16) * 32 + quad * 8]);
#pragma unroll
        for (int mt = 0; mt < 4; mt++)
#pragma unroll
            for (int nt = 0; nt < 4; nt++)
                acc[mt][nt] = __builtin_amdgcn_mfma_f32_16x16x32_bf16(af[mt], bf[nt], acc[mt][nt], 0, 0, 0);
        __syncthreads();
    }
#pragma unroll
    for (int mt = 0; mt < 4; mt++) {
#pragma unroll
        for (int r = 0; r < 4; r++) {
            int rl = wm + mt * 16 + quad * 4 + r;
#pragma unroll
            for (int nt = 0; nt < 4; nt++) {
                int cl = wn + nt * 16 + l16;
                int col = n0 + cl;
                int s = col >> 10, cc = col & 1023;
                const u16* bp = (s == 0) ? bia0 : (s == 1) ? bia1 : (s == 2) ? bia2 : bia3;
                smem[rl * 136 + cl] = f2bu(acc[mt][nt][r] + bu2f(bp[cc]));
            }
        }
    }
    __syncthreads();
#pragma unroll
    for (int c = t; c < 2048; c += 256) {
        int row = c >> 4, kc = c & 15;
        int grow = m0 + row;
        if (grow < NN)
            *reinterpret_cast<uint4*>(C + (size_t)grow * ldc + n0 + kc * 8) =
                *reinterpret_cast<const uint4*>(&smem[row * 136 + kc * 8]);
    }
}

// ---------------- proj GEMM ----------------
__global__ void k_proj(const u16* __restrict__ A, int lda,
                       const u16* __restrict__ Bt,
                       void* __restrict__ C, int mode,
                       const u16* __restrict__ bias, const u16* __restrict__ resid,
                       const int* __restrict__ flag) {
    __shared__ __align__(16) u16 Als[64 * 32];
    __shared__ __align__(16) u16 Bls[128 * 32];
    const int m0 = blockIdx.x * 64;
    const int t = threadIdx.x;
    const int wave = t >> 6, lane = t & 63, quad = lane >> 4, l16 = lane & 15;
    const int fp32out = (mode == 2 && *flag) ? 1 : 0;
    f32x4 acc[8];
#pragma unroll
    for (int j = 0; j < 8; j++) acc[j] = (f32x4){0.f, 0.f, 0.f, 0.f};

    for (int ko = 0; ko < 1024; ko += 32) {
        {
            int row = t >> 2, kc = t & 3;
            uint4 va = *reinterpret_cast<const uint4*>(A + (size_t)(m0 + row) * lda + ko + kc * 8);
            *reinterpret_cast<uint4*>(&Als[row * 32 + kc * 8]) = va;
        }
#pragma unroll
        for (int c = t; c < 512; c += 256) {
            int row = c >> 2, kc = c & 3;
            uint4 vb = *reinterpret_cast<const uint4*>(Bt + (size_t)row * 1024 + ko + kc * 8);
            *reinterpret_cast<uint4*>(&Bls[row * 32 + kc * 8]) = vb;
        }
        __syncthreads();
        short8 af = *reinterpret_cast<const short8*>(&Als[(wave * 16 + l16) * 32 + quad * 8]);
#pragma unroll
        for (int nt = 0; nt < 8; nt++) {
            short8 bf = *reinterpret_cast<const short8*>(&Bls[(nt * 16 + l16) * 32 + quad * 8]);
            acc[nt] = __builtin_amdgcn_mfma_f32_16x16x32_bf16(af, bf, acc[nt], 0, 0, 0);
        }
        __syncthreads();
    }
#pragma unroll
    for (int r = 0; r < 4; r++) {
        int row = m0 + wave * 16 + quad * 4 + r;
        if (row >= NN) continue;
#pragma unroll
        for (int nt = 0; nt < 8; nt++) {
            int col = nt * 16 + l16;
            float v = acc[nt][r] + bu2f(bias[col]) + bu2f(resid[(size_t)row * D_H + col]);
            float rr = (v == v) ? fmaxf(v, 0.f) : v;
            if (fp32out) ((float*)C)[(size_t)row * D_H + col] = rr;
            else         ((u16*)C)[(size_t)row * D_H + col] = f2bu(rr);
        }
    }
}

// ---------------- fused attention + beta gate + LayerNorm: ONE WAVE PER NODE ----
// Lane covers 16 channels. Per edge, all 64 lanes co-load the contiguous 4 KB
// k|v span of the source node. Head dot = 3 shuffles over the head's 8 lanes;
// after the reduce every lane of the head holds the full weight w, so the
// softmax denominator needs no further reduction. No LDS, no __syncthreads.
__global__ void k_attn(u16* __restrict__ qkvs, const int* __restrict__ offs,
                       const int* __restrict__ srcp,
                       const u16* __restrict__ Wb, const u16* __restrict__ lng,
                       const u16* __restrict__ lnb) {
    int d = (blockIdx.x * 256 + threadIdx.x) >> 6;
    int lane = threadIdx.x & 63;
    if (d >= NN) return;
    const float scale = 0.0883883476483184f;  // 1/sqrt(128)

    const u16* qp = qkvs + (size_t)d * QSTRIDE + 16 * lane;
    float qf[16];
    {
        uint4 q0 = *reinterpret_cast<const uint4*>(qp);
        uint4 q1 = *reinterpret_cast<const uint4*>(qp + 8);
        cvt16(q0, q1, qf);
#pragma unroll
        for (int j = 0; j < 16; j++) qf[j] *= scale;
    }
    float a[16];
#pragma unroll
    for (int j = 0; j < 16; j++) a[j] = 0.f;
    float lrun = 0.f;

    int beg = offs[d], end = offs[d + 1];
    for (int c0 = beg; c0 < end; c0 += 64) {
        int cn = min(64, end - c0);
        int myidx = (c0 + lane < end) ? srcp[c0 + lane] : 0;
        for (int i = 0; i < cn; i++) {
            int s = __shfl(myidx, i, 64);
            const u16* kp = qkvs + (size_t)s * QSTRIDE + D_HC + 16 * lane;
            uint4 k0 = *reinterpret_cast<const uint4*>(kp);
            uint4 k1 = *reinterpret_cast<const uint4*>(kp + 8);
            uint4 v0 = *reinterpret_cast<const uint4*>(kp + D_HC);
            uint4 v1 = *reinterpret_cast<const uint4*>(kp + D_HC + 8);
            float kf[16];
            cvt16(k0, k1, kf);
            float p = 0.f;
#pragma unroll
            for (int j = 0; j < 16; j++) p += qf[j] * kf[j];
            p += __shfl_xor(p, 1, 64);
            p += __shfl_xor(p, 2, 64);
            p += __shfl_xor(p, 4, 64);
            float w = __expf(p);
            lrun += w;
            float vf[16];
            cvt16(v0, v1, vf);
#pragma unroll
            for (int j = 0; j < 16; j++) a[j] += w * vf[j];
        }
    }
    float inv = 1.f / (lrun + 1e-16f);
    float o[16];
#pragma unroll
    for (int j = 0; j < 16; j++) o[j] = a[j] * inv;

    // ---- beta gate ----
    float xr[16];
    {
        const u16* xp = qkvs + (size_t)d * QSTRIDE + 3 * D_HC + 16 * lane;
        uint4 x0 = *reinterpret_cast<const uint4*>(xp);
        uint4 x1 = *reinterpret_cast<const uint4*>(xp + 8);
        cvt16(x0, x1, xr);
    }
    float part = 0.f;
    {
        const u16* wp = Wb + 16 * lane;
        uint4 u0 = *reinterpret_cast<const uint4*>(wp);
        uint4 u1 = *reinterpret_cast<const uint4*>(wp + 8);
        float wf[16];
        cvt16(u0, u1, wf);
#pragma unroll
        for (int j = 0; j < 16; j++) part += o[j] * wf[j];
        u0 = *reinterpret_cast<const uint4*>(wp + D_HC);
        u1 = *reinterpret_cast<const uint4*>(wp + D_HC + 8);
        cvt16(u0, u1, wf);
#pragma unroll
        for (int j = 0; j < 16; j++) part += xr[j] * wf[j];
        u0 = *reinterpret_cast<const uint4*>(wp + 2 * D_HC);
        u1 = *reinterpret_cast<const uint4*>(wp + 2 * D_HC + 8);
        cvt16(u0, u1, wf);
#pragma unroll
        for (int j = 0; j < 16; j++) part += (o[j] - xr[j]) * wf[j];
    }
    float logit = wred64(part);
    float beta = 1.f / (1.f + __expf(-logit));

    float g[16], s1 = 0.f, s2 = 0.f;
#pragma unroll
    for (int j = 0; j < 16; j++) {
        g[j] = beta * xr[j] + (1.f - beta) * o[j];
        s1 += g[j]; s2 += g[j] * g[j];
    }
    s1 = wred64(s1);
    s2 = wred64(s2);
    float mu = s1 * (1.f / 1024.f);
    float var = s2 * (1.f / 1024.f) - mu * mu;
    float rs = rsqrtf(var + 1e-5f);

    // ---- LayerNorm + write y into q slot ----
    {
        const u16* gp = lng + 16 * lane;
        const u16* bp2 = lnb + 16 * lane;
        uint4 g0 = *reinterpret_cast<const uint4*>(gp);
        uint4 g1 = *reinterpret_cast<const uint4*>(gp + 8);
        uint4 b0 = *reinterpret_cast<const uint4*>(bp2);
        uint4 b1 = *reinterpret_cast<const uint4*>(bp2 + 8);
        float lgf[16], lbf[16];
        cvt16(g0, g1, lgf);
        cvt16(b0, b1, lbf);
        unsigned out[8];
#pragma unroll
        for (int j = 0; j < 8; j++) {
            float y0 = (g[2 * j] - mu) * rs * lgf[2 * j] + lbf[2 * j];
            float y1 = (g[2 * j + 1] - mu) * rs * lgf[2 * j + 1] + lbf[2 * j + 1];
            out[j] = (unsigned)f2bu(y0) | ((unsigned)f2bu(y1) << 16);
        }
        uint4* op = reinterpret_cast<uint4*>(const_cast<u16*>(qp));
        op[0] = make_uint4(out[0], out[1], out[2], out[3]);
        op[1] = make_uint4(out[4], out[5], out[6], out[7]);
    }
}

// ---------------- host launch ----------------
extern "C" void kernel_launch(void* const* d_in, const int* in_sizes, int n_in,
                              void* d_out, int out_size, void* d_ws, size_t ws_size,
                              hipStream_t stream) {
    const int* ei = (const int*)d_in[1];
    const int* srcI = ei;
    const int* dstI = ei + NE;

    char* w = (char*)d_ws;
    auto carve = [&](size_t bytes) -> char* {
        char* p = w;
        w += (bytes + 255) & ~(size_t)255;
        return p;
    };
    u16* WTq    = (u16*)carve((size_t)N_LAYERS * 4096 * 128 * 2);
    u16* WTp    = (u16*)carve((size_t)N_LAYERS * 128 * 1024 * 2);
    u16* hA     = (u16*)carve((size_t)M_PAD * D_H * 2);
    u16* hB     = (u16*)carve((size_t)M_PAD * D_H * 2);
    u16* qkvs   = (u16*)carve((size_t)M_PAD * QSTRIDE * 2);
    int* cnt    = (int*)carve(2 * NN * 4);
    int* cursor = cnt + NN;
    int* offs   = (int*)carve((NN + 1) * 4);
    int* incl   = (int*)carve(NN * 4);
    int* bsum   = (int*)carve(128 * 4);
    int* bpre   = (int*)carve(128 * 4);
    int* perm   = (int*)carve(NE * 4);
    int* srcp   = (int*)carve(NE * 4);
    int* flag   = (int*)carve(256);

    // small arrays converted to bf16 (weights go through fused convert-transpose)
    const int conv_idx[11]  = {0, 2, 3, 5, 7, 9, 11, 12, 13, 14, 16};
    const int conv_size[11] = {NN * L_IN, L_IN * D_H, D_H,
                               N_LAYERS * D_HC, N_LAYERS * D_HC, N_LAYERS * D_HC,
                               N_LAYERS * D_HC,
                               N_LAYERS * 3 * D_HC,
                               N_LAYERS * D_HC, N_LAYERS * D_HC,
                               N_LAYERS * D_H};
    u16* conv[11];
    for (int i = 0; i < 11; i++) conv[i] = (u16*)carve((size_t)conv_size[i] * 2);

    k_detect<<<1, 256, 0, stream>>>((const u16*)d_in[0], flag);
    for (int i = 0; i < 11; i++)
        k_convert<<<(conv_size[i] + 255) / 256, 256, 0, stream>>>(d_in[conv_idx[i]], conv[i],
                                                                  conv_size[i], flag);
    const u16* x    = conv[0];
    const u16* Win  = conv[1];
    const u16* b_in = conv[2];
    const u16* bq   = conv[3];
    const u16* bk   = conv[4];
    const u16* bv   = conv[5];
    const u16* bsk  = conv[6];
    const u16* Wb   = conv[7];
    const u16* lng  = conv[8];
    const u16* lnb  = conv[9];
    const u16* bp   = conv[10];

    k_convT_qkvs<<<dim3(2, 64, 6), 256, 0, stream>>>(d_in[4], d_in[6], d_in[8], d_in[10],
                                                     WTq, flag);
    k_convT_proj<<<dim3(16, 2, 6), 256, 0, stream>>>(d_in[15], WTp, flag);
    k_input_proj<<<(NN * D_H) / 256, 256, 0, stream>>>(x, Win, b_in, hA);
    k_zero<<<(2 * NN + 255) / 256, 256, 0, stream>>>(cnt, 2 * NN);
    k_hist<<<(NE + 255) / 256, 256, 0, stream>>>(dstI, cnt);
    const int NB = (NN + 255) / 256;  // 79
    k_scanA<<<NB, 256, 0, stream>>>(cnt, incl, bsum);
    k_scanB<<<1, 128, 0, stream>>>(bsum, bpre, NB);
    k_scanC<<<NB, 256, 0, stream>>>(incl, bpre, offs);
    k_scatter<<<(NE + 255) / 256, 256, 0, stream>>>(dstI, offs, cursor, perm);
    k_gather_src<<<(NE + 255) / 256, 256, 0, stream>>>(srcI, perm, srcp);

    u16* hc = hA;
    u16* hn = hB;
    for (int l = 0; l < N_LAYERS; l++) {
        k_gemm<<<dim3(157, 32), 256, 0, stream>>>(hc, D_H, D_H, WTq + (size_t)l * 4096 * 128,
                                                  qkvs, QSTRIDE,
                                                  bq + l * D_HC, bk + l * D_HC, bv + l * D_HC,
                                                  bsk + l * D_HC);
        k_attn<<<(NN * 64 + 255) / 256, 256, 0, stream>>>(qkvs, offs, srcp,
                                                          Wb + (size_t)l * 3 * D_HC,
                                                          lng + l * D_HC, lnb + l * D_HC);
        int last = (l == N_LAYERS - 1);
        void* outp = last ? d_out : (void*)hn;
        k_proj<<<314, 256, 0, stream>>>(qkvs, QSTRIDE, WTp + (size_t)l * 128 * 1024,
                                        outp, last ? 2 : 1,
                                        bp + l * D_H, hc, flag);
        u16* tmp = hc; hc = hn; hn = tmp;
    }
}

// Round 7
// 1259.999 us; speedup vs baseline: 1.3715x; 1.0924x over previous
//
#include <hip/hip_runtime.h>
#include <stdint.h>

#define NN 20000
#define NE 160000
#define L_IN 15
#define D_H 128
#define N_HEADS 8
#define D_HC 1024
#define N_LAYERS 6
#define M_PAD 20096   // 157*128 = 314*64
#define QSTRIDE 4096  // q|k|v|x_r interleaved row stride

typedef unsigned short u16;
typedef __attribute__((ext_vector_type(8))) short short8;
typedef __attribute__((ext_vector_type(4))) float f32x4;

__device__ __forceinline__ float bu2f(u16 u) { return __uint_as_float(((unsigned)u) << 16); }
__device__ __forceinline__ u16 f2bu(float f) {
    unsigned x = __float_as_uint(f);
    return (u16)((x + 0x7fffu + ((x >> 16) & 1u)) >> 16);  // RNE
}
__device__ __forceinline__ float wred64(float v) {
#pragma unroll
    for (int m = 32; m >= 1; m >>= 1) v += __shfl_xor(v, m, 64);
    return v;
}
// 16 bf16 (as 2x uint4) -> 16 f32, channel order preserved
__device__ __forceinline__ void cvt16(const uint4& u0, const uint4& u1, float* f) {
    unsigned d[8] = {u0.x, u0.y, u0.z, u0.w, u1.x, u1.y, u1.z, u1.w};
#pragma unroll
    for (int i = 0; i < 8; i++) {
        f[2 * i]     = __uint_as_float(d[i] << 16);
        f[2 * i + 1] = __uint_as_float(d[i] & 0xffff0000u);
    }
}

// ---------------- dtype detection ----------------
__global__ void k_detect(const u16* __restrict__ xb, int* __restrict__ flag) {
    int t = threadIdx.x;  // 256
    u16 u = xb[2 * t];
    int e = (u >> 7) & 0xFF;
    int weird = (e > 150 || (e != 0 && e < 100)) ? 1 : 0;
    __shared__ int cnt;
    if (t == 0) cnt = 0;
    __syncthreads();
    atomicAdd(&cnt, weird);
    __syncthreads();
    if (t == 0) *flag = (cnt > 64) ? 1 : 0;  // 1 = inputs are fp32
}

// ---------------- fused convert of all small float inputs (one launch) ----------
struct CvDesc { const void* in[11]; u16* out[11]; };
#define CV_TOTAL 358112
__global__ void k_convert_all(CvDesc dsc, const int* __restrict__ flag) {
    const int sizes[11] = {NN * L_IN, L_IN * D_H, D_H,
                           N_LAYERS * D_HC, N_LAYERS * D_HC, N_LAYERS * D_HC,
                           N_LAYERS * D_HC, N_LAYERS * 3 * D_HC,
                           N_LAYERS * D_HC, N_LAYERS * D_HC, N_LAYERS * D_H};
    int off = blockIdx.x * 256 + threadIdx.x;
    if (off >= CV_TOTAL) return;
    int seg = 0;
#pragma unroll
    for (int s = 0; s < 11; s++) {
        if (off >= sizes[s] && seg == s) { off -= sizes[s]; seg = s + 1; }
    }
    if (*flag) dsc.out[seg][off] = f2bu(((const float*)dsc.in[seg])[off]);
    else       dsc.out[seg][off] = ((const u16*)dsc.in[seg])[off];
}

__global__ void k_zero(int* __restrict__ p, int n) {
    int i = blockIdx.x * 256 + threadIdx.x;
    if (i < n) p[i] = 0;
}

// ------------- fused convert + transpose (coalesced read AND write) -------------
__global__ void k_convT_qkvs(const void* __restrict__ Wq, const void* __restrict__ Wk,
                             const void* __restrict__ Wv, const void* __restrict__ Ws,
                             u16* __restrict__ WT, const int* __restrict__ flag) {
    __shared__ u16 tile[64][66];
    int tk = blockIdx.x, tn = blockIdx.y, l = blockIdx.z;
    int t = threadIdx.x;
    int s = (tn * 64) >> 10, nn0 = (tn * 64) & 1023;
    const void* W = (s == 0) ? Wq : (s == 1) ? Wk : (s == 2) ? Wv : Ws;
    int r = t >> 2, c0 = (t & 3) * 16;
    size_t base = (size_t)l * 128 * 1024 + (size_t)(tk * 64 + r) * 1024 + nn0 + c0;
    if (*flag) {
        const float* Wf = (const float*)W;
#pragma unroll
        for (int cc = 0; cc < 16; cc++) tile[c0 + cc][r] = f2bu(Wf[base + cc]);
    } else {
        const u16* Wh = (const u16*)W;
#pragma unroll
        for (int cc = 0; cc < 16; cc++) tile[c0 + cc][r] = Wh[base + cc];
    }
    __syncthreads();
    int i = t >> 2, j0 = (t & 3) * 16;
    u16* dst = WT + ((size_t)l * 4096 + tn * 64 + i) * 128 + tk * 64 + j0;
#pragma unroll
    for (int jj = 0; jj < 16; jj++) dst[jj] = tile[i][j0 + jj];
}

__global__ void k_convT_proj(const void* __restrict__ Wp, u16* __restrict__ WT,
                             const int* __restrict__ flag) {
    __shared__ u16 tile[64][66];
    int tk = blockIdx.x, tn = blockIdx.y, l = blockIdx.z;
    int t = threadIdx.x;
    int r = t >> 2, c0 = (t & 3) * 16;
    size_t base = (size_t)l * 1024 * 128 + (size_t)(tk * 64 + r) * 128 + tn * 64 + c0;
    if (*flag) {
        const float* Wf = (const float*)Wp;
#pragma unroll
        for (int cc = 0; cc < 16; cc++) tile[c0 + cc][r] = f2bu(Wf[base + cc]);
    } else {
        const u16* Wh = (const u16*)Wp;
#pragma unroll
        for (int cc = 0; cc < 16; cc++) tile[c0 + cc][r] = Wh[base + cc];
    }
    __syncthreads();
    int i = t >> 2, j0 = (t & 3) * 16;
    u16* dst = WT + ((size_t)l * 128 + tn * 64 + i) * 1024 + tk * 64 + j0;
#pragma unroll
    for (int jj = 0; jj < 16; jj++) dst[jj] = tile[i][j0 + jj];
}

// ---------------- input projection ----------------
__global__ void k_input_proj(const u16* __restrict__ x, const u16* __restrict__ Win,
                             const u16* __restrict__ b_in, u16* __restrict__ h) {
    int gid = blockIdx.x * 256 + threadIdx.x;  // NN*128
    int n = gid >> 7, j = gid & 127;
    float acc = bu2f(b_in[j]);
#pragma unroll
    for (int i = 0; i < L_IN; i++) acc += bu2f(x[n * L_IN + i]) * bu2f(Win[i * D_H + j]);
    h[gid] = f2bu(acc);
}

// ---------------- CSR build ----------------
__global__ void k_hist(const int* __restrict__ dst, int* __restrict__ cnt) {
    int e = blockIdx.x * 256 + threadIdx.x;
    if (e < NE) atomicAdd(&cnt[dst[e]], 1);
}
__global__ void k_scanA(const int* __restrict__ cnt, int* __restrict__ incl, int* __restrict__ bsum) {
    __shared__ int s[256];
    int b = blockIdx.x, t = threadIdx.x, i = b * 256 + t;
    int v = (i < NN) ? cnt[i] : 0;
    s[t] = v;
    __syncthreads();
    for (int off = 1; off < 256; off <<= 1) {
        int u = (t >= off) ? s[t - off] : 0;
        __syncthreads();
        s[t] += u;
        __syncthreads();
    }
    if (i < NN) incl[i] = s[t];
    if (t == 255) bsum[b] = s[255];
}
__global__ void k_scanB(const int* __restrict__ bsum, int* __restrict__ bpre, int nb) {
    __shared__ int s[128];
    int t = threadIdx.x;  // 128
    int v = (t < nb) ? bsum[t] : 0;
    s[t] = v;
    __syncthreads();
    for (int off = 1; off < 128; off <<= 1) {
        int u = (t >= off) ? s[t - off] : 0;
        __syncthreads();
        s[t] += u;
        __syncthreads();
    }
    if (t < nb) bpre[t] = s[t] - v;  // exclusive
}
__global__ void k_scanC(const int* __restrict__ incl, const int* __restrict__ bpre, int* __restrict__ offs) {
    int b = blockIdx.x, t = threadIdx.x, i = b * 256 + t;
    if (i < NN) offs[i + 1] = incl[i] + bpre[b];
    if (i == 0) offs[0] = 0;
}
// scatter edge e to its CSR slot; writes src id directly (perm eliminated)
__global__ void k_scatter(const int* __restrict__ dst, const int* __restrict__ src,
                          const int* __restrict__ offs, int* __restrict__ cursor,
                          int* __restrict__ srcp) {
    int e = blockIdx.x * 256 + threadIdx.x;
    if (e < NE) {
        int d = dst[e];
        int p = offs[d] + atomicAdd(&cursor[d], 1);
        srcp[p] = src[e];
    }
}

// ---------------- MFMA GEMM (QKVS) ----------------
// grid dim3(32 n, 157 m): consecutive blocks share the A m-tile -> L2 reuse.
__global__ void k_gemm(const u16* __restrict__ A, int lda, int K,
                       const u16* __restrict__ Bt,
                       u16* __restrict__ C, int ldc,
                       const u16* __restrict__ bia0, const u16* __restrict__ bia1,
                       const u16* __restrict__ bia2, const u16* __restrict__ bia3) {
    __shared__ __align__(16) u16 smem[128 * 136];
    u16* Als = smem;
    u16* Bls = smem + 4096;
    const int m0 = blockIdx.y * 128, n0 = blockIdx.x * 128;
    const int t = threadIdx.x;
    const int wave = t >> 6, lane = t & 63, quad = lane >> 4, l16 = lane & 15;
    const int wm = (wave >> 1) * 64, wn = (wave & 1) * 64;
    f32x4 acc[4][4];
#pragma unroll
    for (int i = 0; i < 4; i++)
#pragma unroll
        for (int j = 0; j < 4; j++) acc[i][j] = (f32x4){0.f, 0.f, 0.f, 0.f};

    for (int ko = 0; ko < K; ko += 32) {
#pragma unroll
        for (int c = t; c < 512; c += 256) {
            int row = c >> 2, kc = c & 3;
            uint4 va = *reinterpret_cast<const uint4*>(A + (size_t)(m0 + row) * lda + ko + kc * 8);
            *reinterpret_cast<uint4*>(&Als[row * 32 + kc * 8]) = va;
            uint4 vb = *reinterpret_cast<const uint4*>(Bt + (size_t)(n0 + row) * K + ko + kc * 8);
            *reinterpret_cast<uint4*>(&Bls[row * 32 + kc * 8]) = vb;
        }
        __syncthreads();
        short8 af[4], bf[4];
#pragma unroll
        for (int mt = 0; mt < 4; mt++)
            af[mt] = *reinterpret_cast<const short8*>(&Als[(wm + mt * 16 + l16) * 32 + quad * 8]);
#pragma unroll
        for (int nt = 0; nt < 4; nt++)
            bf[nt] = *reinterpret_cast<const short8*>(&Bls[(wn + nt * 16 + l16) * 32 + quad * 8]);
#pragma unroll
        for (int mt = 0; mt < 4; mt++)
#pragma unroll
            for (int nt = 0; nt < 4; nt++)
                acc[mt][nt] = __builtin_amdgcn_mfma_f32_16x16x32_bf16(af[mt], bf[nt], acc[mt][nt], 0, 0, 0);
        __syncthreads();
    }
#pragma unroll
    for (int mt = 0; mt < 4; mt++) {
#pragma unroll
        for (int r = 0; r < 4; r++) {
            int rl = wm + mt * 16 + quad * 4 + r;
#pragma unroll
            for (int nt = 0; nt < 4; nt++) {
                int cl = wn + nt * 16 + l16;
                int col = n0 + cl;
                int s = col >> 10, cc = col & 1023;
                const u16* bp = (s == 0) ? bia0 : (s == 1) ? bia1 : (s == 2) ? bia2 : bia3;
                smem[rl * 136 + cl] = f2bu(acc[mt][nt][r] + bu2f(bp[cc]));
            }
        }
    }
    __syncthreads();
#pragma unroll
    for (int c = t; c < 2048; c += 256) {
        int row = c >> 4, kc = c & 15;
        int grow = m0 + row;
        if (grow < NN)
            *reinterpret_cast<uint4*>(C + (size_t)grow * ldc + n0 + kc * 8) =
                *reinterpret_cast<const uint4*>(&smem[row * 136 + kc * 8]);
    }
}

// ---------------- proj GEMM ----------------
__global__ void k_proj(const u16* __restrict__ A, int lda,
                       const u16* __restrict__ Bt,
                       void* __restrict__ C, int mode,
                       const u16* __restrict__ bias, const u16* __restrict__ resid,
                       const int* __restrict__ flag) {
    __shared__ __align__(16) u16 Als[64 * 32];
    __shared__ __align__(16) u16 Bls[128 * 32];
    const int m0 = blockIdx.x * 64;
    const int t = threadIdx.x;
    const int wave = t >> 6, lane = t & 63, quad = lane >> 4, l16 = lane & 15;
    const int fp32out = (mode == 2 && *flag) ? 1 : 0;
    f32x4 acc[8];
#pragma unroll
    for (int j = 0; j < 8; j++) acc[j] = (f32x4){0.f, 0.f, 0.f, 0.f};

    for (int ko = 0; ko < 1024; ko += 32) {
        {
            int row = t >> 2, kc = t & 3;
            uint4 va = *reinterpret_cast<const uint4*>(A + (size_t)(m0 + row) * lda + ko + kc * 8);
            *reinterpret_cast<uint4*>(&Als[row * 32 + kc * 8]) = va;
        }
#pragma unroll
        for (int c = t; c < 512; c += 256) {
            int row = c >> 2, kc = c & 3;
            uint4 vb = *reinterpret_cast<const uint4*>(Bt + (size_t)row * 1024 + ko + kc * 8);
            *reinterpret_cast<uint4*>(&Bls[row * 32 + kc * 8]) = vb;
        }
        __syncthreads();
        short8 af = *reinterpret_cast<const short8*>(&Als[(wave * 16 + l16) * 32 + quad * 8]);
#pragma unroll
        for (int nt = 0; nt < 8; nt++) {
            short8 bf = *reinterpret_cast<const short8*>(&Bls[(nt * 16 + l16) * 32 + quad * 8]);
            acc[nt] = __builtin_amdgcn_mfma_f32_16x16x32_bf16(af, bf, acc[nt], 0, 0, 0);
        }
        __syncthreads();
    }
#pragma unroll
    for (int r = 0; r < 4; r++) {
        int row = m0 + wave * 16 + quad * 4 + r;
        if (row >= NN) continue;
#pragma unroll
        for (int nt = 0; nt < 8; nt++) {
            int col = nt * 16 + l16;
            float v = acc[nt][r] + bu2f(bias[col]) + bu2f(resid[(size_t)row * D_H + col]);
            float rr = (v == v) ? fmaxf(v, 0.f) : v;
            if (fp32out) ((float*)C)[(size_t)row * D_H + col] = rr;
            else         ((u16*)C)[(size_t)row * D_H + col] = f2bu(rr);
        }
    }
}

// ---------------- fused attention + beta gate + LayerNorm: ONE WAVE PER NODE ----
// 2-deep software pipeline: edge i+1's k|v loads are issued before edge i's
// compute consumes its (already in-flight) loads, so two edges' 4 KB are
// outstanding at all times -> ~2x memory-level parallelism vs round 6.
__global__ void k_attn(u16* __restrict__ qkvs, const int* __restrict__ offs,
                       const int* __restrict__ srcp,
                       const u16* __restrict__ Wb, const u16* __restrict__ lng,
                       const u16* __restrict__ lnb) {
    int d = (blockIdx.x * 256 + threadIdx.x) >> 6;
    int lane = threadIdx.x & 63;
    if (d >= NN) return;
    const float scale = 0.0883883476483184f;  // 1/sqrt(128)

    const u16* qp = qkvs + (size_t)d * QSTRIDE + 16 * lane;
    uint4 q0r = *reinterpret_cast<const uint4*>(qp);
    uint4 q1r = *reinterpret_cast<const uint4*>(qp + 8);
    // hoist xr load: in flight during the edge loop
    const u16* xp = qkvs + (size_t)d * QSTRIDE + 3 * D_HC + 16 * lane;
    uint4 x0r = *reinterpret_cast<const uint4*>(xp);
    uint4 x1r = *reinterpret_cast<const uint4*>(xp + 8);

    float qf[16];
    cvt16(q0r, q1r, qf);
#pragma unroll
    for (int j = 0; j < 16; j++) qf[j] *= scale;

    float a[16];
#pragma unroll
    for (int j = 0; j < 16; j++) a[j] = 0.f;
    float lrun = 0.f;

    int beg = offs[d], end = offs[d + 1];
    for (int c0 = beg; c0 < end; c0 += 64) {
        int cn = min(64, end - c0);
        int myidx = (c0 + lane < end) ? srcp[c0 + lane] : 0;
        // prime edge 0
        int s = __shfl(myidx, 0, 64);
        const u16* kp = qkvs + (size_t)s * QSTRIDE + D_HC + 16 * lane;
        uint4 k0 = *reinterpret_cast<const uint4*>(kp);
        uint4 k1 = *reinterpret_cast<const uint4*>(kp + 8);
        uint4 v0 = *reinterpret_cast<const uint4*>(kp + D_HC);
        uint4 v1 = *reinterpret_cast<const uint4*>(kp + D_HC + 8);
        for (int i = 0; i < cn; i++) {
            uint4 nk0 = k0, nk1 = k1, nv0 = v0, nv1 = v1;
            if (i + 1 < cn) {
                int sn = __shfl(myidx, i + 1, 64);
                const u16* kpn = qkvs + (size_t)sn * QSTRIDE + D_HC + 16 * lane;
                nk0 = *reinterpret_cast<const uint4*>(kpn);
                nk1 = *reinterpret_cast<const uint4*>(kpn + 8);
                nv0 = *reinterpret_cast<const uint4*>(kpn + D_HC);
                nv1 = *reinterpret_cast<const uint4*>(kpn + D_HC + 8);
            }
            float kf[16];
            cvt16(k0, k1, kf);
            float p = 0.f;
#pragma unroll
            for (int j = 0; j < 16; j++) p += qf[j] * kf[j];
            p += __shfl_xor(p, 1, 64);
            p += __shfl_xor(p, 2, 64);
            p += __shfl_xor(p, 4, 64);
            float w = __expf(p);
            lrun += w;
            float vf[16];
            cvt16(v0, v1, vf);
#pragma unroll
            for (int j = 0; j < 16; j++) a[j] += w * vf[j];
            k0 = nk0; k1 = nk1; v0 = nv0; v1 = nv1;
        }
    }
    float inv = 1.f / (lrun + 1e-16f);
    float o[16];
#pragma unroll
    for (int j = 0; j < 16; j++) o[j] = a[j] * inv;

    // ---- beta gate ----
    float xr[16];
    cvt16(x0r, x1r, xr);
    float part = 0.f;
    {
        const u16* wp = Wb + 16 * lane;
        uint4 u0 = *reinterpret_cast<const uint4*>(wp);
        uint4 u1 = *reinterpret_cast<const uint4*>(wp + 8);
        float wf[16];
        cvt16(u0, u1, wf);
#pragma unroll
        for (int j = 0; j < 16; j++) part += o[j] * wf[j];
        u0 = *reinterpret_cast<const uint4*>(wp + D_HC);
        u1 = *reinterpret_cast<const uint4*>(wp + D_HC + 8);
        cvt16(u0, u1, wf);
#pragma unroll
        for (int j = 0; j < 16; j++) part += xr[j] * wf[j];
        u0 = *reinterpret_cast<const uint4*>(wp + 2 * D_HC);
        u1 = *reinterpret_cast<const uint4*>(wp + 2 * D_HC + 8);
        cvt16(u0, u1, wf);
#pragma unroll
        for (int j = 0; j < 16; j++) part += (o[j] - xr[j]) * wf[j];
    }
    float logit = wred64(part);
    float beta = 1.f / (1.f + __expf(-logit));

    float g[16], s1 = 0.f, s2 = 0.f;
#pragma unroll
    for (int j = 0; j < 16; j++) {
        g[j] = beta * xr[j] + (1.f - beta) * o[j];
        s1 += g[j]; s2 += g[j] * g[j];
    }
    s1 = wred64(s1);
    s2 = wred64(s2);
    float mu = s1 * (1.f / 1024.f);
    float var = s2 * (1.f / 1024.f) - mu * mu;
    float rs = rsqrtf(var + 1e-5f);

    {
        const u16* gp = lng + 16 * lane;
        const u16* bp2 = lnb + 16 * lane;
        uint4 g0 = *reinterpret_cast<const uint4*>(gp);
        uint4 g1 = *reinterpret_cast<const uint4*>(gp + 8);
        uint4 b0 = *reinterpret_cast<const uint4*>(bp2);
        uint4 b1 = *reinterpret_cast<const uint4*>(bp2 + 8);
        float lgf[16], lbf[16];
        cvt16(g0, g1, lgf);
        cvt16(b0, b1, lbf);
        unsigned out[8];
#pragma unroll
        for (int j = 0; j < 8; j++) {
            float y0 = (g[2 * j] - mu) * rs * lgf[2 * j] + lbf[2 * j];
            float y1 = (g[2 * j + 1] - mu) * rs * lgf[2 * j + 1] + lbf[2 * j + 1];
            out[j] = (unsigned)f2bu(y0) | ((unsigned)f2bu(y1) << 16);
        }
        uint4* op = reinterpret_cast<uint4*>(const_cast<u16*>(qp));
        op[0] = make_uint4(out[0], out[1], out[2], out[3]);
        op[1] = make_uint4(out[4], out[5], out[6], out[7]);
    }
}

// ---------------- host launch ----------------
extern "C" void kernel_launch(void* const* d_in, const int* in_sizes, int n_in,
                              void* d_out, int out_size, void* d_ws, size_t ws_size,
                              hipStream_t stream) {
    const int* ei = (const int*)d_in[1];
    const int* srcI = ei;
    const int* dstI = ei + NE;

    char* w = (char*)d_ws;
    auto carve = [&](size_t bytes) -> char* {
        char* p = w;
        w += (bytes + 255) & ~(size_t)255;
        return p;
    };
    u16* WTq    = (u16*)carve((size_t)N_LAYERS * 4096 * 128 * 2);
    u16* WTp    = (u16*)carve((size_t)N_LAYERS * 128 * 1024 * 2);
    u16* hA     = (u16*)carve((size_t)M_PAD * D_H * 2);
    u16* hB     = (u16*)carve((size_t)M_PAD * D_H * 2);
    u16* qkvs   = (u16*)carve((size_t)M_PAD * QSTRIDE * 2);
    int* cnt    = (int*)carve(2 * NN * 4);
    int* cursor = cnt + NN;
    int* offs   = (int*)carve((NN + 1) * 4);
    int* incl   = (int*)carve(NN * 4);
    int* bsum   = (int*)carve(128 * 4);
    int* bpre   = (int*)carve(128 * 4);
    int* srcp   = (int*)carve(NE * 4);
    int* flag   = (int*)carve(256);

    const int conv_size[11] = {NN * L_IN, L_IN * D_H, D_H,
                               N_LAYERS * D_HC, N_LAYERS * D_HC, N_LAYERS * D_HC,
                               N_LAYERS * D_HC,
                               N_LAYERS * 3 * D_HC,
                               N_LAYERS * D_HC, N_LAYERS * D_HC,
                               N_LAYERS * D_H};
    const int conv_idx[11] = {0, 2, 3, 5, 7, 9, 11, 12, 13, 14, 16};
    CvDesc dsc;
    u16* conv[11];
    for (int i = 0; i < 11; i++) {
        conv[i] = (u16*)carve((size_t)conv_size[i] * 2);
        dsc.in[i] = d_in[conv_idx[i]];
        dsc.out[i] = conv[i];
    }

    k_detect<<<1, 256, 0, stream>>>((const u16*)d_in[0], flag);
    k_convert_all<<<(CV_TOTAL + 255) / 256, 256, 0, stream>>>(dsc, flag);
    const u16* x    = conv[0];
    const u16* Win  = conv[1];
    const u16* b_in = conv[2];
    const u16* bq   = conv[3];
    const u16* bk   = conv[4];
    const u16* bv   = conv[5];
    const u16* bsk  = conv[6];
    const u16* Wb   = conv[7];
    const u16* lng  = conv[8];
    const u16* lnb  = conv[9];
    const u16* bp   = conv[10];

    k_convT_qkvs<<<dim3(2, 64, 6), 256, 0, stream>>>(d_in[4], d_in[6], d_in[8], d_in[10],
                                                     WTq, flag);
    k_convT_proj<<<dim3(16, 2, 6), 256, 0, stream>>>(d_in[15], WTp, flag);
    k_input_proj<<<(NN * D_H) / 256, 256, 0, stream>>>(x, Win, b_in, hA);
    k_zero<<<(2 * NN + 255) / 256, 256, 0, stream>>>(cnt, 2 * NN);
    k_hist<<<(NE + 255) / 256, 256, 0, stream>>>(dstI, cnt);
    const int NB = (NN + 255) / 256;  // 79
    k_scanA<<<NB, 256, 0, stream>>>(cnt, incl, bsum);
    k_scanB<<<1, 128, 0, stream>>>(bsum, bpre, NB);
    k_scanC<<<NB, 256, 0, stream>>>(incl, bpre, offs);
    k_scatter<<<(NE + 255) / 256, 256, 0, stream>>>(dstI, srcI, offs, cursor, srcp);

    u16* hc = hA;
    u16* hn = hB;
    for (int l = 0; l < N_LAYERS; l++) {
        k_gemm<<<dim3(32, 157), 256, 0, stream>>>(hc, D_H, D_H, WTq + (size_t)l * 4096 * 128,
                                                  qkvs, QSTRIDE,
                                                  bq + l * D_HC, bk + l * D_HC, bv + l * D_HC,
                                                  bsk + l * D_HC);
        k_attn<<<(NN * 64 + 255) / 256, 256, 0, stream>>>(qkvs, offs, srcp,
                                                          Wb + (size_t)l * 3 * D_HC,
                                                          lng + l * D_HC, lnb + l * D_HC);
        int last = (l == N_LAYERS - 1);
        void* outp = last ? d_out : (void*)hn;
        k_proj<<<314, 256, 0, stream>>>(qkvs, QSTRIDE, WTp + (size_t)l * 128 * 1024,
                                        outp, last ? 2 : 1,
                                        bp + l * D_H, hc, flag);
        u16* tmp = hc; hc = hn; hn = tmp;
    }
}

// Round 9
// 1016.593 us; speedup vs baseline: 1.6999x; 1.2394x over previous
//
#include <hip/hip_runtime.h>
#include <stdint.h>

#define NN 20000
#define NE 160000
#define L_IN 15
#define D_H 128
#define N_HEADS 8
#define D_HC 1024
#define N_LAYERS 6
#define M_PAD 20096   // 157*128
#define QS2 2048      // zd|x_r interleaved row stride (u,y overwrite zd slot)

typedef unsigned short u16;
typedef __attribute__((ext_vector_type(8))) short short8;
typedef __attribute__((ext_vector_type(4))) float f32x4;

#define RSQRT_D 0.08838834764831845f  // 1/sqrt(128)

__device__ __forceinline__ float bu2f(u16 u) { return __uint_as_float(((unsigned)u) << 16); }
__device__ __forceinline__ u16 f2bu(float f) {
    unsigned x = __float_as_uint(f);
    return (u16)((x + 0x7fffu + ((x >> 16) & 1u)) >> 16);  // RNE
}
__device__ __forceinline__ float wred64(float v) {
#pragma unroll
    for (int m = 32; m >= 1; m >>= 1) v += __shfl_xor(v, m, 64);
    return v;
}
__device__ __forceinline__ void cvt16(const uint4& u0, const uint4& u1, float* f) {
    unsigned d[8] = {u0.x, u0.y, u0.z, u0.w, u1.x, u1.y, u1.z, u1.w};
#pragma unroll
    for (int i = 0; i < 8; i++) {
        f[2 * i]     = __uint_as_float(d[i] << 16);
        f[2 * i + 1] = __uint_as_float(d[i] & 0xffff0000u);
    }
}

// ---------------- dtype detection ----------------
__global__ void k_detect(const u16* __restrict__ xb, int* __restrict__ flag) {
    int t = threadIdx.x;
    u16 u = xb[2 * t];
    int e = (u >> 7) & 0xFF;
    int weird = (e > 150 || (e != 0 && e < 100)) ? 1 : 0;
    __shared__ int cnt;
    if (t == 0) cnt = 0;
    __syncthreads();
    atomicAdd(&cnt, weird);
    __syncthreads();
    if (t == 0) *flag = (cnt > 64) ? 1 : 0;  // 1 = inputs are fp32
}

// ---------------- fused convert (13 segments incl. Wq, Wk) ----------------
struct CvDesc { const void* in[13]; u16* out[13]; };
#define CV_TOTAL 1930976
__global__ void k_convert_all(CvDesc dsc, const int* __restrict__ flag) {
    const int sizes[13] = {NN * L_IN, L_IN * D_H, D_H,
                           N_LAYERS * D_HC, N_LAYERS * D_HC, N_LAYERS * D_HC,
                           N_LAYERS * D_HC, N_LAYERS * 3 * D_HC,
                           N_LAYERS * D_HC, N_LAYERS * D_HC, N_LAYERS * D_H,
                           N_LAYERS * D_H * D_HC, N_LAYERS * D_H * D_HC};
    int off = blockIdx.x * 256 + threadIdx.x;
    if (off >= CV_TOTAL) return;
    int seg = 0;
#pragma unroll
    for (int s = 0; s < 13; s++) {
        if (off >= sizes[s] && seg == s) { off -= sizes[s]; seg = s + 1; }
    }
    if (*flag) dsc.out[seg][off] = f2bu(((const float*)dsc.in[seg])[off]);
    else       dsc.out[seg][off] = ((const u16*)dsc.in[seg])[off];
}

__global__ void k_zero(int* __restrict__ p, int n) {
    int i = blockIdx.x * 256 + threadIdx.x;
    if (i < n) p[i] = 0;
}

// ------------- convert+transpose: Wv -> WvT, Wskip -> Bmain rows 1024.. ------
__global__ void k_convT_vs(const void* __restrict__ Wv, const void* __restrict__ Ws,
                           u16* __restrict__ WvT, u16* __restrict__ Bmain,
                           const int* __restrict__ flag) {
    __shared__ u16 tile[64][66];
    int tk = blockIdx.x, tn = blockIdx.y, l = blockIdx.z;
    int t = threadIdx.x;
    int isv = (tn < 16);
    const void* W = isv ? Wv : Ws;
    int n_off = (tn & 15) * 64;
    int r = t >> 2, c0 = (t & 3) * 16;
    size_t base = (size_t)l * 128 * 1024 + (size_t)(tk * 64 + r) * 1024 + n_off + c0;
    if (*flag) {
        const float* Wf = (const float*)W;
#pragma unroll
        for (int cc = 0; cc < 16; cc++) tile[c0 + cc][r] = f2bu(Wf[base + cc]);
    } else {
        const u16* Wh = (const u16*)W;
#pragma unroll
        for (int cc = 0; cc < 16; cc++) tile[c0 + cc][r] = Wh[base + cc];
    }
    __syncthreads();
    int i = t >> 2, j0 = (t & 3) * 16;
    u16* dst = isv ? (WvT + ((size_t)l * 1024 + n_off + i) * 128 + tk * 64 + j0)
                   : (Bmain + ((size_t)l * 2048 + 1024 + n_off + i) * 128 + tk * 64 + j0);
#pragma unroll
    for (int jj = 0; jj < 16; jj++) dst[jj] = tile[i][j0 + jj];
}

// Wp: [l][1024 k][128 n] -> WTp [l][128 n][1024 k]. grid (16, 2, 6).
__global__ void k_convT_proj(const void* __restrict__ Wp, u16* __restrict__ WT,
                             const int* __restrict__ flag) {
    __shared__ u16 tile[64][66];
    int tk = blockIdx.x, tn = blockIdx.y, l = blockIdx.z;
    int t = threadIdx.x;
    int r = t >> 2, c0 = (t & 3) * 16;
    size_t base = (size_t)l * 1024 * 128 + (size_t)(tk * 64 + r) * 128 + tn * 64 + c0;
    if (*flag) {
        const float* Wf = (const float*)Wp;
#pragma unroll
        for (int cc = 0; cc < 16; cc++) tile[c0 + cc][r] = f2bu(Wf[base + cc]);
    } else {
        const u16* Wh = (const u16*)Wp;
#pragma unroll
        for (int cc = 0; cc < 16; cc++) tile[c0 + cc][r] = Wh[base + cc];
    }
    __syncthreads();
    int i = t >> 2, j0 = (t & 3) * 16;
    u16* dst = WT + ((size_t)l * 128 + tn * 64 + i) * 1024 + tk * 64 + j0;
#pragma unroll
    for (int jj = 0; jj < 16; jj++) dst[jj] = tile[i][j0 + jj];
}

// ---------------- GG precompute: Bmain rows 0-1023 = (Wq_h Wk_h^T)^T / sqrt(d) --
__global__ void k_GG(const u16* __restrict__ Wqb, const u16* __restrict__ Wkb,
                     u16* __restrict__ Bmain) {
    int h = blockIdx.x, l = blockIdx.y;
    __shared__ __align__(16) u16 Als[128 * 32];
    __shared__ __align__(16) u16 Bls[128 * 32];
    const int t = threadIdx.x;
    const int wave = t >> 6, lane = t & 63, quad = lane >> 4, l16 = lane & 15;
    const int wm = (wave >> 1) * 64, wn = (wave & 1) * 64;
    const u16* Ab = Wqb + (size_t)l * 128 * 1024 + h * 128;
    const u16* Bb = Wkb + (size_t)l * 128 * 1024 + h * 128;
    f32x4 acc[4][4];
#pragma unroll
    for (int i = 0; i < 4; i++)
#pragma unroll
        for (int j = 0; j < 4; j++) acc[i][j] = (f32x4){0.f, 0.f, 0.f, 0.f};
    for (int ko = 0; ko < 128; ko += 32) {
#pragma unroll
        for (int c = t; c < 512; c += 256) {
            int row = c >> 2, kc = c & 3;
            *reinterpret_cast<uint4*>(&Als[row * 32 + kc * 8]) =
                *reinterpret_cast<const uint4*>(Ab + (size_t)row * 1024 + ko + kc * 8);
            *reinterpret_cast<uint4*>(&Bls[row * 32 + kc * 8]) =
                *reinterpret_cast<const uint4*>(Bb + (size_t)row * 1024 + ko + kc * 8);
        }
        __syncthreads();
        short8 af[4], bf[4];
#pragma unroll
        for (int mt = 0; mt < 4; mt++)
            af[mt] = *reinterpret_cast<const short8*>(&Als[(wm + mt * 16 + l16) * 32 + quad * 8]);
#pragma unroll
        for (int nt = 0; nt < 4; nt++)
            bf[nt] = *reinterpret_cast<const short8*>(&Bls[(wn + nt * 16 + l16) * 32 + quad * 8]);
#pragma unroll
        for (int mt = 0; mt < 4; mt++)
#pragma unroll
            for (int nt = 0; nt < 4; nt++)
                acc[mt][nt] = __builtin_amdgcn_mfma_f32_16x16x32_bf16(af[mt], bf[nt], acc[mt][nt], 0, 0, 0);
        __syncthreads();
    }
    u16* dst = Bmain + (size_t)l * 2048 * 128;
#pragma unroll
    for (int mt = 0; mt < 4; mt++)
#pragma unroll
        for (int r = 0; r < 4; r++) {
            int row = wm + mt * 16 + quad * 4 + r;  // a
#pragma unroll
            for (int nt = 0; nt < 4; nt++) {
                int col = wn + nt * 16 + l16;       // b
                dst[(size_t)(h * 128 + col) * 128 + row] = f2bu(acc[mt][nt][r] * RSQRT_D);
            }
        }
}

// ---------------- small precompute: cb, wsc, csc ----------------
__global__ void k_pre_small(const u16* __restrict__ Wqb, const u16* __restrict__ Wkb,
                            const u16* __restrict__ bq, const u16* __restrict__ bk,
                            u16* __restrict__ cb, float* __restrict__ wsc,
                            float* __restrict__ csc) {
    int gid = blockIdx.x * 256 + threadIdx.x;  // 6*2056
    if (gid >= N_LAYERS * 2056) return;
    int l = gid / 2056, r = gid % 2056;
    float acc = 0.f;
    if (r < 1024) {  // cb[l][h*128+b] = sum_m bq[hm]*Wk[b,hm] / sqrt(d)
        int h = r >> 7, b = r & 127;
        const u16* bqp = bq + l * D_HC + h * 128;
        const u16* wkp = Wkb + (size_t)l * 128 * 1024 + (size_t)b * 1024 + h * 128;
        for (int m = 0; m < 128; m++) acc += bu2f(bqp[m]) * bu2f(wkp[m]);
        cb[l * 1024 + r] = f2bu(acc * RSQRT_D);
    } else if (r < 2048) {  // wsc[l][a*8+h] = sum_m Wq[a,hm]*bk[hm] / sqrt(d)
        int a = (r - 1024) >> 3, h = (r - 1024) & 7;
        const u16* wqp = Wqb + (size_t)l * 128 * 1024 + (size_t)a * 1024 + h * 128;
        const u16* bkp = bk + l * D_HC + h * 128;
        for (int m = 0; m < 128; m++) acc += bu2f(wqp[m]) * bu2f(bkp[m]);
        wsc[l * 1024 + (r - 1024)] = acc * RSQRT_D;
    } else {  // csc[l][h]
        int h = r - 2048;
        const u16* bqp = bq + l * D_HC + h * 128;
        const u16* bkp = bk + l * D_HC + h * 128;
        for (int m = 0; m < 128; m++) acc += bu2f(bqp[m]) * bu2f(bkp[m]);
        csc[l * 8 + h] = acc * RSQRT_D;
    }
}

// ---------------- input projection ----------------
__global__ void k_input_proj(const u16* __restrict__ x, const u16* __restrict__ Win,
                             const u16* __restrict__ b_in, u16* __restrict__ h) {
    int gid = blockIdx.x * 256 + threadIdx.x;  // NN*128
    int n = gid >> 7, j = gid & 127;
    float acc = bu2f(b_in[j]);
#pragma unroll
    for (int i = 0; i < L_IN; i++) acc += bu2f(x[n * L_IN + i]) * bu2f(Win[i * D_H + j]);
    h[gid] = f2bu(acc);
}

// ---------------- CSR build ----------------
__global__ void k_hist(const int* __restrict__ dst, int* __restrict__ cnt) {
    int e = blockIdx.x * 256 + threadIdx.x;
    if (e < NE) atomicAdd(&cnt[dst[e]], 1);
}
__global__ void k_scanA(const int* __restrict__ cnt, int* __restrict__ incl, int* __restrict__ bsum) {
    __shared__ int s[256];
    int b = blockIdx.x, t = threadIdx.x, i = b * 256 + t;
    int v = (i < NN) ? cnt[i] : 0;
    s[t] = v;
    __syncthreads();
    for (int off = 1; off < 256; off <<= 1) {
        int u = (t >= off) ? s[t - off] : 0;
        __syncthreads();
        s[t] += u;
        __syncthreads();
    }
    if (i < NN) incl[i] = s[t];
    if (t == 255) bsum[b] = s[255];
}
__global__ void k_scanB(const int* __restrict__ bsum, int* __restrict__ bpre, int nb) {
    __shared__ int s[128];
    int t = threadIdx.x;
    int v = (t < nb) ? bsum[t] : 0;
    s[t] = v;
    __syncthreads();
    for (int off = 1; off < 128; off <<= 1) {
        int u = (t >= off) ? s[t - off] : 0;
        __syncthreads();
        s[t] += u;
        __syncthreads();
    }
    if (t < nb) bpre[t] = s[t] - v;
}
__global__ void k_scanC(const int* __restrict__ incl, const int* __restrict__ bpre, int* __restrict__ offs) {
    int b = blockIdx.x, t = threadIdx.x, i = b * 256 + t;
    if (i < NN) offs[i + 1] = incl[i] + bpre[b];
    if (i == 0) offs[0] = 0;
}
__global__ void k_scatter(const int* __restrict__ dst, const int* __restrict__ src,
                          const int* __restrict__ offs, int* __restrict__ cursor,
                          int* __restrict__ srcp) {
    int e = blockIdx.x * 256 + threadIdx.x;
    if (e < NE) {
        int d = dst[e];
        int p = offs[d] + atomicAdd(&cursor[d], 1);
        srcp[p] = src[e];
    }
}

// ---------------- main MFMA GEMM: C[M,2048] = h @ [GG^T | WskipT]^T + [cb|bskip] --
__global__ void k_gemm(const u16* __restrict__ A, int lda, int K,
                       const u16* __restrict__ Bt,
                       u16* __restrict__ C, int ldc,
                       const u16* __restrict__ bia0, const u16* __restrict__ bia1) {
    __shared__ __align__(16) u16 smem[128 * 136];
    u16* Als = smem;
    u16* Bls = smem + 4096;
    const int m0 = blockIdx.y * 128, n0 = blockIdx.x * 128;
    const int t = threadIdx.x;
    const int wave = t >> 6, lane = t & 63, quad = lane >> 4, l16 = lane & 15;
    const int wm = (wave >> 1) * 64, wn = (wave & 1) * 64;
    f32x4 acc[4][4];
#pragma unroll
    for (int i = 0; i < 4; i++)
#pragma unroll
        for (int j = 0; j < 4; j++) acc[i][j] = (f32x4){0.f, 0.f, 0.f, 0.f};

    for (int ko = 0; ko < K; ko += 32) {
#pragma unroll
        for (int c = t; c < 512; c += 256) {
            int row = c >> 2, kc = c & 3;
            *reinterpret_cast<uint4*>(&Als[row * 32 + kc * 8]) =
                *reinterpret_cast<const uint4*>(A + (size_t)(m0 + row) * lda + ko + kc * 8);
            *reinterpret_cast<uint4*>(&Bls[row * 32 + kc * 8]) =
                *reinterpret_cast<const uint4*>(Bt + (size_t)(n0 + row) * K + ko + kc * 8);
        }
        __syncthreads();
        short8 af[4], bf[4];
#pragma unroll
        for (int mt = 0; mt < 4; mt++)
            af[mt] = *reinterpret_cast<const short8*>(&Als[(wm + mt * 16 + l16) * 32 + quad * 8]);
#pragma unroll
        for (int nt = 0; nt < 4; nt++)
            bf[nt] = *reinterpret_cast<const short8*>(&Bls[(wn + nt * 16 + l16) * 32 + quad * 8]);
#pragma unroll
        for (int mt = 0; mt < 4; mt++)
#pragma unroll
            for (int nt = 0; nt < 4; nt++)
                acc[mt][nt] = __builtin_amdgcn_mfma_f32_16x16x32_bf16(af[mt], bf[nt], acc[mt][nt], 0, 0, 0);
        __syncthreads();
    }
#pragma unroll
    for (int mt = 0; mt < 4; mt++)
#pragma unroll
        for (int r = 0; r < 4; r++) {
            int rl = wm + mt * 16 + quad * 4 + r;
#pragma unroll
            for (int nt = 0; nt < 4; nt++) {
                int cl = wn + nt * 16 + l16;
                int col = n0 + cl;
                const u16* bp = (col < 1024) ? bia0 : bia1;
                smem[rl * 136 + cl] = f2bu(acc[mt][nt][r] + bu2f(bp[col & 1023]));
            }
        }
    __syncthreads();
#pragma unroll
    for (int c = t; c < 2048; c += 256) {
        int row = c >> 4, kc = c & 15;
        int grow = m0 + row;
        if (grow < NN)
            *reinterpret_cast<uint4*>(C + (size_t)grow * ldc + n0 + kc * 8) =
                *reinterpret_cast<const uint4*>(&smem[row * 136 + kc * 8]);
    }
}

// ---------------- sc: per-(node,head) scalar logit term ----------------
__global__ void k_sc(const u16* __restrict__ hc, const float* __restrict__ wsc,
                     const float* __restrict__ csc, float* __restrict__ scbuf) {
    int gid = blockIdx.x * 256 + threadIdx.x;  // NN*8
    if (gid >= NN * 8) return;
    int d = gid >> 3, h = gid & 7;
    const u16* hr = hc + (size_t)d * 128;
    float acc = csc[h];
    for (int a = 0; a < 128; a++) acc += bu2f(hr[a]) * wsc[a * 8 + h];
    scbuf[gid] = acc;
}

// ---------------- attention: one wave per dst node ----------------
__global__ void k_attn2(u16* __restrict__ qkvs2, const u16* __restrict__ hc,
                        const int* __restrict__ offs, const int* __restrict__ srcp,
                        const float* __restrict__ scbuf) {
    int gid = blockIdx.x * 256 + threadIdx.x;
    int d = gid >> 6, lane = gid & 63;
    if (d >= NN) return;
    int hh = lane >> 3, ci = (lane & 7) * 16;
    u16* zp = qkvs2 + (size_t)d * QS2 + hh * 128 + ci;
    float zf[16];
    {
        uint4 z0 = *reinterpret_cast<const uint4*>(zp);
        uint4 z1 = *reinterpret_cast<const uint4*>(zp + 8);
        cvt16(z0, z1, zf);
    }
    float scown = scbuf[d * 8 + hh];
    float u[16];
#pragma unroll
    for (int j = 0; j < 16; j++) u[j] = 0.f;
    float lrun = 0.f;

    int beg = offs[d], end = offs[d + 1];
    for (int c0 = beg; c0 < end; c0 += 64) {
        int cn = min(64, end - c0);
        int myidx = (c0 + lane < end) ? srcp[c0 + lane] : 0;
        int s = __shfl(myidx, 0, 64);
        const u16* hp = hc + (size_t)s * 128 + ci;
        uint4 a0 = *reinterpret_cast<const uint4*>(hp);
        uint4 a1 = *reinterpret_cast<const uint4*>(hp + 8);
        for (int i = 0; i < cn; i++) {
            uint4 n0 = a0, n1 = a1;
            if (i + 1 < cn) {
                int sn = __shfl(myidx, i + 1, 64);
                const u16* hpn = hc + (size_t)sn * 128 + ci;
                n0 = *reinterpret_cast<const uint4*>(hpn);
                n1 = *reinterpret_cast<const uint4*>(hpn + 8);
            }
            float hf[16];
            cvt16(a0, a1, hf);
            float p = 0.f;
#pragma unroll
            for (int j = 0; j < 16; j++) p += zf[j] * hf[j];
            p += __shfl_xor(p, 1, 64);
            p += __shfl_xor(p, 2, 64);
            p += __shfl_xor(p, 4, 64);
            float w = __expf(p + scown);
            lrun += w;
#pragma unroll
            for (int j = 0; j < 16; j++) u[j] += w * hf[j];
            a0 = n0; a1 = n1;
        }
    }
    float inv = 1.f / (lrun + 1e-16f);
    unsigned out[8];
#pragma unroll
    for (int j = 0; j < 8; j++)
        out[j] = (unsigned)f2bu(u[2 * j] * inv) | ((unsigned)f2bu(u[2 * j + 1] * inv) << 16);
    uint4* op = reinterpret_cast<uint4*>(zp);
    op[0] = make_uint4(out[0], out[1], out[2], out[3]);
    op[1] = make_uint4(out[4], out[5], out[6], out[7]);
}

// ---------------- vproj: o[d, h*128+c'] = u[d,h,:] @ Wv_h + bv ----------------
__global__ void k_vproj(const u16* __restrict__ A /*qkvs2 u-slot*/,
                        const u16* __restrict__ WvT_l, const u16* __restrict__ bv_l,
                        u16* __restrict__ obuf) {
    __shared__ __align__(16) u16 smem[128 * 136];
    u16* Als = smem;
    u16* Bls = smem + 4096;
    const int m0 = blockIdx.x * 128, h = blockIdx.y;
    const int t = threadIdx.x;
    const int wave = t >> 6, lane = t & 63, quad = lane >> 4, l16 = lane & 15;
    const int wm = (wave >> 1) * 64, wn = (wave & 1) * 64;
    f32x4 acc[4][4];
#pragma unroll
    for (int i = 0; i < 4; i++)
#pragma unroll
        for (int j = 0; j < 4; j++) acc[i][j] = (f32x4){0.f, 0.f, 0.f, 0.f};

    for (int ko = 0; ko < 128; ko += 32) {
#pragma unroll
        for (int c = t; c < 512; c += 256) {
            int row = c >> 2, kc = c & 3;
            *reinterpret_cast<uint4*>(&Als[row * 32 + kc * 8]) =
                *reinterpret_cast<const uint4*>(A + (size_t)(m0 + row) * QS2 + h * 128 + ko + kc * 8);
            *reinterpret_cast<uint4*>(&Bls[row * 32 + kc * 8]) =
                *reinterpret_cast<const uint4*>(WvT_l + (size_t)(h * 128 + row) * 128 + ko + kc * 8);
        }
        __syncthreads();
        short8 af[4], bf[4];
#pragma unroll
        for (int mt = 0; mt < 4; mt++)
            af[mt] = *reinterpret_cast<const short8*>(&Als[(wm + mt * 16 + l16) * 32 + quad * 8]);
#pragma unroll
        for (int nt = 0; nt < 4; nt++)
            bf[nt] = *reinterpret_cast<const short8*>(&Bls[(wn + nt * 16 + l16) * 32 + quad * 8]);
#pragma unroll
        for (int mt = 0; mt < 4; mt++)
#pragma unroll
            for (int nt = 0; nt < 4; nt++)
                acc[mt][nt] = __builtin_amdgcn_mfma_f32_16x16x32_bf16(af[mt], bf[nt], acc[mt][nt], 0, 0, 0);
        __syncthreads();
    }
#pragma unroll
    for (int mt = 0; mt < 4; mt++)
#pragma unroll
        for (int r = 0; r < 4; r++) {
            int rl = wm + mt * 16 + quad * 4 + r;
#pragma unroll
            for (int nt = 0; nt < 4; nt++) {
                int cl = wn + nt * 16 + l16;
                smem[rl * 136 + cl] = f2bu(acc[mt][nt][r] + bu2f(bv_l[h * 128 + cl]));
            }
        }
    __syncthreads();
    // FIX (r8 bug): full 128x128 tile = 2048 uint4 chunks (was c<1024 with
    // row=c>>3/kc=c&7, which wrote only cols 0..63 and left half of o poison).
#pragma unroll
    for (int c = t; c < 2048; c += 256) {
        int row = c >> 4, kc = c & 15;
        int grow = m0 + row;
        if (grow < NN)
            *reinterpret_cast<uint4*>(obuf + (size_t)grow * 1024 + h * 128 + kc * 8) =
                *reinterpret_cast<const uint4*>(&smem[row * 136 + kc * 8]);
    }
}

// ---------------- beta gate + LayerNorm: one wave per node ----------------
__global__ void k_betaLN(const u16* __restrict__ obuf, u16* __restrict__ qkvs2,
                         const u16* __restrict__ Wb, const u16* __restrict__ lng,
                         const u16* __restrict__ lnb) {
    int gid = blockIdx.x * 256 + threadIdx.x;
    int d = gid >> 6, lane = gid & 63;
    if (d >= NN) return;
    int c0 = lane * 16;
    float o[16], xr[16];
    {
        const u16* op = obuf + (size_t)d * 1024 + c0;
        uint4 o0 = *reinterpret_cast<const uint4*>(op);
        uint4 o1 = *reinterpret_cast<const uint4*>(op + 8);
        cvt16(o0, o1, o);
        const u16* xp = qkvs2 + (size_t)d * QS2 + 1024 + c0;
        uint4 x0 = *reinterpret_cast<const uint4*>(xp);
        uint4 x1 = *reinterpret_cast<const uint4*>(xp + 8);
        cvt16(x0, x1, xr);
    }
    float part = 0.f;
    {
        const u16* wp = Wb + c0;
        uint4 u0 = *reinterpret_cast<const uint4*>(wp);
        uint4 u1 = *reinterpret_cast<const uint4*>(wp + 8);
        float wf[16];
        cvt16(u0, u1, wf);
#pragma unroll
        for (int j = 0; j < 16; j++) part += o[j] * wf[j];
        u0 = *reinterpret_cast<const uint4*>(wp + D_HC);
        u1 = *reinterpret_cast<const uint4*>(wp + D_HC + 8);
        cvt16(u0, u1, wf);
#pragma unroll
        for (int j = 0; j < 16; j++) part += xr[j] * wf[j];
        u0 = *reinterpret_cast<const uint4*>(wp + 2 * D_HC);
        u1 = *reinterpret_cast<const uint4*>(wp + 2 * D_HC + 8);
        cvt16(u0, u1, wf);
#pragma unroll
        for (int j = 0; j < 16; j++) part += (o[j] - xr[j]) * wf[j];
    }
    float logit = wred64(part);
    float beta = 1.f / (1.f + __expf(-logit));
    float g[16], s1 = 0.f, s2 = 0.f;
#pragma unroll
    for (int j = 0; j < 16; j++) {
        g[j] = beta * xr[j] + (1.f - beta) * o[j];
        s1 += g[j]; s2 += g[j] * g[j];
    }
    s1 = wred64(s1);
    s2 = wred64(s2);
    float mu = s1 * (1.f / 1024.f);
    float var = s2 * (1.f / 1024.f) - mu * mu;
    float rs = rsqrtf(var + 1e-5f);
    {
        const u16* gp = lng + c0;
        const u16* bp2 = lnb + c0;
        uint4 g0 = *reinterpret_cast<const uint4*>(gp);
        uint4 g1 = *reinterpret_cast<const uint4*>(gp + 8);
        uint4 b0 = *reinterpret_cast<const uint4*>(bp2);
        uint4 b1 = *reinterpret_cast<const uint4*>(bp2 + 8);
        float lgf[16], lbf[16];
        cvt16(g0, g1, lgf);
        cvt16(b0, b1, lbf);
        unsigned out[8];
#pragma unroll
        for (int j = 0; j < 8; j++) {
            float y0 = (g[2 * j] - mu) * rs * lgf[2 * j] + lbf[2 * j];
            float y1 = (g[2 * j + 1] - mu) * rs * lgf[2 * j + 1] + lbf[2 * j + 1];
            out[j] = (unsigned)f2bu(y0) | ((unsigned)f2bu(y1) << 16);
        }
        uint4* yp = reinterpret_cast<uint4*>(qkvs2 + (size_t)d * QS2 + c0);
        yp[0] = make_uint4(out[0], out[1], out[2], out[3]);
        yp[1] = make_uint4(out[4], out[5], out[6], out[7]);
    }
}

// ---------------- proj GEMM: C[M,128] = y @ WpT + bias + resid, relu ----------
__global__ void k_proj(const u16* __restrict__ A, int lda,
                       const u16* __restrict__ Bt,
                       void* __restrict__ C, int mode,
                       const u16* __restrict__ bias, const u16* __restrict__ resid,
                       const int* __restrict__ flag) {
    __shared__ __align__(16) u16 Als[64 * 32];
    __shared__ __align__(16) u16 Bls[128 * 32];
    const int m0 = blockIdx.x * 64;
    const int t = threadIdx.x;
    const int wave = t >> 6, lane = t & 63, quad = lane >> 4, l16 = lane & 15;
    const int fp32out = (mode == 2 && *flag) ? 1 : 0;
    f32x4 acc[8];
#pragma unroll
    for (int j = 0; j < 8; j++) acc[j] = (f32x4){0.f, 0.f, 0.f, 0.f};

    for (int ko = 0; ko < 1024; ko += 32) {
        {
            int row = t >> 2, kc = t & 3;
            *reinterpret_cast<uint4*>(&Als[row * 32 + kc * 8]) =
                *reinterpret_cast<const uint4*>(A + (size_t)(m0 + row) * lda + ko + kc * 8);
        }
#pragma unroll
        for (int c = t; c < 512; c += 256) {
            int row = c >> 2, kc = c & 3;
            *reinterpret_cast<uint4*>(&Bls[row * 32 + kc * 8]) =
                *reinterpret_cast<const uint4*>(Bt + (size_t)row * 1024 + ko + kc * 8);
        }
        __syncthreads();
        short8 af = *reinterpret_cast<const short8*>(&Als[(wave * 16 + l16) * 32 + quad * 8]);
#pragma unroll
        for (int nt = 0; nt < 8; nt++) {
            short8 bf = *reinterpret_cast<const short8*>(&Bls[(nt * 16 + l16) * 32 + quad * 8]);
            acc[nt] = __builtin_amdgcn_mfma_f32_16x16x32_bf16(af, bf, acc[nt], 0, 0, 0);
        }
        __syncthreads();
    }
#pragma unroll
    for (int r = 0; r < 4; r++) {
        int row = m0 + wave * 16 + quad * 4 + r;
        if (row >= NN) continue;
#pragma unroll
        for (int nt = 0; nt < 8; nt++) {
            int col = nt * 16 + l16;
            float v = acc[nt][r] + bu2f(bias[col]) + bu2f(resid[(size_t)row * D_H + col]);
            float rr = (v == v) ? fmaxf(v, 0.f) : v;
            if (fp32out) ((float*)C)[(size_t)row * D_H + col] = rr;
            else         ((u16*)C)[(size_t)row * D_H + col] = f2bu(rr);
        }
    }
}

// ---------------- host launch ----------------
extern "C" void kernel_launch(void* const* d_in, const int* in_sizes, int n_in,
                              void* d_out, int out_size, void* d_ws, size_t ws_size,
                              hipStream_t stream) {
    const int* ei = (const int*)d_in[1];
    const int* srcI = ei;
    const int* dstI = ei + NE;

    char* w = (char*)d_ws;
    auto carve = [&](size_t bytes) -> char* {
        char* p = w;
        w += (bytes + 255) & ~(size_t)255;
        return p;
    };
    u16* Bmain  = (u16*)carve((size_t)N_LAYERS * 2048 * 128 * 2);
    u16* WvT    = (u16*)carve((size_t)N_LAYERS * 1024 * 128 * 2);
    u16* WTp    = (u16*)carve((size_t)N_LAYERS * 128 * 1024 * 2);
    u16* hA     = (u16*)carve((size_t)M_PAD * D_H * 2);
    u16* hB     = (u16*)carve((size_t)M_PAD * D_H * 2);
    u16* qkvs2  = (u16*)carve((size_t)M_PAD * QS2 * 2);
    u16* obuf   = (u16*)carve((size_t)M_PAD * 1024 * 2);
    float* scbuf = (float*)carve((size_t)NN * 8 * 4);
    u16* cbuf   = (u16*)carve((size_t)N_LAYERS * 1024 * 2);
    float* wscb = (float*)carve((size_t)N_LAYERS * 1024 * 4);
    float* cscb = (float*)carve((size_t)N_LAYERS * 8 * 4);
    int* cnt    = (int*)carve(2 * NN * 4);
    int* cursor = cnt + NN;
    int* offs   = (int*)carve((NN + 1) * 4);
    int* incl   = (int*)carve(NN * 4);
    int* bsum   = (int*)carve(128 * 4);
    int* bpre   = (int*)carve(128 * 4);
    int* srcp   = (int*)carve(NE * 4);
    int* flag   = (int*)carve(256);

    const int conv_size[13] = {NN * L_IN, L_IN * D_H, D_H,
                               N_LAYERS * D_HC, N_LAYERS * D_HC, N_LAYERS * D_HC,
                               N_LAYERS * D_HC, N_LAYERS * 3 * D_HC,
                               N_LAYERS * D_HC, N_LAYERS * D_HC, N_LAYERS * D_H,
                               N_LAYERS * D_H * D_HC, N_LAYERS * D_H * D_HC};
    const int conv_idx[13] = {0, 2, 3, 5, 7, 9, 11, 12, 13, 14, 16, 4, 6};
    CvDesc dsc;
    u16* conv[13];
    for (int i = 0; i < 13; i++) {
        conv[i] = (u16*)carve((size_t)conv_size[i] * 2);
        dsc.in[i] = d_in[conv_idx[i]];
        dsc.out[i] = conv[i];
    }

    k_detect<<<1, 256, 0, stream>>>((const u16*)d_in[0], flag);
    k_convert_all<<<(CV_TOTAL + 255) / 256, 256, 0, stream>>>(dsc, flag);
    const u16* x    = conv[0];
    const u16* Win  = conv[1];
    const u16* b_in = conv[2];
    const u16* bq   = conv[3];
    const u16* bk   = conv[4];
    const u16* bv   = conv[5];
    const u16* bsk  = conv[6];
    const u16* Wb   = conv[7];
    const u16* lng  = conv[8];
    const u16* lnb  = conv[9];
    const u16* bp   = conv[10];
    const u16* Wqb  = conv[11];
    const u16* Wkb  = conv[12];

    k_convT_vs<<<dim3(2, 32, 6), 256, 0, stream>>>(d_in[8], d_in[10], WvT, Bmain, flag);
    k_convT_proj<<<dim3(16, 2, 6), 256, 0, stream>>>(d_in[15], WTp, flag);
    k_GG<<<dim3(8, 6), 256, 0, stream>>>(Wqb, Wkb, Bmain);
    k_pre_small<<<(N_LAYERS * 2056 + 255) / 256, 256, 0, stream>>>(Wqb, Wkb, bq, bk,
                                                                   cbuf, wscb, cscb);
    k_input_proj<<<(NN * D_H) / 256, 256, 0, stream>>>(x, Win, b_in, hA);
    k_zero<<<(2 * NN + 255) / 256, 256, 0, stream>>>(cnt, 2 * NN);
    k_hist<<<(NE + 255) / 256, 256, 0, stream>>>(dstI, cnt);
    const int NB = (NN + 255) / 256;  // 79
    k_scanA<<<NB, 256, 0, stream>>>(cnt, incl, bsum);
    k_scanB<<<1, 128, 0, stream>>>(bsum, bpre, NB);
    k_scanC<<<NB, 256, 0, stream>>>(incl, bpre, offs);
    k_scatter<<<(NE + 255) / 256, 256, 0, stream>>>(dstI, srcI, offs, cursor, srcp);

    u16* hc = hA;
    u16* hn = hB;
    for (int l = 0; l < N_LAYERS; l++) {
        k_gemm<<<dim3(16, 157), 256, 0, stream>>>(hc, D_H, D_H,
                                                  Bmain + (size_t)l * 2048 * 128,
                                                  qkvs2, QS2,
                                                  cbuf + l * 1024, bsk + l * D_HC);
        k_sc<<<(NN * 8 + 255) / 256, 256, 0, stream>>>(hc, wscb + l * 1024,
                                                       cscb + l * 8, scbuf);
        k_attn2<<<(NN * 64) / 256, 256, 0, stream>>>(qkvs2, hc, offs, srcp, scbuf);
        k_vproj<<<dim3(157, 8), 256, 0, stream>>>(qkvs2, WvT + (size_t)l * 1024 * 128,
                                                  bv + l * D_HC, obuf);
        k_betaLN<<<(NN * 64) / 256, 256, 0, stream>>>(obuf, qkvs2,
                                                      Wb + (size_t)l * 3 * D_HC,
                                                      lng + l * D_HC, lnb + l * D_HC);
        int last = (l == N_LAYERS - 1);
        void* outp = last ? d_out : (void*)hn;
        k_proj<<<314, 256, 0, stream>>>(qkvs2, QS2, WTp + (size_t)l * 128 * 1024,
                                        outp, last ? 2 : 1,
                                        bp + l * D_H, hc, flag);
        u16* tmp = hc; hc = hn; hn = tmp;
    }
}

// Round 10
// 944.955 us; speedup vs baseline: 1.8288x; 1.0758x over previous
//
#include <hip/hip_runtime.h>
#include <stdint.h>

#define NN 20000
#define NE 160000
#define L_IN 15
#define D_H 128
#define N_HEADS 8
#define D_HC 1024
#define N_LAYERS 6
#define M_PAD 20096   // 157*128 = 628*32
#define QS2 2048      // zd|x_r interleaved row stride (u,y overwrite zd slot)

typedef unsigned short u16;
typedef __attribute__((ext_vector_type(8))) short short8;
typedef __attribute__((ext_vector_type(4))) float f32x4;

#define RSQRT_D 0.08838834764831845f  // 1/sqrt(128)

__device__ __forceinline__ float bu2f(u16 u) { return __uint_as_float(((unsigned)u) << 16); }
__device__ __forceinline__ u16 f2bu(float f) {
    unsigned x = __float_as_uint(f);
    return (u16)((x + 0x7fffu + ((x >> 16) & 1u)) >> 16);  // RNE
}
__device__ __forceinline__ float wred64(float v) {
#pragma unroll
    for (int m = 32; m >= 1; m >>= 1) v += __shfl_xor(v, m, 64);
    return v;
}
__device__ __forceinline__ void cvt16(const uint4& u0, const uint4& u1, float* f) {
    unsigned d[8] = {u0.x, u0.y, u0.z, u0.w, u1.x, u1.y, u1.z, u1.w};
#pragma unroll
    for (int i = 0; i < 8; i++) {
        f[2 * i]     = __uint_as_float(d[i] << 16);
        f[2 * i + 1] = __uint_as_float(d[i] & 0xffff0000u);
    }
}

// ---------------- dtype detection ----------------
__global__ void k_detect(const u16* __restrict__ xb, int* __restrict__ flag) {
    int t = threadIdx.x;
    u16 u = xb[2 * t];
    int e = (u >> 7) & 0xFF;
    int weird = (e > 150 || (e != 0 && e < 100)) ? 1 : 0;
    __shared__ int cnt;
    if (t == 0) cnt = 0;
    __syncthreads();
    atomicAdd(&cnt, weird);
    __syncthreads();
    if (t == 0) *flag = (cnt > 64) ? 1 : 0;  // 1 = inputs are fp32
}

// ---------------- fused convert (13 segments incl. Wq, Wk) ----------------
struct CvDesc { const void* in[13]; u16* out[13]; };
#define CV_TOTAL 1930976
__global__ void k_convert_all(CvDesc dsc, const int* __restrict__ flag) {
    const int sizes[13] = {NN * L_IN, L_IN * D_H, D_H,
                           N_LAYERS * D_HC, N_LAYERS * D_HC, N_LAYERS * D_HC,
                           N_LAYERS * D_HC, N_LAYERS * 3 * D_HC,
                           N_LAYERS * D_HC, N_LAYERS * D_HC, N_LAYERS * D_H,
                           N_LAYERS * D_H * D_HC, N_LAYERS * D_H * D_HC};
    int off = blockIdx.x * 256 + threadIdx.x;
    if (off >= CV_TOTAL) return;
    int seg = 0;
#pragma unroll
    for (int s = 0; s < 13; s++) {
        if (off >= sizes[s] && seg == s) { off -= sizes[s]; seg = s + 1; }
    }
    if (*flag) dsc.out[seg][off] = f2bu(((const float*)dsc.in[seg])[off]);
    else       dsc.out[seg][off] = ((const u16*)dsc.in[seg])[off];
}

__global__ void k_zero(int* __restrict__ p, int n) {
    int i = blockIdx.x * 256 + threadIdx.x;
    if (i < n) p[i] = 0;
}

// ------------- convert+transpose: Wv -> WvT, Wskip -> Bmain rows 1024.. ------
__global__ void k_convT_vs(const void* __restrict__ Wv, const void* __restrict__ Ws,
                           u16* __restrict__ WvT, u16* __restrict__ Bmain,
                           const int* __restrict__ flag) {
    __shared__ u16 tile[64][66];
    int tk = blockIdx.x, tn = blockIdx.y, l = blockIdx.z;
    int t = threadIdx.x;
    int isv = (tn < 16);
    const void* W = isv ? Wv : Ws;
    int n_off = (tn & 15) * 64;
    int r = t >> 2, c0 = (t & 3) * 16;
    size_t base = (size_t)l * 128 * 1024 + (size_t)(tk * 64 + r) * 1024 + n_off + c0;
    if (*flag) {
        const float* Wf = (const float*)W;
#pragma unroll
        for (int cc = 0; cc < 16; cc++) tile[c0 + cc][r] = f2bu(Wf[base + cc]);
    } else {
        const u16* Wh = (const u16*)W;
#pragma unroll
        for (int cc = 0; cc < 16; cc++) tile[c0 + cc][r] = Wh[base + cc];
    }
    __syncthreads();
    int i = t >> 2, j0 = (t & 3) * 16;
    u16* dst = isv ? (WvT + ((size_t)l * 1024 + n_off + i) * 128 + tk * 64 + j0)
                   : (Bmain + ((size_t)l * 2048 + 1024 + n_off + i) * 128 + tk * 64 + j0);
#pragma unroll
    for (int jj = 0; jj < 16; jj++) dst[jj] = tile[i][j0 + jj];
}

// Wp: [l][1024 k][128 n] -> WTp [l][128 n][1024 k]. grid (16, 2, 6).
__global__ void k_convT_proj(const void* __restrict__ Wp, u16* __restrict__ WT,
                             const int* __restrict__ flag) {
    __shared__ u16 tile[64][66];
    int tk = blockIdx.x, tn = blockIdx.y, l = blockIdx.z;
    int t = threadIdx.x;
    int r = t >> 2, c0 = (t & 3) * 16;
    size_t base = (size_t)l * 1024 * 128 + (size_t)(tk * 64 + r) * 128 + tn * 64 + c0;
    if (*flag) {
        const float* Wf = (const float*)Wp;
#pragma unroll
        for (int cc = 0; cc < 16; cc++) tile[c0 + cc][r] = f2bu(Wf[base + cc]);
    } else {
        const u16* Wh = (const u16*)Wp;
#pragma unroll
        for (int cc = 0; cc < 16; cc++) tile[c0 + cc][r] = Wh[base + cc];
    }
    __syncthreads();
    int i = t >> 2, j0 = (t & 3) * 16;
    u16* dst = WT + ((size_t)l * 128 + tn * 64 + i) * 1024 + tk * 64 + j0;
#pragma unroll
    for (int jj = 0; jj < 16; jj++) dst[jj] = tile[i][j0 + jj];
}

// ---------------- GG precompute: Bmain rows 0-1023 = (Wq_h Wk_h^T)^T / sqrt(d) --
__global__ void k_GG(const u16* __restrict__ Wqb, const u16* __restrict__ Wkb,
                     u16* __restrict__ Bmain) {
    int h = blockIdx.x, l = blockIdx.y;
    __shared__ __align__(16) u16 Als[128 * 32];
    __shared__ __align__(16) u16 Bls[128 * 32];
    const int t = threadIdx.x;
    const int wave = t >> 6, lane = t & 63, quad = lane >> 4, l16 = lane & 15;
    const int wm = (wave >> 1) * 64, wn = (wave & 1) * 64;
    const u16* Ab = Wqb + (size_t)l * 128 * 1024 + h * 128;
    const u16* Bb = Wkb + (size_t)l * 128 * 1024 + h * 128;
    f32x4 acc[4][4];
#pragma unroll
    for (int i = 0; i < 4; i++)
#pragma unroll
        for (int j = 0; j < 4; j++) acc[i][j] = (f32x4){0.f, 0.f, 0.f, 0.f};
    for (int ko = 0; ko < 128; ko += 32) {
#pragma unroll
        for (int c = t; c < 512; c += 256) {
            int row = c >> 2, kc = c & 3;
            *reinterpret_cast<uint4*>(&Als[row * 32 + kc * 8]) =
                *reinterpret_cast<const uint4*>(Ab + (size_t)row * 1024 + ko + kc * 8);
            *reinterpret_cast<uint4*>(&Bls[row * 32 + kc * 8]) =
                *reinterpret_cast<const uint4*>(Bb + (size_t)row * 1024 + ko + kc * 8);
        }
        __syncthreads();
        short8 af[4], bf[4];
#pragma unroll
        for (int mt = 0; mt < 4; mt++)
            af[mt] = *reinterpret_cast<const short8*>(&Als[(wm + mt * 16 + l16) * 32 + quad * 8]);
#pragma unroll
        for (int nt = 0; nt < 4; nt++)
            bf[nt] = *reinterpret_cast<const short8*>(&Bls[(wn + nt * 16 + l16) * 32 + quad * 8]);
#pragma unroll
        for (int mt = 0; mt < 4; mt++)
#pragma unroll
            for (int nt = 0; nt < 4; nt++)
                acc[mt][nt] = __builtin_amdgcn_mfma_f32_16x16x32_bf16(af[mt], bf[nt], acc[mt][nt], 0, 0, 0);
        __syncthreads();
    }
    u16* dst = Bmain + (size_t)l * 2048 * 128;
#pragma unroll
    for (int mt = 0; mt < 4; mt++)
#pragma unroll
        for (int r = 0; r < 4; r++) {
            int row = wm + mt * 16 + quad * 4 + r;  // a
#pragma unroll
            for (int nt = 0; nt < 4; nt++) {
                int col = wn + nt * 16 + l16;       // b
                dst[(size_t)(h * 128 + col) * 128 + row] = f2bu(acc[mt][nt][r] * RSQRT_D);
            }
        }
}

// ---------------- small precompute: cb, wsc, csc ----------------
__global__ void k_pre_small(const u16* __restrict__ Wqb, const u16* __restrict__ Wkb,
                            const u16* __restrict__ bq, const u16* __restrict__ bk,
                            u16* __restrict__ cb, float* __restrict__ wsc,
                            float* __restrict__ csc) {
    int gid = blockIdx.x * 256 + threadIdx.x;  // 6*2056
    if (gid >= N_LAYERS * 2056) return;
    int l = gid / 2056, r = gid % 2056;
    float acc = 0.f;
    if (r < 1024) {
        int h = r >> 7, b = r & 127;
        const u16* bqp = bq + l * D_HC + h * 128;
        const u16* wkp = Wkb + (size_t)l * 128 * 1024 + (size_t)b * 1024 + h * 128;
        for (int m = 0; m < 128; m++) acc += bu2f(bqp[m]) * bu2f(wkp[m]);
        cb[l * 1024 + r] = f2bu(acc * RSQRT_D);
    } else if (r < 2048) {
        int a = (r - 1024) >> 3, h = (r - 1024) & 7;
        const u16* wqp = Wqb + (size_t)l * 128 * 1024 + (size_t)a * 1024 + h * 128;
        const u16* bkp = bk + l * D_HC + h * 128;
        for (int m = 0; m < 128; m++) acc += bu2f(wqp[m]) * bu2f(bkp[m]);
        wsc[l * 1024 + (r - 1024)] = acc * RSQRT_D;
    } else {
        int h = r - 2048;
        const u16* bqp = bq + l * D_HC + h * 128;
        const u16* bkp = bk + l * D_HC + h * 128;
        for (int m = 0; m < 128; m++) acc += bu2f(bqp[m]) * bu2f(bkp[m]);
        csc[l * 8 + h] = acc * RSQRT_D;
    }
}

// ---------------- input projection ----------------
__global__ void k_input_proj(const u16* __restrict__ x, const u16* __restrict__ Win,
                             const u16* __restrict__ b_in, u16* __restrict__ h) {
    int gid = blockIdx.x * 256 + threadIdx.x;  // NN*128
    int n = gid >> 7, j = gid & 127;
    float acc = bu2f(b_in[j]);
#pragma unroll
    for (int i = 0; i < L_IN; i++) acc += bu2f(x[n * L_IN + i]) * bu2f(Win[i * D_H + j]);
    h[gid] = f2bu(acc);
}

// ---------------- CSR build ----------------
__global__ void k_hist(const int* __restrict__ dst, int* __restrict__ cnt) {
    int e = blockIdx.x * 256 + threadIdx.x;
    if (e < NE) atomicAdd(&cnt[dst[e]], 1);
}
__global__ void k_scanA(const int* __restrict__ cnt, int* __restrict__ incl, int* __restrict__ bsum) {
    __shared__ int s[256];
    int b = blockIdx.x, t = threadIdx.x, i = b * 256 + t;
    int v = (i < NN) ? cnt[i] : 0;
    s[t] = v;
    __syncthreads();
    for (int off = 1; off < 256; off <<= 1) {
        int u = (t >= off) ? s[t - off] : 0;
        __syncthreads();
        s[t] += u;
        __syncthreads();
    }
    if (i < NN) incl[i] = s[t];
    if (t == 255) bsum[b] = s[255];
}
__global__ void k_scanB(const int* __restrict__ bsum, int* __restrict__ bpre, int nb) {
    __shared__ int s[128];
    int t = threadIdx.x;
    int v = (t < nb) ? bsum[t] : 0;
    s[t] = v;
    __syncthreads();
    for (int off = 1; off < 128; off <<= 1) {
        int u = (t >= off) ? s[t - off] : 0;
        __syncthreads();
        s[t] += u;
        __syncthreads();
    }
    if (t < nb) bpre[t] = s[t] - v;
}
__global__ void k_scanC(const int* __restrict__ incl, const int* __restrict__ bpre, int* __restrict__ offs) {
    int b = blockIdx.x, t = threadIdx.x, i = b * 256 + t;
    if (i < NN) offs[i + 1] = incl[i] + bpre[b];
    if (i == 0) offs[0] = 0;
}
__global__ void k_scatter(const int* __restrict__ dst, const int* __restrict__ src,
                          const int* __restrict__ offs, int* __restrict__ cursor,
                          int* __restrict__ srcp) {
    int e = blockIdx.x * 256 + threadIdx.x;
    if (e < NE) {
        int d = dst[e];
        int p = offs[d] + atomicAdd(&cursor[d], 1);
        srcp[p] = src[e];
    }
}

// ---------------- main MFMA GEMM: C[M,2048] = h @ [GG^T | WskipT]^T + [cb|bskip] --
__global__ void k_gemm(const u16* __restrict__ A, int lda, int K,
                       const u16* __restrict__ Bt,
                       u16* __restrict__ C, int ldc,
                       const u16* __restrict__ bia0, const u16* __restrict__ bia1) {
    __shared__ __align__(16) u16 smem[128 * 136];
    u16* Als = smem;
    u16* Bls = smem + 4096;
    const int m0 = blockIdx.y * 128, n0 = blockIdx.x * 128;
    const int t = threadIdx.x;
    const int wave = t >> 6, lane = t & 63, quad = lane >> 4, l16 = lane & 15;
    const int wm = (wave >> 1) * 64, wn = (wave & 1) * 64;
    f32x4 acc[4][4];
#pragma unroll
    for (int i = 0; i < 4; i++)
#pragma unroll
        for (int j = 0; j < 4; j++) acc[i][j] = (f32x4){0.f, 0.f, 0.f, 0.f};

    for (int ko = 0; ko < K; ko += 32) {
#pragma unroll
        for (int c = t; c < 512; c += 256) {
            int row = c >> 2, kc = c & 3;
            *reinterpret_cast<uint4*>(&Als[row * 32 + kc * 8]) =
                *reinterpret_cast<const uint4*>(A + (size_t)(m0 + row) * lda + ko + kc * 8);
            *reinterpret_cast<uint4*>(&Bls[row * 32 + kc * 8]) =
                *reinterpret_cast<const uint4*>(Bt + (size_t)(n0 + row) * K + ko + kc * 8);
        }
        __syncthreads();
        short8 af[4], bf[4];
#pragma unroll
        for (int mt = 0; mt < 4; mt++)
            af[mt] = *reinterpret_cast<const short8*>(&Als[(wm + mt * 16 + l16) * 32 + quad * 8]);
#pragma unroll
        for (int nt = 0; nt < 4; nt++)
            bf[nt] = *reinterpret_cast<const short8*>(&Bls[(wn + nt * 16 + l16) * 32 + quad * 8]);
#pragma unroll
        for (int mt = 0; mt < 4; mt++)
#pragma unroll
            for (int nt = 0; nt < 4; nt++)
                acc[mt][nt] = __builtin_amdgcn_mfma_f32_16x16x32_bf16(af[mt], bf[nt], acc[mt][nt], 0, 0, 0);
        __syncthreads();
    }
#pragma unroll
    for (int mt = 0; mt < 4; mt++)
#pragma unroll
        for (int r = 0; r < 4; r++) {
            int rl = wm + mt * 16 + quad * 4 + r;
#pragma unroll
            for (int nt = 0; nt < 4; nt++) {
                int cl = wn + nt * 16 + l16;
                int col = n0 + cl;
                const u16* bp = (col < 1024) ? bia0 : bia1;
                smem[rl * 136 + cl] = f2bu(acc[mt][nt][r] + bu2f(bp[col & 1023]));
            }
        }
    __syncthreads();
#pragma unroll
    for (int c = t; c < 2048; c += 256) {
        int row = c >> 4, kc = c & 15;
        int grow = m0 + row;
        if (grow < NN)
            *reinterpret_cast<uint4*>(C + (size_t)grow * ldc + n0 + kc * 8) =
                *reinterpret_cast<const uint4*>(&smem[row * 136 + kc * 8]);
    }
}

// ---------------- sc: per-(node,head) scalar logit term ----------------
__global__ void k_sc(const u16* __restrict__ hc, const float* __restrict__ wsc,
                     const float* __restrict__ csc, float* __restrict__ scbuf) {
    int gid = blockIdx.x * 256 + threadIdx.x;  // NN*8
    if (gid >= NN * 8) return;
    int d = gid >> 3, h = gid & 7;
    const u16* hr = hc + (size_t)d * 128;
    float acc = csc[h];
    for (int a = 0; a < 128; a++) acc += bu2f(hr[a]) * wsc[a * 8 + h];
    scbuf[gid] = acc;
}

// ---------------- attention: one wave per dst node ----------------
__global__ void k_attn2(u16* __restrict__ qkvs2, const u16* __restrict__ hc,
                        const int* __restrict__ offs, const int* __restrict__ srcp,
                        const float* __restrict__ scbuf) {
    int gid = blockIdx.x * 256 + threadIdx.x;
    int d = gid >> 6, lane = gid & 63;
    if (d >= NN) return;
    int hh = lane >> 3, ci = (lane & 7) * 16;
    u16* zp = qkvs2 + (size_t)d * QS2 + hh * 128 + ci;
    float zf[16];
    {
        uint4 z0 = *reinterpret_cast<const uint4*>(zp);
        uint4 z1 = *reinterpret_cast<const uint4*>(zp + 8);
        cvt16(z0, z1, zf);
    }
    float scown = scbuf[d * 8 + hh];
    float u[16];
#pragma unroll
    for (int j = 0; j < 16; j++) u[j] = 0.f;
    float lrun = 0.f;

    int beg = offs[d], end = offs[d + 1];
    for (int c0 = beg; c0 < end; c0 += 64) {
        int cn = min(64, end - c0);
        int myidx = (c0 + lane < end) ? srcp[c0 + lane] : 0;
        int s = __shfl(myidx, 0, 64);
        const u16* hp = hc + (size_t)s * 128 + ci;
        uint4 a0 = *reinterpret_cast<const uint4*>(hp);
        uint4 a1 = *reinterpret_cast<const uint4*>(hp + 8);
        for (int i = 0; i < cn; i++) {
            uint4 n0 = a0, n1 = a1;
            if (i + 1 < cn) {
                int sn = __shfl(myidx, i + 1, 64);
                const u16* hpn = hc + (size_t)sn * 128 + ci;
                n0 = *reinterpret_cast<const uint4*>(hpn);
                n1 = *reinterpret_cast<const uint4*>(hpn + 8);
            }
            float hf[16];
            cvt16(a0, a1, hf);
            float p = 0.f;
#pragma unroll
            for (int j = 0; j < 16; j++) p += zf[j] * hf[j];
            p += __shfl_xor(p, 1, 64);
            p += __shfl_xor(p, 2, 64);
            p += __shfl_xor(p, 4, 64);
            float w = __expf(p + scown);
            lrun += w;
#pragma unroll
            for (int j = 0; j < 16; j++) u[j] += w * hf[j];
            a0 = n0; a1 = n1;
        }
    }
    float inv = 1.f / (lrun + 1e-16f);
    unsigned out[8];
#pragma unroll
    for (int j = 0; j < 8; j++)
        out[j] = (unsigned)f2bu(u[2 * j] * inv) | ((unsigned)f2bu(u[2 * j + 1] * inv) << 16);
    uint4* op = reinterpret_cast<uint4*>(zp);
    op[0] = make_uint4(out[0], out[1], out[2], out[3]);
    op[1] = make_uint4(out[4], out[5], out[6], out[7]);
}

// ---------------- vproj: o[d, h*128+c'] = u[d,h,:] @ Wv_h + bv ----------------
__global__ void k_vproj(const u16* __restrict__ A /*qkvs2 u-slot*/,
                        const u16* __restrict__ WvT_l, const u16* __restrict__ bv_l,
                        u16* __restrict__ obuf) {
    __shared__ __align__(16) u16 smem[128 * 136];
    u16* Als = smem;
    u16* Bls = smem + 4096;
    const int m0 = blockIdx.x * 128, h = blockIdx.y;
    const int t = threadIdx.x;
    const int wave = t >> 6, lane = t & 63, quad = lane >> 4, l16 = lane & 15;
    const int wm = (wave >> 1) * 64, wn = (wave & 1) * 64;
    f32x4 acc[4][4];
#pragma unroll
    for (int i = 0; i < 4; i++)
#pragma unroll
        for (int j = 0; j < 4; j++) acc[i][j] = (f32x4){0.f, 0.f, 0.f, 0.f};

    for (int ko = 0; ko < 128; ko += 32) {
#pragma unroll
        for (int c = t; c < 512; c += 256) {
            int row = c >> 2, kc = c & 3;
            *reinterpret_cast<uint4*>(&Als[row * 32 + kc * 8]) =
                *reinterpret_cast<const uint4*>(A + (size_t)(m0 + row) * QS2 + h * 128 + ko + kc * 8);
            *reinterpret_cast<uint4*>(&Bls[row * 32 + kc * 8]) =
                *reinterpret_cast<const uint4*>(WvT_l + (size_t)(h * 128 + row) * 128 + ko + kc * 8);
        }
        __syncthreads();
        short8 af[4], bf[4];
#pragma unroll
        for (int mt = 0; mt < 4; mt++)
            af[mt] = *reinterpret_cast<const short8*>(&Als[(wm + mt * 16 + l16) * 32 + quad * 8]);
#pragma unroll
        for (int nt = 0; nt < 4; nt++)
            bf[nt] = *reinterpret_cast<const short8*>(&Bls[(wn + nt * 16 + l16) * 32 + quad * 8]);
#pragma unroll
        for (int mt = 0; mt < 4; mt++)
#pragma unroll
            for (int nt = 0; nt < 4; nt++)
                acc[mt][nt] = __builtin_amdgcn_mfma_f32_16x16x32_bf16(af[mt], bf[nt], acc[mt][nt], 0, 0, 0);
        __syncthreads();
    }
#pragma unroll
    for (int mt = 0; mt < 4; mt++)
#pragma unroll
        for (int r = 0; r < 4; r++) {
            int rl = wm + mt * 16 + quad * 4 + r;
#pragma unroll
            for (int nt = 0; nt < 4; nt++) {
                int cl = wn + nt * 16 + l16;
                smem[rl * 136 + cl] = f2bu(acc[mt][nt][r] + bu2f(bv_l[h * 128 + cl]));
            }
        }
    __syncthreads();
#pragma unroll
    for (int c = t; c < 2048; c += 256) {
        int row = c >> 4, kc = c & 15;
        int grow = m0 + row;
        if (grow < NN)
            *reinterpret_cast<uint4*>(obuf + (size_t)grow * 1024 + h * 128 + kc * 8) =
                *reinterpret_cast<const uint4*>(&smem[row * 136 + kc * 8]);
    }
}

// ---------------- beta gate + LayerNorm: one wave per node ----------------
__global__ void k_betaLN(const u16* __restrict__ obuf, u16* __restrict__ qkvs2,
                         const u16* __restrict__ Wb, const u16* __restrict__ lng,
                         const u16* __restrict__ lnb) {
    int gid = blockIdx.x * 256 + threadIdx.x;
    int d = gid >> 6, lane = gid & 63;
    if (d >= NN) return;
    int c0 = lane * 16;
    float o[16], xr[16];
    {
        const u16* op = obuf + (size_t)d * 1024 + c0;
        uint4 o0 = *reinterpret_cast<const uint4*>(op);
        uint4 o1 = *reinterpret_cast<const uint4*>(op + 8);
        cvt16(o0, o1, o);
        const u16* xp = qkvs2 + (size_t)d * QS2 + 1024 + c0;
        uint4 x0 = *reinterpret_cast<const uint4*>(xp);
        uint4 x1 = *reinterpret_cast<const uint4*>(xp + 8);
        cvt16(x0, x1, xr);
    }
    float part = 0.f;
    {
        const u16* wp = Wb + c0;
        uint4 u0 = *reinterpret_cast<const uint4*>(wp);
        uint4 u1 = *reinterpret_cast<const uint4*>(wp + 8);
        float wf[16];
        cvt16(u0, u1, wf);
#pragma unroll
        for (int j = 0; j < 16; j++) part += o[j] * wf[j];
        u0 = *reinterpret_cast<const uint4*>(wp + D_HC);
        u1 = *reinterpret_cast<const uint4*>(wp + D_HC + 8);
        cvt16(u0, u1, wf);
#pragma unroll
        for (int j = 0; j < 16; j++) part += xr[j] * wf[j];
        u0 = *reinterpret_cast<const uint4*>(wp + 2 * D_HC);
        u1 = *reinterpret_cast<const uint4*>(wp + 2 * D_HC + 8);
        cvt16(u0, u1, wf);
#pragma unroll
        for (int j = 0; j < 16; j++) part += (o[j] - xr[j]) * wf[j];
    }
    float logit = wred64(part);
    float beta = 1.f / (1.f + __expf(-logit));
    float g[16], s1 = 0.f, s2 = 0.f;
#pragma unroll
    for (int j = 0; j < 16; j++) {
        g[j] = beta * xr[j] + (1.f - beta) * o[j];
        s1 += g[j]; s2 += g[j] * g[j];
    }
    s1 = wred64(s1);
    s2 = wred64(s2);
    float mu = s1 * (1.f / 1024.f);
    float var = s2 * (1.f / 1024.f) - mu * mu;
    float rs = rsqrtf(var + 1e-5f);
    {
        const u16* gp = lng + c0;
        const u16* bp2 = lnb + c0;
        uint4 g0 = *reinterpret_cast<const uint4*>(gp);
        uint4 g1 = *reinterpret_cast<const uint4*>(gp + 8);
        uint4 b0 = *reinterpret_cast<const uint4*>(bp2);
        uint4 b1 = *reinterpret_cast<const uint4*>(bp2 + 8);
        float lgf[16], lbf[16];
        cvt16(g0, g1, lgf);
        cvt16(b0, b1, lbf);
        unsigned out[8];
#pragma unroll
        for (int j = 0; j < 8; j++) {
            float y0 = (g[2 * j] - mu) * rs * lgf[2 * j] + lbf[2 * j];
            float y1 = (g[2 * j + 1] - mu) * rs * lgf[2 * j + 1] + lbf[2 * j + 1];
            out[j] = (unsigned)f2bu(y0) | ((unsigned)f2bu(y1) << 16);
        }
        uint4* yp = reinterpret_cast<uint4*>(qkvs2 + (size_t)d * QS2 + c0);
        yp[0] = make_uint4(out[0], out[1], out[2], out[3]);
        yp[1] = make_uint4(out[4], out[5], out[6], out[7]);
    }
}

// ---------------- proj GEMM v2: M=32 tiles (628 blocks) + register-prefetch ----
// C[M,128] = y @ WpT + bias + resid, relu. LDS stride 40 u16 (2-way conflicts).
// Wave w owns n-cols [w*32, w*32+32): 2 m-tiles x 2 n-tiles of 16x16.
#define PLDA 40
__global__ void k_proj(const u16* __restrict__ A, int lda,
                       const u16* __restrict__ Bt,
                       void* __restrict__ C, int mode,
                       const u16* __restrict__ bias, const u16* __restrict__ resid,
                       const int* __restrict__ flag) {
    __shared__ __align__(16) u16 Als[32 * PLDA];
    __shared__ __align__(16) u16 Bls[128 * PLDA];
    const int m0 = blockIdx.x * 32;
    const int t = threadIdx.x;
    const int wave = t >> 6, lane = t & 63, quad = lane >> 4, l16 = lane & 15;
    const int fp32out = (mode == 2 && *flag) ? 1 : 0;
    f32x4 acc[2][2];
#pragma unroll
    for (int i = 0; i < 2; i++)
#pragma unroll
        for (int j = 0; j < 2; j++) acc[i][j] = (f32x4){0.f, 0.f, 0.f, 0.f};

    // prefetch registers for the 2-stage pipeline
    uint4 pa;              // A task: threads 0..127 (row = t>>2, kc = t&3)
    uint4 pb0, pb1;        // B tasks: c = t and c = t+256 (row = c>>2, kc = c&3)
    const int arow = t >> 2, akc = t & 3;
    const int b0row = t >> 2, b0kc = t & 3;
    const int b1row = (t + 256) >> 2, b1kc = t & 3;
    {
        if (t < 128)
            pa = *reinterpret_cast<const uint4*>(A + (size_t)(m0 + arow) * lda + akc * 8);
        pb0 = *reinterpret_cast<const uint4*>(Bt + (size_t)b0row * 1024 + b0kc * 8);
        pb1 = *reinterpret_cast<const uint4*>(Bt + (size_t)b1row * 1024 + b1kc * 8);
    }
    for (int ko = 0; ko < 1024; ko += 32) {
        // commit prefetched tile to LDS
        if (t < 128)
            *reinterpret_cast<uint4*>(&Als[arow * PLDA + akc * 8]) = pa;
        *reinterpret_cast<uint4*>(&Bls[b0row * PLDA + b0kc * 8]) = pb0;
        *reinterpret_cast<uint4*>(&Bls[b1row * PLDA + b1kc * 8]) = pb1;
        __syncthreads();
        // issue next tile's global loads (overlap with MFMA below)
        int kn = ko + 32;
        if (kn < 1024) {
            if (t < 128)
                pa = *reinterpret_cast<const uint4*>(A + (size_t)(m0 + arow) * lda + kn + akc * 8);
            pb0 = *reinterpret_cast<const uint4*>(Bt + (size_t)b0row * 1024 + kn + b0kc * 8);
            pb1 = *reinterpret_cast<const uint4*>(Bt + (size_t)b1row * 1024 + kn + b1kc * 8);
        }
        short8 af[2], bf[2];
#pragma unroll
        for (int mt = 0; mt < 2; mt++)
            af[mt] = *reinterpret_cast<const short8*>(&Als[(mt * 16 + l16) * PLDA + quad * 8]);
#pragma unroll
        for (int nt = 0; nt < 2; nt++)
            bf[nt] = *reinterpret_cast<const short8*>(&Bls[(wave * 32 + nt * 16 + l16) * PLDA + quad * 8]);
#pragma unroll
        for (int mt = 0; mt < 2; mt++)
#pragma unroll
            for (int nt = 0; nt < 2; nt++)
                acc[mt][nt] = __builtin_amdgcn_mfma_f32_16x16x32_bf16(af[mt], bf[nt], acc[mt][nt], 0, 0, 0);
        __syncthreads();
    }
#pragma unroll
    for (int mt = 0; mt < 2; mt++)
#pragma unroll
    for (int r = 0; r < 4; r++) {
        int row = m0 + mt * 16 + quad * 4 + r;
        if (row >= NN) continue;
#pragma unroll
        for (int nt = 0; nt < 2; nt++) {
            int col = wave * 32 + nt * 16 + l16;
            float v = acc[mt][nt][r] + bu2f(bias[col]) + bu2f(resid[(size_t)row * D_H + col]);
            float rr = (v == v) ? fmaxf(v, 0.f) : v;
            if (fp32out) ((float*)C)[(size_t)row * D_H + col] = rr;
            else         ((u16*)C)[(size_t)row * D_H + col] = f2bu(rr);
        }
    }
}

// ---------------- host launch ----------------
extern "C" void kernel_launch(void* const* d_in, const int* in_sizes, int n_in,
                              void* d_out, int out_size, void* d_ws, size_t ws_size,
                              hipStream_t stream) {
    const int* ei = (const int*)d_in[1];
    const int* srcI = ei;
    const int* dstI = ei + NE;

    char* w = (char*)d_ws;
    auto carve = [&](size_t bytes) -> char* {
        char* p = w;
        w += (bytes + 255) & ~(size_t)255;
        return p;
    };
    u16* Bmain  = (u16*)carve((size_t)N_LAYERS * 2048 * 128 * 2);
    u16* WvT    = (u16*)carve((size_t)N_LAYERS * 1024 * 128 * 2);
    u16* WTp    = (u16*)carve((size_t)N_LAYERS * 128 * 1024 * 2);
    u16* hA     = (u16*)carve((size_t)M_PAD * D_H * 2);
    u16* hB     = (u16*)carve((size_t)M_PAD * D_H * 2);
    u16* qkvs2  = (u16*)carve((size_t)M_PAD * QS2 * 2);
    u16* obuf   = (u16*)carve((size_t)M_PAD * 1024 * 2);
    float* scbuf = (float*)carve((size_t)NN * 8 * 4);
    u16* cbuf   = (u16*)carve((size_t)N_LAYERS * 1024 * 2);
    float* wscb = (float*)carve((size_t)N_LAYERS * 1024 * 4);
    float* cscb = (float*)carve((size_t)N_LAYERS * 8 * 4);
    int* cnt    = (int*)carve(2 * NN * 4);
    int* cursor = cnt + NN;
    int* offs   = (int*)carve((NN + 1) * 4);
    int* incl   = (int*)carve(NN * 4);
    int* bsum   = (int*)carve(128 * 4);
    int* bpre   = (int*)carve(128 * 4);
    int* srcp   = (int*)carve(NE * 4);
    int* flag   = (int*)carve(256);

    const int conv_size[13] = {NN * L_IN, L_IN * D_H, D_H,
                               N_LAYERS * D_HC, N_LAYERS * D_HC, N_LAYERS * D_HC,
                               N_LAYERS * D_HC, N_LAYERS * 3 * D_HC,
                               N_LAYERS * D_HC, N_LAYERS * D_HC, N_LAYERS * D_H,
                               N_LAYERS * D_H * D_HC, N_LAYERS * D_H * D_HC};
    const int conv_idx[13] = {0, 2, 3, 5, 7, 9, 11, 12, 13, 14, 16, 4, 6};
    CvDesc dsc;
    u16* conv[13];
    for (int i = 0; i < 13; i++) {
        conv[i] = (u16*)carve((size_t)conv_size[i] * 2);
        dsc.in[i] = d_in[conv_idx[i]];
        dsc.out[i] = conv[i];
    }

    k_detect<<<1, 256, 0, stream>>>((const u16*)d_in[0], flag);
    k_convert_all<<<(CV_TOTAL + 255) / 256, 256, 0, stream>>>(dsc, flag);
    const u16* x    = conv[0];
    const u16* Win  = conv[1];
    const u16* b_in = conv[2];
    const u16* bq   = conv[3];
    const u16* bk   = conv[4];
    const u16* bv   = conv[5];
    const u16* bsk  = conv[6];
    const u16* Wb   = conv[7];
    const u16* lng  = conv[8];
    const u16* lnb  = conv[9];
    const u16* bp   = conv[10];
    const u16* Wqb  = conv[11];
    const u16* Wkb  = conv[12];

    k_convT_vs<<<dim3(2, 32, 6), 256, 0, stream>>>(d_in[8], d_in[10], WvT, Bmain, flag);
    k_convT_proj<<<dim3(16, 2, 6), 256, 0, stream>>>(d_in[15], WTp, flag);
    k_GG<<<dim3(8, 6), 256, 0, stream>>>(Wqb, Wkb, Bmain);
    k_pre_small<<<(N_LAYERS * 2056 + 255) / 256, 256, 0, stream>>>(Wqb, Wkb, bq, bk,
                                                                   cbuf, wscb, cscb);
    k_input_proj<<<(NN * D_H) / 256, 256, 0, stream>>>(x, Win, b_in, hA);
    k_zero<<<(2 * NN + 255) / 256, 256, 0, stream>>>(cnt, 2 * NN);
    k_hist<<<(NE + 255) / 256, 256, 0, stream>>>(dstI, cnt);
    const int NB = (NN + 255) / 256;  // 79
    k_scanA<<<NB, 256, 0, stream>>>(cnt, incl, bsum);
    k_scanB<<<1, 128, 0, stream>>>(bsum, bpre, NB);
    k_scanC<<<NB, 256, 0, stream>>>(incl, bpre, offs);
    k_scatter<<<(NE + 255) / 256, 256, 0, stream>>>(dstI, srcI, offs, cursor, srcp);

    u16* hc = hA;
    u16* hn = hB;
    for (int l = 0; l < N_LAYERS; l++) {
        k_gemm<<<dim3(16, 157), 256, 0, stream>>>(hc, D_H, D_H,
                                                  Bmain + (size_t)l * 2048 * 128,
                                                  qkvs2, QS2,
                                                  cbuf + l * 1024, bsk + l * D_HC);
        k_sc<<<(NN * 8 + 255) / 256, 256, 0, stream>>>(hc, wscb + l * 1024,
                                                       cscb + l * 8, scbuf);
        k_attn2<<<(NN * 64) / 256, 256, 0, stream>>>(qkvs2, hc, offs, srcp, scbuf);
        k_vproj<<<dim3(157, 8), 256, 0, stream>>>(qkvs2, WvT + (size_t)l * 1024 * 128,
                                                  bv + l * D_HC, obuf);
        k_betaLN<<<(NN * 64) / 256, 256, 0, stream>>>(obuf, qkvs2,
                                                      Wb + (size_t)l * 3 * D_HC,
                                                      lng + l * D_HC, lnb + l * D_HC);
        int last = (l == N_LAYERS - 1);
        void* outp = last ? d_out : (void*)hn;
        k_proj<<<628, 256, 0, stream>>>(qkvs2, QS2, WTp + (size_t)l * 128 * 1024,
                                        outp, last ? 2 : 1,
                                        bp + l * D_H, hc, flag);
        u16* tmp = hc; hc = hn; hn = tmp;
    }
}

// Round 12
// 907.615 us; speedup vs baseline: 1.9040x; 1.0411x over previous
//
#include <hip/hip_runtime.h>
#include <stdint.h>

#define NN 20000
#define NE 160000
#define L_IN 15
#define D_H 128
#define N_HEADS 8
#define D_HC 1024
#define N_LAYERS 6
#define M_PAD 20096   // 157*128 = 628*32
#define QS2 2048      // zd|x_r interleaved row stride (u,y overwrite zd slot)

typedef unsigned short u16;
typedef __attribute__((ext_vector_type(8))) short short8;
typedef __attribute__((ext_vector_type(4))) float f32x4;

#define RSQRT_D 0.08838834764831845f  // 1/sqrt(128)

__device__ __forceinline__ float bu2f(u16 u) { return __uint_as_float(((unsigned)u) << 16); }
__device__ __forceinline__ u16 f2bu(float f) {
    unsigned x = __float_as_uint(f);
    return (u16)((x + 0x7fffu + ((x >> 16) & 1u)) >> 16);  // RNE
}
__device__ __forceinline__ float wred64(float v) {
#pragma unroll
    for (int m = 32; m >= 1; m >>= 1) v += __shfl_xor(v, m, 64);
    return v;
}
__device__ __forceinline__ void cvt16(const uint4& u0, const uint4& u1, float* f) {
    unsigned d[8] = {u0.x, u0.y, u0.z, u0.w, u1.x, u1.y, u1.z, u1.w};
#pragma unroll
    for (int i = 0; i < 8; i++) {
        f[2 * i]     = __uint_as_float(d[i] << 16);
        f[2 * i + 1] = __uint_as_float(d[i] & 0xffff0000u);
    }
}

// ---------------- dtype detection ----------------
__global__ void k_detect(const u16* __restrict__ xb, int* __restrict__ flag) {
    int t = threadIdx.x;
    u16 u = xb[2 * t];
    int e = (u >> 7) & 0xFF;
    int weird = (e > 150 || (e != 0 && e < 100)) ? 1 : 0;
    __shared__ int cnt;
    if (t == 0) cnt = 0;
    __syncthreads();
    atomicAdd(&cnt, weird);
    __syncthreads();
    if (t == 0) *flag = (cnt > 64) ? 1 : 0;  // 1 = inputs are fp32
}

// ---------------- fused convert (13 segments incl. Wq, Wk) ----------------
struct CvDesc { const void* in[13]; u16* out[13]; };
#define CV_TOTAL 1930976
__global__ void k_convert_all(CvDesc dsc, const int* __restrict__ flag) {
    const int sizes[13] = {NN * L_IN, L_IN * D_H, D_H,
                           N_LAYERS * D_HC, N_LAYERS * D_HC, N_LAYERS * D_HC,
                           N_LAYERS * D_HC, N_LAYERS * 3 * D_HC,
                           N_LAYERS * D_HC, N_LAYERS * D_HC, N_LAYERS * D_H,
                           N_LAYERS * D_H * D_HC, N_LAYERS * D_H * D_HC};
    int off = blockIdx.x * 256 + threadIdx.x;
    if (off >= CV_TOTAL) return;
    int seg = 0;
#pragma unroll
    for (int s = 0; s < 13; s++) {
        if (off >= sizes[s] && seg == s) { off -= sizes[s]; seg = s + 1; }
    }
    if (*flag) dsc.out[seg][off] = f2bu(((const float*)dsc.in[seg])[off]);
    else       dsc.out[seg][off] = ((const u16*)dsc.in[seg])[off];
}

__global__ void k_zero(int* __restrict__ p, int n) {
    int i = blockIdx.x * 256 + threadIdx.x;
    if (i < n) p[i] = 0;
}

// ------------- convert+transpose: Wv -> WvT, Wskip -> Bmain rows 1024.. ------
__global__ void k_convT_vs(const void* __restrict__ Wv, const void* __restrict__ Ws,
                           u16* __restrict__ WvT, u16* __restrict__ Bmain,
                           const int* __restrict__ flag) {
    __shared__ u16 tile[64][66];
    int tk = blockIdx.x, tn = blockIdx.y, l = blockIdx.z;
    int t = threadIdx.x;
    int isv = (tn < 16);
    const void* W = isv ? Wv : Ws;
    int n_off = (tn & 15) * 64;
    int r = t >> 2, c0 = (t & 3) * 16;
    size_t base = (size_t)l * 128 * 1024 + (size_t)(tk * 64 + r) * 1024 + n_off + c0;
    if (*flag) {
        const float* Wf = (const float*)W;
#pragma unroll
        for (int cc = 0; cc < 16; cc++) tile[c0 + cc][r] = f2bu(Wf[base + cc]);
    } else {
        const u16* Wh = (const u16*)W;
#pragma unroll
        for (int cc = 0; cc < 16; cc++) tile[c0 + cc][r] = Wh[base + cc];
    }
    __syncthreads();
    int i = t >> 2, j0 = (t & 3) * 16;
    u16* dst = isv ? (WvT + ((size_t)l * 1024 + n_off + i) * 128 + tk * 64 + j0)
                   : (Bmain + ((size_t)l * 2048 + 1024 + n_off + i) * 128 + tk * 64 + j0);
#pragma unroll
    for (int jj = 0; jj < 16; jj++) dst[jj] = tile[i][j0 + jj];
}

// Wp: [l][1024 k][128 n] -> WTp [l][128 n][1024 k]. grid (16, 2, 6).
__global__ void k_convT_proj(const void* __restrict__ Wp, u16* __restrict__ WT,
                             const int* __restrict__ flag) {
    __shared__ u16 tile[64][66];
    int tk = blockIdx.x, tn = blockIdx.y, l = blockIdx.z;
    int t = threadIdx.x;
    int r = t >> 2, c0 = (t & 3) * 16;
    size_t base = (size_t)l * 1024 * 128 + (size_t)(tk * 64 + r) * 128 + tn * 64 + c0;
    if (*flag) {
        const float* Wf = (const float*)Wp;
#pragma unroll
        for (int cc = 0; cc < 16; cc++) tile[c0 + cc][r] = f2bu(Wf[base + cc]);
    } else {
        const u16* Wh = (const u16*)Wp;
#pragma unroll
        for (int cc = 0; cc < 16; cc++) tile[c0 + cc][r] = Wh[base + cc];
    }
    __syncthreads();
    int i = t >> 2, j0 = (t & 3) * 16;
    u16* dst = WT + ((size_t)l * 128 + tn * 64 + i) * 1024 + tk * 64 + j0;
#pragma unroll
    for (int jj = 0; jj < 16; jj++) dst[jj] = tile[i][j0 + jj];
}

// ---------------- GG precompute: Bmain rows 0-1023 = (Wq_h Wk_h^T)^T / sqrt(d) --
__global__ void k_GG(const u16* __restrict__ Wqb, const u16* __restrict__ Wkb,
                     u16* __restrict__ Bmain) {
    int h = blockIdx.x, l = blockIdx.y;
    __shared__ __align__(16) u16 Als[128 * 32];
    __shared__ __align__(16) u16 Bls[128 * 32];
    const int t = threadIdx.x;
    const int wave = t >> 6, lane = t & 63, quad = lane >> 4, l16 = lane & 15;
    const int wm = (wave >> 1) * 64, wn = (wave & 1) * 64;
    const u16* Ab = Wqb + (size_t)l * 128 * 1024 + h * 128;
    const u16* Bb = Wkb + (size_t)l * 128 * 1024 + h * 128;
    f32x4 acc[4][4];
#pragma unroll
    for (int i = 0; i < 4; i++)
#pragma unroll
        for (int j = 0; j < 4; j++) acc[i][j] = (f32x4){0.f, 0.f, 0.f, 0.f};
    for (int ko = 0; ko < 128; ko += 32) {
#pragma unroll
        for (int c = t; c < 512; c += 256) {
            int row = c >> 2, kc = c & 3;
            *reinterpret_cast<uint4*>(&Als[row * 32 + kc * 8]) =
                *reinterpret_cast<const uint4*>(Ab + (size_t)row * 1024 + ko + kc * 8);
            *reinterpret_cast<uint4*>(&Bls[row * 32 + kc * 8]) =
                *reinterpret_cast<const uint4*>(Bb + (size_t)row * 1024 + ko + kc * 8);
        }
        __syncthreads();
        short8 af[4], bf[4];
#pragma unroll
        for (int mt = 0; mt < 4; mt++)
            af[mt] = *reinterpret_cast<const short8*>(&Als[(wm + mt * 16 + l16) * 32 + quad * 8]);
#pragma unroll
        for (int nt = 0; nt < 4; nt++)
            bf[nt] = *reinterpret_cast<const short8*>(&Bls[(wn + nt * 16 + l16) * 32 + quad * 8]);
#pragma unroll
        for (int mt = 0; mt < 4; mt++)
#pragma unroll
            for (int nt = 0; nt < 4; nt++)
                acc[mt][nt] = __builtin_amdgcn_mfma_f32_16x16x32_bf16(af[mt], bf[nt], acc[mt][nt], 0, 0, 0);
        __syncthreads();
    }
    u16* dst = Bmain + (size_t)l * 2048 * 128;
#pragma unroll
    for (int mt = 0; mt < 4; mt++)
#pragma unroll
        for (int r = 0; r < 4; r++) {
            int row = wm + mt * 16 + quad * 4 + r;  // a
#pragma unroll
            for (int nt = 0; nt < 4; nt++) {
                int col = wn + nt * 16 + l16;       // b
                dst[(size_t)(h * 128 + col) * 128 + row] = f2bu(acc[mt][nt][r] * RSQRT_D);
            }
        }
}

// ---------------- small precompute: cb, wscT ([h][a] layout), csc ----------------
__global__ void k_pre_small(const u16* __restrict__ Wqb, const u16* __restrict__ Wkb,
                            const u16* __restrict__ bq, const u16* __restrict__ bk,
                            u16* __restrict__ cb, float* __restrict__ wscT,
                            float* __restrict__ csc) {
    int gid = blockIdx.x * 256 + threadIdx.x;  // 6*2056
    if (gid >= N_LAYERS * 2056) return;
    int l = gid / 2056, r = gid % 2056;
    float acc = 0.f;
    if (r < 1024) {
        int h = r >> 7, b = r & 127;
        const u16* bqp = bq + l * D_HC + h * 128;
        const u16* wkp = Wkb + (size_t)l * 128 * 1024 + (size_t)b * 1024 + h * 128;
        for (int m = 0; m < 128; m++) acc += bu2f(bqp[m]) * bu2f(wkp[m]);
        cb[l * 1024 + r] = f2bu(acc * RSQRT_D);
    } else if (r < 2048) {
        int idx = r - 1024;          // idx = h*128 + a
        int h = idx >> 7, a = idx & 127;
        const u16* wqp = Wqb + (size_t)l * 128 * 1024 + (size_t)a * 1024 + h * 128;
        const u16* bkp = bk + l * D_HC + h * 128;
        for (int m = 0; m < 128; m++) acc += bu2f(wqp[m]) * bu2f(bkp[m]);
        wscT[l * 1024 + idx] = acc * RSQRT_D;
    } else {
        int h = r - 2048;
        const u16* bqp = bq + l * D_HC + h * 128;
        const u16* bkp = bk + l * D_HC + h * 128;
        for (int m = 0; m < 128; m++) acc += bu2f(bqp[m]) * bu2f(bkp[m]);
        csc[l * 8 + h] = acc * RSQRT_D;
    }
}

// ---------------- input projection ----------------
__global__ void k_input_proj(const u16* __restrict__ x, const u16* __restrict__ Win,
                             const u16* __restrict__ b_in, u16* __restrict__ h) {
    int gid = blockIdx.x * 256 + threadIdx.x;  // NN*128
    int n = gid >> 7, j = gid & 127;
    float acc = bu2f(b_in[j]);
#pragma unroll
    for (int i = 0; i < L_IN; i++) acc += bu2f(x[n * L_IN + i]) * bu2f(Win[i * D_H + j]);
    h[gid] = f2bu(acc);
}

// ---------------- CSR build ----------------
__global__ void k_hist(const int* __restrict__ dst, int* __restrict__ cnt) {
    int e = blockIdx.x * 256 + threadIdx.x;
    if (e < NE) atomicAdd(&cnt[dst[e]], 1);
}
__global__ void k_scanA(const int* __restrict__ cnt, int* __restrict__ incl, int* __restrict__ bsum) {
    __shared__ int s[256];
    int b = blockIdx.x, t = threadIdx.x, i = b * 256 + t;
    int v = (i < NN) ? cnt[i] : 0;
    s[t] = v;
    __syncthreads();
    for (int off = 1; off < 256; off <<= 1) {
        int u = (t >= off) ? s[t - off] : 0;
        __syncthreads();
        s[t] += u;
        __syncthreads();
    }
    if (i < NN) incl[i] = s[t];
    if (t == 255) bsum[b] = s[255];
}
__global__ void k_scanB(const int* __restrict__ bsum, int* __restrict__ bpre, int nb) {
    __shared__ int s[128];
    int t = threadIdx.x;
    int v = (t < nb) ? bsum[t] : 0;
    s[t] = v;
    __syncthreads();
    for (int off = 1; off < 128; off <<= 1) {
        int u = (t >= off) ? s[t - off] : 0;
        __syncthreads();
        s[t] += u;
        __syncthreads();
    }
    if (t < nb) bpre[t] = s[t] - v;
}
__global__ void k_scanC(const int* __restrict__ incl, const int* __restrict__ bpre, int* __restrict__ offs) {
    int b = blockIdx.x, t = threadIdx.x, i = b * 256 + t;
    if (i < NN) offs[i + 1] = incl[i] + bpre[b];
    if (i == 0) offs[0] = 0;
}
__global__ void k_scatter(const int* __restrict__ dst, const int* __restrict__ src,
                          const int* __restrict__ offs, int* __restrict__ cursor,
                          int* __restrict__ srcp) {
    int e = blockIdx.x * 256 + threadIdx.x;
    if (e < NE) {
        int d = dst[e];
        int p = offs[d] + atomicAdd(&cursor[d], 1);
        srcp[p] = src[e];
    }
}

// ---------------- main MFMA GEMM: C[M,2048] = h @ [GG^T | WskipT]^T + [cb|bskip] --
__global__ void k_gemm(const u16* __restrict__ A, int lda, int K,
                       const u16* __restrict__ Bt,
                       u16* __restrict__ C, int ldc,
                       const u16* __restrict__ bia0, const u16* __restrict__ bia1) {
    __shared__ __align__(16) u16 smem[128 * 136];
    u16* Als = smem;
    u16* Bls = smem + 4096;
    const int m0 = blockIdx.y * 128, n0 = blockIdx.x * 128;
    const int t = threadIdx.x;
    const int wave = t >> 6, lane = t & 63, quad = lane >> 4, l16 = lane & 15;
    const int wm = (wave >> 1) * 64, wn = (wave & 1) * 64;
    f32x4 acc[4][4];
#pragma unroll
    for (int i = 0; i < 4; i++)
#pragma unroll
        for (int j = 0; j < 4; j++) acc[i][j] = (f32x4){0.f, 0.f, 0.f, 0.f};

    for (int ko = 0; ko < K; ko += 32) {
#pragma unroll
        for (int c = t; c < 512; c += 256) {
            int row = c >> 2, kc = c & 3;
            *reinterpret_cast<uint4*>(&Als[row * 32 + kc * 8]) =
                *reinterpret_cast<const uint4*>(A + (size_t)(m0 + row) * lda + ko + kc * 8);
            *reinterpret_cast<uint4*>(&Bls[row * 32 + kc * 8]) =
                *reinterpret_cast<const uint4*>(Bt + (size_t)(n0 + row) * K + ko + kc * 8);
        }
        __syncthreads();
        short8 af[4], bf[4];
#pragma unroll
        for (int mt = 0; mt < 4; mt++)
            af[mt] = *reinterpret_cast<const short8*>(&Als[(wm + mt * 16 + l16) * 32 + quad * 8]);
#pragma unroll
        for (int nt = 0; nt < 4; nt++)
            bf[nt] = *reinterpret_cast<const short8*>(&Bls[(wn + nt * 16 + l16) * 32 + quad * 8]);
#pragma unroll
        for (int mt = 0; mt < 4; mt++)
#pragma unroll
            for (int nt = 0; nt < 4; nt++)
                acc[mt][nt] = __builtin_amdgcn_mfma_f32_16x16x32_bf16(af[mt], bf[nt], acc[mt][nt], 0, 0, 0);
        __syncthreads();
    }
#pragma unroll
    for (int mt = 0; mt < 4; mt++)
#pragma unroll
        for (int r = 0; r < 4; r++) {
            int rl = wm + mt * 16 + quad * 4 + r;
#pragma unroll
            for (int nt = 0; nt < 4; nt++) {
                int cl = wn + nt * 16 + l16;
                int col = n0 + cl;
                const u16* bp = (col < 1024) ? bia0 : bia1;
                smem[rl * 136 + cl] = f2bu(acc[mt][nt][r] + bu2f(bp[col & 1023]));
            }
        }
    __syncthreads();
#pragma unroll
    for (int c = t; c < 2048; c += 256) {
        int row = c >> 4, kc = c & 15;
        int grow = m0 + row;
        if (grow < NN)
            *reinterpret_cast<uint4*>(C + (size_t)grow * ldc + n0 + kc * 8) =
                *reinterpret_cast<const uint4*>(&smem[row * 136 + kc * 8]);
    }
}

// ---------------- attention (sc inlined): one wave per dst node ----------------
__global__ void k_attn2(u16* __restrict__ qkvs2, const u16* __restrict__ hc,
                        const int* __restrict__ offs, const int* __restrict__ srcp,
                        const float* __restrict__ wscT_l, const float* __restrict__ csc_l) {
    int gid = blockIdx.x * 256 + threadIdx.x;
    int d = gid >> 6, lane = gid & 63;
    if (d >= NN) return;
    int hh = lane >> 3, ci = (lane & 7) * 16;
    u16* zp = qkvs2 + (size_t)d * QS2 + hh * 128 + ci;
    float zf[16];
    {
        uint4 z0 = *reinterpret_cast<const uint4*>(zp);
        uint4 z1 = *reinterpret_cast<const uint4*>(zp + 8);
        cvt16(z0, z1, zf);
    }
    // inline sc: scown = csc[h] + sum_a h_d[a] * wscT[h][a]
    float scown;
    {
        const u16* hdp = hc + (size_t)d * 128 + ci;
        uint4 hd0 = *reinterpret_cast<const uint4*>(hdp);
        uint4 hd1 = *reinterpret_cast<const uint4*>(hdp + 8);
        float hdf[16];
        cvt16(hd0, hd1, hdf);
        const float* wt = wscT_l + hh * 128 + ci;
        float scp = 0.f;
#pragma unroll
        for (int j = 0; j < 16; j++) scp += hdf[j] * wt[j];
        scp += __shfl_xor(scp, 1, 64);
        scp += __shfl_xor(scp, 2, 64);
        scp += __shfl_xor(scp, 4, 64);
        scown = scp + csc_l[hh];
    }
    float u[16];
#pragma unroll
    for (int j = 0; j < 16; j++) u[j] = 0.f;
    float lrun = 0.f;

    int beg = offs[d], end = offs[d + 1];
    for (int c0 = beg; c0 < end; c0 += 64) {
        int cn = min(64, end - c0);
        int myidx = (c0 + lane < end) ? srcp[c0 + lane] : 0;
        int s = __shfl(myidx, 0, 64);
        const u16* hp = hc + (size_t)s * 128 + ci;
        uint4 a0 = *reinterpret_cast<const uint4*>(hp);
        uint4 a1 = *reinterpret_cast<const uint4*>(hp + 8);
        for (int i = 0; i < cn; i++) {
            uint4 n0 = a0, n1 = a1;
            if (i + 1 < cn) {
                int sn = __shfl(myidx, i + 1, 64);
                const u16* hpn = hc + (size_t)sn * 128 + ci;
                n0 = *reinterpret_cast<const uint4*>(hpn);
                n1 = *reinterpret_cast<const uint4*>(hpn + 8);
            }
            float hf[16];
            cvt16(a0, a1, hf);
            float p = 0.f;
#pragma unroll
            for (int j = 0; j < 16; j++) p += zf[j] * hf[j];
            p += __shfl_xor(p, 1, 64);
            p += __shfl_xor(p, 2, 64);
            p += __shfl_xor(p, 4, 64);
            float w = __expf(p + scown);
            lrun += w;
#pragma unroll
            for (int j = 0; j < 16; j++) u[j] += w * hf[j];
            a0 = n0; a1 = n1;
        }
    }
    float inv = 1.f / (lrun + 1e-16f);
    unsigned out[8];
#pragma unroll
    for (int j = 0; j < 8; j++)
        out[j] = (unsigned)f2bu(u[2 * j] * inv) | ((unsigned)f2bu(u[2 * j + 1] * inv) << 16);
    uint4* op = reinterpret_cast<uint4*>(zp);
    op[0] = make_uint4(out[0], out[1], out[2], out[3]);
    op[1] = make_uint4(out[4], out[5], out[6], out[7]);
}

// ---------------- vproj: o[d, h*128+c'] = u[d,h,:] @ Wv_h + bv ----------------
__global__ void k_vproj(const u16* __restrict__ A /*qkvs2 u-slot*/,
                        const u16* __restrict__ WvT_l, const u16* __restrict__ bv_l,
                        u16* __restrict__ obuf) {
    __shared__ __align__(16) u16 smem[128 * 136];
    u16* Als = smem;
    u16* Bls = smem + 4096;
    const int m0 = blockIdx.x * 128, h = blockIdx.y;
    const int t = threadIdx.x;
    const int wave = t >> 6, lane = t & 63, quad = lane >> 4, l16 = lane & 15;
    const int wm = (wave >> 1) * 64, wn = (wave & 1) * 64;
    f32x4 acc[4][4];
#pragma unroll
    for (int i = 0; i < 4; i++)
#pragma unroll
        for (int j = 0; j < 4; j++) acc[i][j] = (f32x4){0.f, 0.f, 0.f, 0.f};

    for (int ko = 0; ko < 128; ko += 32) {
#pragma unroll
        for (int c = t; c < 512; c += 256) {
            int row = c >> 2, kc = c & 3;
            *reinterpret_cast<uint4*>(&Als[row * 32 + kc * 8]) =
                *reinterpret_cast<const uint4*>(A + (size_t)(m0 + row) * QS2 + h * 128 + ko + kc * 8);
            *reinterpret_cast<uint4*>(&Bls[row * 32 + kc * 8]) =
                *reinterpret_cast<const uint4*>(WvT_l + (size_t)(h * 128 + row) * 128 + ko + kc * 8);
        }
        __syncthreads();
        short8 af[4], bf[4];
#pragma unroll
        for (int mt = 0; mt < 4; mt++)
            af[mt] = *reinterpret_cast<const short8*>(&Als[(wm + mt * 16 + l16) * 32 + quad * 8]);
#pragma unroll
        for (int nt = 0; nt < 4; nt++)
            bf[nt] = *reinterpret_cast<const short8*>(&Bls[(wn + nt * 16 + l16) * 32 + quad * 8]);
#pragma unroll
        for (int mt = 0; mt < 4; mt++)
#pragma unroll
            for (int nt = 0; nt < 4; nt++)
                acc[mt][nt] = __builtin_amdgcn_mfma_f32_16x16x32_bf16(af[mt], bf[nt], acc[mt][nt], 0, 0, 0);
        __syncthreads();
    }
#pragma unroll
    for (int mt = 0; mt < 4; mt++)
#pragma unroll
        for (int r = 0; r < 4; r++) {
            int rl = wm + mt * 16 + quad * 4 + r;
#pragma unroll
            for (int nt = 0; nt < 4; nt++) {
                int cl = wn + nt * 16 + l16;
                smem[rl * 136 + cl] = f2bu(acc[mt][nt][r] + bu2f(bv_l[h * 128 + cl]));
            }
        }
    __syncthreads();
#pragma unroll
    for (int c = t; c < 2048; c += 256) {
        int row = c >> 4, kc = c & 15;
        int grow = m0 + row;
        if (grow < NN)
            *reinterpret_cast<uint4*>(obuf + (size_t)grow * 1024 + h * 128 + kc * 8) =
                *reinterpret_cast<const uint4*>(&smem[row * 136 + kc * 8]);
    }
}

// ---------------- beta gate + LayerNorm: one wave per node ----------------
__global__ void k_betaLN(const u16* __restrict__ obuf, u16* __restrict__ qkvs2,
                         const u16* __restrict__ Wb, const u16* __restrict__ lng,
                         const u16* __restrict__ lnb) {
    int gid = blockIdx.x * 256 + threadIdx.x;
    int d = gid >> 6, lane = gid & 63;
    if (d >= NN) return;
    int c0 = lane * 16;
    float o[16], xr[16];
    {
        const u16* op = obuf + (size_t)d * 1024 + c0;
        uint4 o0 = *reinterpret_cast<const uint4*>(op);
        uint4 o1 = *reinterpret_cast<const uint4*>(op + 8);
        cvt16(o0, o1, o);
        const u16* xp = qkvs2 + (size_t)d * QS2 + 1024 + c0;
        uint4 x0 = *reinterpret_cast<const uint4*>(xp);
        uint4 x1 = *reinterpret_cast<const uint4*>(xp + 8);
        cvt16(x0, x1, xr);
    }
    float part = 0.f;
    {
        const u16* wp = Wb + c0;
        uint4 u0 = *reinterpret_cast<const uint4*>(wp);
        uint4 u1 = *reinterpret_cast<const uint4*>(wp + 8);
        float wf[16];
        cvt16(u0, u1, wf);
#pragma unroll
        for (int j = 0; j < 16; j++) part += o[j] * wf[j];
        u0 = *reinterpret_cast<const uint4*>(wp + D_HC);
        u1 = *reinterpret_cast<const uint4*>(wp + D_HC + 8);
        cvt16(u0, u1, wf);
#pragma unroll
        for (int j = 0; j < 16; j++) part += xr[j] * wf[j];
        u0 = *reinterpret_cast<const uint4*>(wp + 2 * D_HC);
        u1 = *reinterpret_cast<const uint4*>(wp + 2 * D_HC + 8);
        cvt16(u0, u1, wf);
#pragma unroll
        for (int j = 0; j < 16; j++) part += (o[j] - xr[j]) * wf[j];
    }
    float logit = wred64(part);
    float beta = 1.f / (1.f + __expf(-logit));
    float g[16], s1 = 0.f, s2 = 0.f;
#pragma unroll
    for (int j = 0; j < 16; j++) {
        g[j] = beta * xr[j] + (1.f - beta) * o[j];
        s1 += g[j]; s2 += g[j] * g[j];
    }
    s1 = wred64(s1);
    s2 = wred64(s2);
    float mu = s1 * (1.f / 1024.f);
    float var = s2 * (1.f / 1024.f) - mu * mu;
    float rs = rsqrtf(var + 1e-5f);
    {
        const u16* gp = lng + c0;
        const u16* bp2 = lnb + c0;
        uint4 g0 = *reinterpret_cast<const uint4*>(gp);
        uint4 g1 = *reinterpret_cast<const uint4*>(gp + 8);
        uint4 b0 = *reinterpret_cast<const uint4*>(bp2);
        uint4 b1 = *reinterpret_cast<const uint4*>(bp2 + 8);
        float lgf[16], lbf[16];
        cvt16(g0, g1, lgf);
        cvt16(b0, b1, lbf);
        unsigned out[8];
#pragma unroll
        for (int j = 0; j < 8; j++) {
            float y0 = (g[2 * j] - mu) * rs * lgf[2 * j] + lbf[2 * j];
            float y1 = (g[2 * j + 1] - mu) * rs * lgf[2 * j + 1] + lbf[2 * j + 1];
            out[j] = (unsigned)f2bu(y0) | ((unsigned)f2bu(y1) << 16);
        }
        uint4* yp = reinterpret_cast<uint4*>(qkvs2 + (size_t)d * QS2 + c0);
        yp[0] = make_uint4(out[0], out[1], out[2], out[3]);
        yp[1] = make_uint4(out[4], out[5], out[6], out[7]);
    }
}

// ---------------- proj GEMM v2: M=32 tiles (628 blocks) + register-prefetch ----
#define PLDA 40
__global__ void k_proj(const u16* __restrict__ A, int lda,
                       const u16* __restrict__ Bt,
                       void* __restrict__ C, int mode,
                       const u16* __restrict__ bias, const u16* __restrict__ resid,
                       const int* __restrict__ flag) {
    __shared__ __align__(16) u16 Als[32 * PLDA];
    __shared__ __align__(16) u16 Bls[128 * PLDA];
    const int m0 = blockIdx.x * 32;
    const int t = threadIdx.x;
    const int wave = t >> 6, lane = t & 63, quad = lane >> 4, l16 = lane & 15;
    const int fp32out = (mode == 2 && *flag) ? 1 : 0;
    f32x4 acc[2][2];
#pragma unroll
    for (int i = 0; i < 2; i++)
#pragma unroll
        for (int j = 0; j < 2; j++) acc[i][j] = (f32x4){0.f, 0.f, 0.f, 0.f};

    uint4 pa, pb0, pb1;
    const int arow = t >> 2, akc = t & 3;
    const int b0row = t >> 2, b0kc = t & 3;
    const int b1row = (t + 256) >> 2, b1kc = t & 3;
    {
        if (t < 128)
            pa = *reinterpret_cast<const uint4*>(A + (size_t)(m0 + arow) * lda + akc * 8);
        pb0 = *reinterpret_cast<const uint4*>(Bt + (size_t)b0row * 1024 + b0kc * 8);
        pb1 = *reinterpret_cast<const uint4*>(Bt + (size_t)b1row * 1024 + b1kc * 8);
    }
    for (int ko = 0; ko < 1024; ko += 32) {
        if (t < 128)
            *reinterpret_cast<uint4*>(&Als[arow * PLDA + akc * 8]) = pa;
        *reinterpret_cast<uint4*>(&Bls[b0row * PLDA + b0kc * 8]) = pb0;
        *reinterpret_cast<uint4*>(&Bls[b1row * PLDA + b1kc * 8]) = pb1;
        __syncthreads();
        int kn = ko + 32;
        if (kn < 1024) {
            if (t < 128)
                pa = *reinterpret_cast<const uint4*>(A + (size_t)(m0 + arow) * lda + kn + akc * 8);
            pb0 = *reinterpret_cast<const uint4*>(Bt + (size_t)b0row * 1024 + kn + b0kc * 8);
            pb1 = *reinterpret_cast<const uint4*>(Bt + (size_t)b1row * 1024 + kn + b1kc * 8);
        }
        short8 af[2], bf[2];
#pragma unroll
        for (int mt = 0; mt < 2; mt++)
            af[mt] = *reinterpret_cast<const short8*>(&Als[(mt * 16 + l16) * PLDA + quad * 8]);
#pragma unroll
        for (int nt = 0; nt < 2; nt++)
            bf[nt] = *reinterpret_cast<const short8*>(&Bls[(wave * 32 + nt * 16 + l16) * PLDA + quad * 8]);
#pragma unroll
        for (int mt = 0; mt < 2; mt++)
#pragma unroll
            for (int nt = 0; nt < 2; nt++)
                acc[mt][nt] = __builtin_amdgcn_mfma_f32_16x16x32_bf16(af[mt], bf[nt], acc[mt][nt], 0, 0, 0);
        __syncthreads();
    }
#pragma unroll
    for (int mt = 0; mt < 2; mt++)
#pragma unroll
    for (int r = 0; r < 4; r++) {
        int row = m0 + mt * 16 + quad * 4 + r;
        if (row >= NN) continue;
#pragma unroll
        for (int nt = 0; nt < 2; nt++) {
            int col = wave * 32 + nt * 16 + l16;
            float v = acc[mt][nt][r] + bu2f(bias[col]) + bu2f(resid[(size_t)row * D_H + col]);
            float rr = (v == v) ? fmaxf(v, 0.f) : v;
            if (fp32out) ((float*)C)[(size_t)row * D_H + col] = rr;
            else         ((u16*)C)[(size_t)row * D_H + col] = f2bu(rr);
        }
    }
}

// ---------------- host launch ----------------
extern "C" void kernel_launch(void* const* d_in, const int* in_sizes, int n_in,
                              void* d_out, int out_size, void* d_ws, size_t ws_size,
                              hipStream_t stream) {
    const int* ei = (const int*)d_in[1];
    const int* srcI = ei;
    const int* dstI = ei + NE;

    char* w = (char*)d_ws;
    auto carve = [&](size_t bytes) -> char* {
        char* p = w;
        w += (bytes + 255) & ~(size_t)255;
        return p;
    };
    u16* Bmain  = (u16*)carve((size_t)N_LAYERS * 2048 * 128 * 2);
    u16* WvT    = (u16*)carve((size_t)N_LAYERS * 1024 * 128 * 2);
    u16* WTp    = (u16*)carve((size_t)N_LAYERS * 128 * 1024 * 2);
    u16* hA     = (u16*)carve((size_t)M_PAD * D_H * 2);
    u16* hB     = (u16*)carve((size_t)M_PAD * D_H * 2);
    u16* qkvs2  = (u16*)carve((size_t)M_PAD * QS2 * 2);
    u16* obuf   = (u16*)carve((size_t)M_PAD * 1024 * 2);
    u16* cbuf   = (u16*)carve((size_t)N_LAYERS * 1024 * 2);
    float* wscb = (float*)carve((size_t)N_LAYERS * 1024 * 4);
    float* cscb = (float*)carve((size_t)N_LAYERS * 8 * 4);
    int* cnt    = (int*)carve(2 * NN * 4);
    int* cursor = cnt + NN;
    int* offs   = (int*)carve((NN + 1) * 4);
    int* incl   = (int*)carve(NN * 4);
    int* bsum   = (int*)carve(128 * 4);
    int* bpre   = (int*)carve(128 * 4);
    int* srcp   = (int*)carve(NE * 4);
    int* flag   = (int*)carve(256);

    const int conv_size[13] = {NN * L_IN, L_IN * D_H, D_H,
                               N_LAYERS * D_HC, N_LAYERS * D_HC, N_LAYERS * D_HC,
                               N_LAYERS * D_HC, N_LAYERS * 3 * D_HC,
                               N_LAYERS * D_HC, N_LAYERS * D_HC, N_LAYERS * D_H,
                               N_LAYERS * D_H * D_HC, N_LAYERS * D_H * D_HC};
    const int conv_idx[13] = {0, 2, 3, 5, 7, 9, 11, 12, 13, 14, 16, 4, 6};
    CvDesc dsc;
    u16* conv[13];
    for (int i = 0; i < 13; i++) {
        conv[i] = (u16*)carve((size_t)conv_size[i] * 2);
        dsc.in[i] = d_in[conv_idx[i]];
        dsc.out[i] = conv[i];
    }

    k_detect<<<1, 256, 0, stream>>>((const u16*)d_in[0], flag);
    k_convert_all<<<(CV_TOTAL + 255) / 256, 256, 0, stream>>>(dsc, flag);
    const u16* x    = conv[0];
    const u16* Win  = conv[1];
    const u16* b_in = conv[2];
    const u16* bq   = conv[3];
    const u16* bk   = conv[4];
    const u16* bv   = conv[5];
    const u16* bsk  = conv[6];
    const u16* Wb   = conv[7];
    const u16* lng  = conv[8];
    const u16* lnb  = conv[9];
    const u16* bp   = conv[10];
    const u16* Wqb  = conv[11];
    const u16* Wkb  = conv[12];

    k_convT_vs<<<dim3(2, 32, 6), 256, 0, stream>>>(d_in[8], d_in[10], WvT, Bmain, flag);
    k_convT_proj<<<dim3(16, 2, 6), 256, 0, stream>>>(d_in[15], WTp, flag);
    k_GG<<<dim3(8, 6), 256, 0, stream>>>(Wqb, Wkb, Bmain);
    k_pre_small<<<(N_LAYERS * 2056 + 255) / 256, 256, 0, stream>>>(Wqb, Wkb, bq, bk,
                                                                   cbuf, wscb, cscb);
    k_input_proj<<<(NN * D_H) / 256, 256, 0, stream>>>(x, Win, b_in, hA);
    k_zero<<<(2 * NN + 255) / 256, 256, 0, stream>>>(cnt, 2 * NN);
    k_hist<<<(NE + 255) / 256, 256, 0, stream>>>(dstI, cnt);
    const int NB = (NN + 255) / 256;  // 79
    k_scanA<<<NB, 256, 0, stream>>>(cnt, incl, bsum);
    k_scanB<<<1, 128, 0, stream>>>(bsum, bpre, NB);
    k_scanC<<<NB, 256, 0, stream>>>(incl, bpre, offs);
    k_scatter<<<(NE + 255) / 256, 256, 0, stream>>>(dstI, srcI, offs, cursor, srcp);

    u16* hc = hA;
    u16* hn = hB;
    for (int l = 0; l < N_LAYERS; l++) {
        k_gemm<<<dim3(16, 157), 256, 0, stream>>>(hc, D_H, D_H,
                                                  Bmain + (size_t)l * 2048 * 128,
                                                  qkvs2, QS2,
                                                  cbuf + l * 1024, bsk + l * D_HC);
        k_attn2<<<(NN * 64) / 256, 256, 0, stream>>>(qkvs2, hc, offs, srcp,
                                                     wscb + l * 1024, cscb + l * 8);
        k_vproj<<<dim3(157, 8), 256, 0, stream>>>(qkvs2, WvT + (size_t)l * 1024 * 128,
                                                  bv + l * D_HC, obuf);
        k_betaLN<<<(NN * 64) / 256, 256, 0, stream>>>(obuf, qkvs2,
                                                      Wb + (size_t)l * 3 * D_HC,
                                                      lng + l * D_HC, lnb + l * D_HC);
        int last = (l == N_LAYERS - 1);
        void* outp = last ? d_out : (void*)hn;
        k_proj<<<628, 256, 0, stream>>>(qkvs2, QS2, WTp + (size_t)l * 128 * 1024,
                                        outp, last ? 2 : 1,
                                        bp + l * D_H, hc, flag);
        u16* tmp = hc; hc = hn; hn = tmp;
    }
}